// Round 1
// baseline (2187.761 us; speedup 1.0000x reference)
//
#include <hip/hip_runtime.h>
#include <hip/hip_bf16.h>

#define Bdim 2
#define Sdim 1024
#define Vdim 32000
#define HDdim 1024
#define Ldim 4
#define Hdim 16
#define Ddim 64
#define Idim 4096
#define BSdim 2048

typedef __attribute__((ext_vector_type(8))) short bf16x8;
typedef __attribute__((ext_vector_type(4))) float f32x4;

__device__ __forceinline__ unsigned short f2bf(float f) {
    __hip_bfloat16 h = __float2bfloat16(f);
    return *reinterpret_cast<unsigned short*>(&h);
}
__device__ __forceinline__ float bf2f(unsigned short u) {
    return __uint_as_float(((unsigned int)u) << 16);
}

#define MFMA16(a, b, c) __builtin_amdgcn_mfma_f32_16x16x32_bf16((a), (b), (c), 0, 0, 0)

// ---------------- rope tables ----------------
__global__ __launch_bounds__(256) void tables_kernel(float* __restrict__ cosT, float* __restrict__ sinT) {
    int i = blockIdx.x * 256 + threadIdx.x;   // 65536 = S*D
    int d = i & 63;
    int s = i >> 6;
    float inv = powf(1.0e6f, -((float)(2 * (d & 31))) / 64.0f);
    float f = (float)s * inv;
    cosT[i] = cosf(f);
    sinT[i] = sinf(f);
}

// ---------------- embedding gather ----------------
__global__ __launch_bounds__(256) void embed_kernel(const int* __restrict__ ids, const float* __restrict__ emb,
                                                    float* __restrict__ x) {
    int m = blockIdx.x;
    int tid = threadIdx.x;
    int id = ids[m];
    const float4* src = (const float4*)(emb + (size_t)id * HDdim);
    ((float4*)(x + (size_t)m * HDdim))[tid] = src[tid];
}

// ---------------- layernorm -> bf16 (+ optional f32 copy) ----------------
__global__ __launch_bounds__(256) void ln_kernel(const float* __restrict__ x, const float* __restrict__ w,
                                                 const float* __restrict__ bw, unsigned short* __restrict__ outH,
                                                 float* __restrict__ out32) {
    int m = blockIdx.x;
    int tid = threadIdx.x;
    float4 a = ((const float4*)(x + (size_t)m * HDdim))[tid];
    float s = a.x + a.y + a.z + a.w;
    #pragma unroll
    for (int o = 1; o < 64; o <<= 1) s += __shfl_xor(s, o);
    __shared__ float red[4], red2[4];
    if ((tid & 63) == 0) red[tid >> 6] = s;
    __syncthreads();
    float mean = (red[0] + red[1] + red[2] + red[3]) * (1.0f / 1024.0f);
    float dx = a.x - mean, dy = a.y - mean, dz = a.z - mean, dw = a.w - mean;
    float s2 = dx * dx + dy * dy + dz * dz + dw * dw;
    #pragma unroll
    for (int o = 1; o < 64; o <<= 1) s2 += __shfl_xor(s2, o);
    if ((tid & 63) == 0) red2[tid >> 6] = s2;
    __syncthreads();
    float var = (red2[0] + red2[1] + red2[2] + red2[3]) * (1.0f / 1024.0f);
    float rs = rsqrtf(var + 1e-6f);
    float4 wv = ((const float4*)w)[tid];
    float4 bv = ((const float4*)bw)[tid];
    float v0 = dx * rs * wv.x + bv.x;
    float v1 = dy * rs * wv.y + bv.y;
    float v2 = dz * rs * wv.z + bv.z;
    float v3 = dw * rs * wv.w + bv.w;
    short4 st = make_short4((short)f2bf(v0), (short)f2bf(v1), (short)f2bf(v2), (short)f2bf(v3));
    *(short4*)(outH + (size_t)m * HDdim + tid * 4) = st;
    if (out32) ((float4*)(out32 + (size_t)m * HDdim))[tid] = make_float4(v0, v1, v2, v3);
}

// ---------------- router GEMM: router[b,h,s] = h32[b,s,:] . Wr[:,h] ----------------
__global__ __launch_bounds__(256) void router_kernel(const float* __restrict__ h32, const float* __restrict__ Wr,
                                                     float* __restrict__ router) {
    int m = blockIdx.x;                 // b*S + s
    int tid = threadIdx.x;
    int hh = tid & 15, eg = tid >> 4;
    const float* hr = h32 + (size_t)m * HDdim;
    float sum = 0.0f;
    for (int e = eg; e < HDdim; e += 16) sum += hr[e] * Wr[e * Hdim + hh];
    __shared__ float red[256];
    red[tid] = sum;
    __syncthreads();
    if (tid < 16) {
        float s = 0.0f;
        #pragma unroll
        for (int g = 0; g < 16; g++) s += red[g * 16 + tid];
        router[((size_t)((m >> 10) * Hdim + tid)) * Sdim + (m & 1023)] = s;
    }
}

// ---------------- exact top-k threshold + bias ----------------
__global__ __launch_bounds__(1024) void topk_kernel(const float* __restrict__ router, const float* __restrict__ amask,
                                                    float* __restrict__ biasA) {
    int bh = blockIdx.x;
    int t = threadIdx.x;
    __shared__ float r[1024];
    __shared__ float kths;
    float v = router[(size_t)bh * Sdim + t];
    r[t] = v;
    __syncthreads();
    int gt = 0, eq = 0;
    for (int j = 0; j < 1024; j++) {
        float xv = r[j];
        gt += (xv > v) ? 1 : 0;
        eq += (xv == v) ? 1 : 0;
    }
    if (gt < 512 && gt + eq >= 512) kths = v;
    __syncthreads();
    float kth = kths;
    float bias;
    if (v >= kth) {
        bias = (v >= 0.0f) ? -log1pf(expf(-v)) : (v - log1pf(expf(v)));
    } else {
        bias = -1e9f;
    }
    int b = bh >> 4;
    bias += (1.0f - amask[b * Sdim + t]) * (-1e9f);
    biasA[(size_t)bh * Sdim + t] = bias;
}

// ---------------- MFMA GEMM: C = A(bf16 [M,K]) * B(f32 [K,N]) ----------------
// EPI: 1=QKV(rope->bf16 BHSD), 2=residual add f32, 3=bias+silu->bf16, 4=bias+residual, 5=plain f32
template <int EPI>
__global__ __launch_bounds__(256) void gemm_kernel(
    const unsigned short* __restrict__ A,
    const float* __restrict__ Bq, const float* __restrict__ Bk, const float* __restrict__ Bv,
    float* __restrict__ OF,
    unsigned short* __restrict__ Hq, unsigned short* __restrict__ Hk, unsigned short* __restrict__ Hv,
    const float* __restrict__ bias, const float* __restrict__ cosT, const float* __restrict__ sinT,
    int M, int N, int K) {
    const int z = blockIdx.z;
    const float* Bm = (z == 0) ? Bq : (z == 1) ? Bk : Bv;
    unsigned short* OH = (z == 0) ? Hq : (z == 1) ? Hk : Hv;

    const int bn = blockIdx.x * 128;
    const int bm = blockIdx.y * 128;
    const int tid = threadIdx.x;
    const int lane = tid & 63;
    const int w = tid >> 6;
    const int wr = w >> 1, wc = w & 1;
    const int lg = lane >> 4, lc = lane & 15;

    __shared__ unsigned short As[128][40];
    __shared__ unsigned short Bs[128][40];

    f32x4 acc[4][4];
    f32x4 zero = {0.0f, 0.0f, 0.0f, 0.0f};
    #pragma unroll
    for (int i = 0; i < 4; i++)
        #pragma unroll
        for (int j = 0; j < 4; j++) acc[i][j] = zero;

    const int arow = tid >> 1;
    const int ac0 = (tid & 1) * 16;
    const int bk0 = (tid & 7) * 4;
    const int bn0 = (tid >> 3) * 4;

    for (int kt = 0; kt < K; kt += 32) {
        // A tile: bf16 [128][32] row-major, K-contiguous
        const unsigned short* ag = A + (size_t)(bm + arow) * K + kt + ac0;
        *(bf16x8*)&As[arow][ac0] = *(const bf16x8*)ag;
        *(bf16x8*)&As[arow][ac0 + 8] = *(const bf16x8*)(ag + 8);
        // B tile: f32 [32][128] -> transpose+cvt -> Bs[n][k]
        const float* bg = Bm + (size_t)(kt + bk0) * N + bn + bn0;
        float4 r0 = *(const float4*)bg;
        float4 r1 = *(const float4*)(bg + (size_t)N);
        float4 r2 = *(const float4*)(bg + 2 * (size_t)N);
        float4 r3 = *(const float4*)(bg + 3 * (size_t)N);
        *(short4*)&Bs[bn0 + 0][bk0] = make_short4((short)f2bf(r0.x), (short)f2bf(r1.x), (short)f2bf(r2.x), (short)f2bf(r3.x));
        *(short4*)&Bs[bn0 + 1][bk0] = make_short4((short)f2bf(r0.y), (short)f2bf(r1.y), (short)f2bf(r2.y), (short)f2bf(r3.y));
        *(short4*)&Bs[bn0 + 2][bk0] = make_short4((short)f2bf(r0.z), (short)f2bf(r1.z), (short)f2bf(r2.z), (short)f2bf(r3.z));
        *(short4*)&Bs[bn0 + 3][bk0] = make_short4((short)f2bf(r0.w), (short)f2bf(r1.w), (short)f2bf(r2.w), (short)f2bf(r3.w));
        __syncthreads();

        bf16x8 af[4], bfr[4];
        #pragma unroll
        for (int i = 0; i < 4; i++) af[i] = *(bf16x8*)&As[wr * 64 + i * 16 + lc][lg * 8];
        #pragma unroll
        for (int j = 0; j < 4; j++) bfr[j] = *(bf16x8*)&Bs[wc * 64 + j * 16 + lc][lg * 8];
        #pragma unroll
        for (int i = 0; i < 4; i++)
            #pragma unroll
            for (int j = 0; j < 4; j++) acc[i][j] = MFMA16(af[i], bfr[j], acc[i][j]);
        __syncthreads();
    }

    // epilogue. D layout: row = 4*lg + r, col = lc (within each 16x16 frag)
    #pragma unroll
    for (int i = 0; i < 4; i++) {
        #pragma unroll
        for (int r = 0; r < 4; r++) {
            int row = bm + wr * 64 + i * 16 + lg * 4 + r;
            if (EPI == 1) {
                int b = row >> 10, s = row & 1023;
                if (z == 2) {
                    #pragma unroll
                    for (int j = 0; j < 4; j++) {
                        int col = bn + wc * 64 + j * 16 + lc;
                        int h = col >> 6, d = col & 63;
                        OH[(((size_t)(b * Hdim + h) * Sdim + s) << 6) + d] = f2bf(acc[i][j][r]);
                    }
                } else {
                    #pragma unroll
                    for (int j = 0; j < 2; j++) {
                        int col = bn + wc * 64 + j * 16 + lc;
                        int h = col >> 6, d = col & 63;  // d in [0,32)
                        float x1 = acc[i][j][r];
                        float x2 = acc[i][j + 2][r];
                        float c = cosT[s * 64 + d];
                        float sn = sinT[s * 64 + d];
                        size_t base = ((size_t)(b * Hdim + h) * Sdim + s) << 6;
                        OH[base + d] = f2bf(x1 * c - x2 * sn);
                        OH[base + d + 32] = f2bf(x2 * c + x1 * sn);
                    }
                }
            } else {
                #pragma unroll
                for (int j = 0; j < 4; j++) {
                    int col = bn + wc * 64 + j * 16 + lc;
                    float v = acc[i][j][r];
                    if (EPI == 2) {
                        OF[(size_t)row * N + col] += v;
                    } else if (EPI == 3) {
                        float t = v + bias[col];
                        OH[(size_t)row * N + col] = f2bf(t / (1.0f + expf(-t)));
                    } else if (EPI == 4) {
                        OF[(size_t)row * N + col] += v + bias[col];
                    } else {
                        OF[(size_t)row * N + col] = v;
                    }
                }
            }
        }
    }
}

// ---------------- flash attention (routed bias), S^T orientation ----------------
__global__ __launch_bounds__(256) void attn_kernel(const unsigned short* __restrict__ q16,
                                                   const unsigned short* __restrict__ k16,
                                                   const unsigned short* __restrict__ v16,
                                                   const float* __restrict__ biasA,
                                                   unsigned short* __restrict__ o16) {
    const int qb = blockIdx.x;   // 0..15 (64 q rows each)
    const int bh = blockIdx.y;   // 0..31
    const int tid = threadIdx.x;
    const int w = tid >> 6, lane = tid & 63;
    const int lg = lane >> 4, lc = lane & 15;

    __shared__ unsigned short Kt[64][72];      // [t][d]
    __shared__ unsigned short Vt[64][72];      // [d][t]  (V transposed)
    __shared__ unsigned short Pq[4][16][72];   // per wave: [q][t]
    __shared__ float sb[64];

    const int qrow = qb * 64 + w * 16 + lc;
    const unsigned short* qbase = q16 + ((size_t)bh * Sdim + qrow) * Ddim;
    bf16x8 qf[2];
    qf[0] = *(const bf16x8*)(qbase + lg * 8);
    qf[1] = *(const bf16x8*)(qbase + 32 + lg * 8);

    float m_i = -1e30f, l_i = 0.0f;
    f32x4 ot[4];
    f32x4 zero = {0.0f, 0.0f, 0.0f, 0.0f};
    #pragma unroll
    for (int fd = 0; fd < 4; fd++) ot[fd] = zero;

    const int srow = tid >> 2;
    const int sc0 = (tid & 3) * 16;

    for (int t0 = 0; t0 < Sdim; t0 += 64) {
        const unsigned short* kg = k16 + ((size_t)bh * Sdim + t0 + srow) * Ddim + sc0;
        *(bf16x8*)&Kt[srow][sc0] = *(const bf16x8*)kg;
        *(bf16x8*)&Kt[srow][sc0 + 8] = *(const bf16x8*)(kg + 8);
        const unsigned short* vg = v16 + ((size_t)bh * Sdim + t0 + srow) * Ddim + sc0;
        bf16x8 v0 = *(const bf16x8*)vg;
        bf16x8 v1 = *(const bf16x8*)(vg + 8);
        #pragma unroll
        for (int i2 = 0; i2 < 8; i2++) Vt[sc0 + i2][srow] = (unsigned short)v0[i2];
        #pragma unroll
        for (int i2 = 0; i2 < 8; i2++) Vt[sc0 + 8 + i2][srow] = (unsigned short)v1[i2];
        if (tid < 64) sb[tid] = biasA[(size_t)bh * Sdim + t0 + tid];
        __syncthreads();

        // S^T = K * Q^T ; frag f covers t-local [16f,16f+16)
        f32x4 sf[4];
        #pragma unroll
        for (int f = 0; f < 4; f++) {
            f32x4 a = zero;
            #pragma unroll
            for (int ks = 0; ks < 2; ks++) {
                bf16x8 kfr = *(bf16x8*)&Kt[f * 16 + lc][ks * 32 + lg * 8];
                a = MFMA16(kfr, qf[ks], a);
            }
            sf[f] = a;
        }
        // scale + bias, online softmax (per-lane state for column q = lc)
        float tmax = -1e30f;
        #pragma unroll
        for (int f = 0; f < 4; f++)
            #pragma unroll
            for (int j = 0; j < 4; j++) {
                float v = sf[f][j] * 0.125f + sb[f * 16 + lg * 4 + j];
                sf[f][j] = v;
                tmax = fmaxf(tmax, v);
            }
        tmax = fmaxf(tmax, __shfl_xor(tmax, 16));
        tmax = fmaxf(tmax, __shfl_xor(tmax, 32));
        float mnew = fmaxf(m_i, tmax);
        float alpha = expf(m_i - mnew);
        float lsum = 0.0f;
        #pragma unroll
        for (int f = 0; f < 4; f++)
            #pragma unroll
            for (int j = 0; j < 4; j++) {
                float p = expf(sf[f][j] - mnew);
                sf[f][j] = p;
                lsum += p;
            }
        lsum += __shfl_xor(lsum, 16);
        lsum += __shfl_xor(lsum, 32);
        l_i = l_i * alpha + lsum;
        m_i = mnew;
        #pragma unroll
        for (int fd = 0; fd < 4; fd++)
            #pragma unroll
            for (int j = 0; j < 4; j++) ot[fd][j] *= alpha;
        // P -> LDS (per-wave) in [q][t] layout
        #pragma unroll
        for (int f = 0; f < 4; f++)
            #pragma unroll
            for (int j = 0; j < 4; j++) Pq[w][lc][f * 16 + lg * 4 + j] = f2bf(sf[f][j]);
        // O^T += V^T * P^T
        #pragma unroll
        for (int ks = 0; ks < 2; ks++) {
            bf16x8 pf = *(bf16x8*)&Pq[w][lc][ks * 32 + lg * 8];
            #pragma unroll
            for (int fd = 0; fd < 4; fd++) {
                bf16x8 vfr = *(bf16x8*)&Vt[fd * 16 + lc][ks * 32 + lg * 8];
                ot[fd] = MFMA16(vfr, pf, ot[fd]);
            }
        }
        __syncthreads();
    }
    float rl = 1.0f / l_i;
    int b = bh >> 4, h = bh & 15;
    #pragma unroll
    for (int fd = 0; fd < 4; fd++)
        #pragma unroll
        for (int j = 0; j < 4; j++) {
            int d = fd * 16 + lg * 4 + j;
            o16[((size_t)b * Sdim + qrow) * HDdim + h * 64 + d] = f2bf(ot[fd][j] * rl);
        }
}

extern "C" void kernel_launch(void* const* d_in, const int* in_sizes, int n_in,
                              void* d_out, int out_size, void* d_ws, size_t ws_size,
                              hipStream_t stream) {
    const int* ids = (const int*)d_in[0];
    const float* amask = (const float*)d_in[1];
    const float* emb = (const float*)d_in[2];
    const float* ln1w = (const float*)d_in[3];
    const float* ln1b = (const float*)d_in[4];
    const float* Wq = (const float*)d_in[5];
    const float* Wk = (const float*)d_in[6];
    const float* Wv = (const float*)d_in[7];
    const float* Wo = (const float*)d_in[8];
    const float* Wr = (const float*)d_in[9];
    const float* ln2w = (const float*)d_in[10];
    const float* ln2b = (const float*)d_in[11];
    const float* W1 = (const float*)d_in[12];
    const float* b1 = (const float*)d_in[13];
    const float* W2 = (const float*)d_in[14];
    const float* b2 = (const float*)d_in[15];
    const float* nw = (const float*)d_in[16];
    const float* nb = (const float*)d_in[17];
    const float* lmh = (const float*)d_in[18];
    float* out = (float*)d_out;

    char* p = (char*)d_ws;
    size_t off = 0;
    auto alloc = [&](size_t bytes) -> void* {
        void* r = p + off;
        off += (bytes + 255) & ~(size_t)255;
        return r;
    };
    float* cosT = (float*)alloc((size_t)Sdim * Ddim * 4);
    float* sinT = (float*)alloc((size_t)Sdim * Ddim * 4);
    float* x = (float*)alloc((size_t)BSdim * HDdim * 4);
    float* h32 = (float*)alloc((size_t)BSdim * HDdim * 4);
    unsigned short* h16 = (unsigned short*)alloc((size_t)BSdim * HDdim * 2);
    unsigned short* o16 = (unsigned short*)alloc((size_t)BSdim * HDdim * 2);
    unsigned short* m16 = (unsigned short*)alloc((size_t)BSdim * Idim * 2);
    unsigned short* q16 = (unsigned short*)alloc((size_t)Bdim * Hdim * Sdim * Ddim * 2);
    unsigned short* k16 = (unsigned short*)alloc((size_t)Bdim * Hdim * Sdim * Ddim * 2);
    unsigned short* v16 = (unsigned short*)alloc((size_t)Bdim * Hdim * Sdim * Ddim * 2);
    float* router = (float*)alloc((size_t)Bdim * Hdim * Sdim * 4);
    float* biasA = (float*)alloc((size_t)Bdim * Hdim * Sdim * 4);

    tables_kernel<<<256, 256, 0, stream>>>(cosT, sinT);
    embed_kernel<<<BSdim, 256, 0, stream>>>(ids, emb, x);

    for (int l = 0; l < Ldim; l++) {
        const float* Wq_l = Wq + (size_t)l * HDdim * HDdim;
        const float* Wk_l = Wk + (size_t)l * HDdim * HDdim;
        const float* Wv_l = Wv + (size_t)l * HDdim * HDdim;
        const float* Wo_l = Wo + (size_t)l * HDdim * HDdim;
        const float* Wr_l = Wr + (size_t)l * HDdim * Hdim;
        const float* W1_l = W1 + (size_t)l * HDdim * Idim;
        const float* W2_l = W2 + (size_t)l * Idim * HDdim;
        const float* b1_l = b1 + (size_t)l * Idim;
        const float* b2_l = b2 + (size_t)l * HDdim;

        ln_kernel<<<BSdim, 256, 0, stream>>>(x, ln1w + l * HDdim, ln1b + l * HDdim, h16, h32);
        router_kernel<<<BSdim, 256, 0, stream>>>(h32, Wr_l, router);
        topk_kernel<<<Bdim * Hdim, 1024, 0, stream>>>(router, amask, biasA);
        gemm_kernel<1><<<dim3(8, 16, 3), 256, 0, stream>>>(h16, Wq_l, Wk_l, Wv_l, nullptr, q16, k16, v16,
                                                           nullptr, cosT, sinT, BSdim, HDdim, HDdim);
        attn_kernel<<<dim3(16, 32), 256, 0, stream>>>(q16, k16, v16, biasA, o16);
        gemm_kernel<2><<<dim3(8, 16, 1), 256, 0, stream>>>(o16, Wo_l, Wo_l, Wo_l, x, nullptr, nullptr, nullptr,
                                                           nullptr, nullptr, nullptr, BSdim, HDdim, HDdim);
        ln_kernel<<<BSdim, 256, 0, stream>>>(x, ln2w + l * HDdim, ln2b + l * HDdim, h16, nullptr);
        gemm_kernel<3><<<dim3(32, 16, 1), 256, 0, stream>>>(h16, W1_l, W1_l, W1_l, nullptr, m16, m16, m16,
                                                            b1_l, nullptr, nullptr, BSdim, Idim, HDdim);
        gemm_kernel<4><<<dim3(8, 16, 1), 256, 0, stream>>>(m16, W2_l, W2_l, W2_l, x, nullptr, nullptr, nullptr,
                                                           b2_l, nullptr, nullptr, BSdim, HDdim, Idim);
    }

    ln_kernel<<<BSdim, 256, 0, stream>>>(x, nw, nb, h16, nullptr);
    gemm_kernel<5><<<dim3(250, 16, 1), 256, 0, stream>>>(h16, lmh, lmh, lmh, out, nullptr, nullptr, nullptr,
                                                         nullptr, nullptr, nullptr, BSdim, Vdim, HDdim);
}

// Round 2
// 1406.389 us; speedup vs baseline: 1.5556x; 1.5556x over previous
//
#include <hip/hip_runtime.h>
#include <hip/hip_bf16.h>

#define Bdim 2
#define Sdim 1024
#define Vdim 32000
#define HDdim 1024
#define Ldim 4
#define Hdim 16
#define Ddim 64
#define Idim 4096
#define BSdim 2048

typedef __attribute__((ext_vector_type(8))) short bf16x8;
typedef __attribute__((ext_vector_type(4))) float f32x4;

__device__ __forceinline__ unsigned short f2bf(float f) {
    __hip_bfloat16 h = __float2bfloat16(f);
    return *reinterpret_cast<unsigned short*>(&h);
}

#define MFMA16(a, b, c) __builtin_amdgcn_mfma_f32_16x16x32_bf16((a), (b), (c), 0, 0, 0)

#define GLD16(gp, lp)                                                            \
    __builtin_amdgcn_global_load_lds((const __attribute__((address_space(1))) void*)(gp), \
                                     (__attribute__((address_space(3))) void*)(lp), 16, 0, 0)

// ---------------- rope tables ----------------
__global__ __launch_bounds__(256) void tables_kernel(float* __restrict__ cosT, float* __restrict__ sinT) {
    int i = blockIdx.x * 256 + threadIdx.x;   // 65536 = S*D
    int d = i & 63;
    int s = i >> 6;
    float inv = powf(1.0e6f, -((float)(2 * (d & 31))) / 64.0f);
    float f = (float)s * inv;
    cosT[i] = cosf(f);
    sinT[i] = sinf(f);
}

// ---------------- embedding gather ----------------
__global__ __launch_bounds__(256) void embed_kernel(const int* __restrict__ ids, const float* __restrict__ emb,
                                                    float* __restrict__ x) {
    int m = blockIdx.x;
    int tid = threadIdx.x;
    int id = ids[m];
    const float4* src = (const float4*)(emb + (size_t)id * HDdim);
    ((float4*)(x + (size_t)m * HDdim))[tid] = src[tid];
}

// ---------------- layernorm -> bf16 (+ optional f32 copy) ----------------
__global__ __launch_bounds__(256) void ln_kernel(const float* __restrict__ x, const float* __restrict__ w,
                                                 const float* __restrict__ bw, unsigned short* __restrict__ outH,
                                                 float* __restrict__ out32) {
    int m = blockIdx.x;
    int tid = threadIdx.x;
    float4 a = ((const float4*)(x + (size_t)m * HDdim))[tid];
    float s = a.x + a.y + a.z + a.w;
    #pragma unroll
    for (int o = 1; o < 64; o <<= 1) s += __shfl_xor(s, o);
    __shared__ float red[4], red2[4];
    if ((tid & 63) == 0) red[tid >> 6] = s;
    __syncthreads();
    float mean = (red[0] + red[1] + red[2] + red[3]) * (1.0f / 1024.0f);
    float dx = a.x - mean, dy = a.y - mean, dz = a.z - mean, dw = a.w - mean;
    float s2 = dx * dx + dy * dy + dz * dz + dw * dw;
    #pragma unroll
    for (int o = 1; o < 64; o <<= 1) s2 += __shfl_xor(s2, o);
    if ((tid & 63) == 0) red2[tid >> 6] = s2;
    __syncthreads();
    float var = (red2[0] + red2[1] + red2[2] + red2[3]) * (1.0f / 1024.0f);
    float rs = rsqrtf(var + 1e-6f);
    float4 wv = ((const float4*)w)[tid];
    float4 bv = ((const float4*)bw)[tid];
    float v0 = dx * rs * wv.x + bv.x;
    float v1 = dy * rs * wv.y + bv.y;
    float v2 = dz * rs * wv.z + bv.z;
    float v3 = dw * rs * wv.w + bv.w;
    short4 st = make_short4((short)f2bf(v0), (short)f2bf(v1), (short)f2bf(v2), (short)f2bf(v3));
    *(short4*)(outH + (size_t)m * HDdim + tid * 4) = st;
    if (out32) ((float4*)(out32 + (size_t)m * HDdim))[tid] = make_float4(v0, v1, v2, v3);
}

// ---------------- router GEMM: router[b,h,s] = h32[b,s,:] . Wr[:,h] ----------------
__global__ __launch_bounds__(256) void router_kernel(const float* __restrict__ h32, const float* __restrict__ Wr,
                                                     float* __restrict__ router) {
    int m = blockIdx.x;                 // b*S + s
    int tid = threadIdx.x;
    int hh = tid & 15, eg = tid >> 4;
    const float* hr = h32 + (size_t)m * HDdim;
    float sum = 0.0f;
    for (int e = eg; e < HDdim; e += 16) sum += hr[e] * Wr[e * Hdim + hh];
    __shared__ float red[256];
    red[tid] = sum;
    __syncthreads();
    if (tid < 16) {
        float s = 0.0f;
        #pragma unroll
        for (int g = 0; g < 16; g++) s += red[g * 16 + tid];
        router[((size_t)((m >> 10) * Hdim + tid)) * Sdim + (m & 1023)] = s;
    }
}

// ---------------- exact top-k threshold + bias ----------------
__global__ __launch_bounds__(1024) void topk_kernel(const float* __restrict__ router, const float* __restrict__ amask,
                                                    float* __restrict__ biasA) {
    int bh = blockIdx.x;
    int t = threadIdx.x;
    __shared__ float r[1024];
    __shared__ float kths;
    float v = router[(size_t)bh * Sdim + t];
    r[t] = v;
    __syncthreads();
    int gt = 0, eq = 0;
    for (int j = 0; j < 1024; j++) {
        float xv = r[j];
        gt += (xv > v) ? 1 : 0;
        eq += (xv == v) ? 1 : 0;
    }
    if (gt < 512 && gt + eq >= 512) kths = v;
    __syncthreads();
    float kth = kths;
    float bias;
    if (v >= kth) {
        bias = (v >= 0.0f) ? -log1pf(expf(-v)) : (v - log1pf(expf(v)));
    } else {
        bias = -1e9f;
    }
    int b = bh >> 4;
    bias += (1.0f - amask[b * Sdim + t]) * (-1e9f);
    biasA[(size_t)bh * Sdim + t] = bias;
}

// ---------------- transpose + f32->bf16 convert: S [K][N] f32 -> D [N][K] bf16 ----------------
__global__ __launch_bounds__(256) void tconv_kernel(const float* __restrict__ S0, const float* __restrict__ S1,
                                                    const float* __restrict__ S2, const float* __restrict__ S3,
                                                    unsigned short* __restrict__ D, int K, int ldS, size_t dstride) {
    const float* S = (blockIdx.z == 0) ? S0 : (blockIdx.z == 1) ? S1 : (blockIdx.z == 2) ? S2 : S3;
    unsigned short* dz = D + (size_t)blockIdx.z * dstride;
    __shared__ float t[32][33];
    int kt = blockIdx.y * 32, nt = blockIdx.x * 32;
    int r = threadIdx.x >> 3, c4 = (threadIdx.x & 7) * 4;
    float4 v = *(const float4*)(S + (size_t)(kt + r) * ldS + nt + c4);
    t[r][c4] = v.x; t[r][c4 + 1] = v.y; t[r][c4 + 2] = v.z; t[r][c4 + 3] = v.w;
    __syncthreads();
    short4 o = make_short4((short)f2bf(t[c4][r]), (short)f2bf(t[c4 + 1][r]),
                           (short)f2bf(t[c4 + 2][r]), (short)f2bf(t[c4 + 3][r]));
    *(short4*)(dz + (size_t)(nt + r) * K + kt + c4) = o;
}

// ---------------- MFMA GEMM: C = A(bf16 [M,K]) * Bt(bf16 [N,K])^T ----------------
// EPI: 1=QKV(rope->bf16 BHSD), 2=residual add f32, 3=bias+silu->bf16, 4=bias+residual, 5=plain f32
template <int EPI, int BN>
__global__ __launch_bounds__(256) void gemm_bt(
    const unsigned short* __restrict__ A,
    const unsigned short* __restrict__ Bt0, size_t strideB,
    float* __restrict__ OF,
    unsigned short* __restrict__ Hq, unsigned short* __restrict__ Hk, unsigned short* __restrict__ Hv,
    const float* __restrict__ bias, const float* __restrict__ cosT, const float* __restrict__ sinT,
    int M, int N, int K, int ldC) {
    const int z = blockIdx.z;
    const unsigned short* Bt = Bt0 + (size_t)z * strideB;
    unsigned short* OH = (EPI == 1) ? ((z == 0) ? Hq : (z == 1) ? Hk : Hv) : Hq;

    const int bn = blockIdx.x * BN;
    const int bm = blockIdx.y * 128;
    const int tid = threadIdx.x;
    const int lane = tid & 63;
    const int w = tid >> 6;
    constexpr int NWC = (BN == 128) ? 2 : 1;   // wave cols
    constexpr int MI = (BN == 128) ? 4 : 2;    // M frags per wave
    const int wr = w / NWC, wc = w % NWC;
    const int lg = lane >> 4, lc = lane & 15;

    __shared__ unsigned short As[128 * 32];
    __shared__ unsigned short Bs[BN * 32];

    f32x4 acc[MI][4];
    f32x4 zero = {0.0f, 0.0f, 0.0f, 0.0f};
    #pragma unroll
    for (int i = 0; i < MI; i++)
        #pragma unroll
        for (int j = 0; j < 4; j++) acc[i][j] = zero;

    const int srow = tid >> 2;          // 0..63
    const int scol = (tid & 3) * 8;     // element offset (16B chunks)

    for (int kt = 0; kt < K; kt += 32) {
        const unsigned short* ag = A + (size_t)(bm + srow) * K + kt + scol;
        GLD16(ag, &As[tid * 8]);
        GLD16(ag + (size_t)64 * K, &As[2048 + tid * 8]);
        const unsigned short* bg = Bt + (size_t)(bn + srow) * K + kt + scol;
        GLD16(bg, &Bs[tid * 8]);
        if (BN == 128) GLD16(bg + (size_t)64 * K, &Bs[2048 + tid * 8]);
        __syncthreads();

        bf16x8 af[MI], bfr[4];
        #pragma unroll
        for (int i = 0; i < MI; i++) af[i] = *(bf16x8*)&As[(wr * (MI * 16) + i * 16 + lc) * 32 + lg * 8];
        #pragma unroll
        for (int j = 0; j < 4; j++) bfr[j] = *(bf16x8*)&Bs[(wc * 64 + j * 16 + lc) * 32 + lg * 8];
        #pragma unroll
        for (int i = 0; i < MI; i++)
            #pragma unroll
            for (int j = 0; j < 4; j++) acc[i][j] = MFMA16(af[i], bfr[j], acc[i][j]);
        __syncthreads();
    }

    // epilogue. D frag layout: row = lg*4 + r, col = lc
    #pragma unroll
    for (int i = 0; i < MI; i++) {
        #pragma unroll
        for (int r = 0; r < 4; r++) {
            int row = bm + wr * (MI * 16) + i * 16 + lg * 4 + r;
            if (EPI == 1) {
                int b = row >> 10, s = row & 1023;
                if (z == 2) {
                    #pragma unroll
                    for (int j = 0; j < 4; j++) {
                        int col = bn + wc * 64 + j * 16 + lc;
                        int h = col >> 6, d = col & 63;
                        OH[(((size_t)(b * Hdim + h) * Sdim + s) << 6) + d] = f2bf(acc[i][j][r]);
                    }
                } else {
                    #pragma unroll
                    for (int j = 0; j < 2; j++) {
                        int col = bn + wc * 64 + j * 16 + lc;
                        int h = col >> 6, d = col & 63;  // d in [0,32)
                        float x1 = acc[i][j][r];
                        float x2 = acc[i][j + 2][r];
                        float c = cosT[s * 64 + d];
                        float sn = sinT[s * 64 + d];
                        size_t base = ((size_t)(b * Hdim + h) * Sdim + s) << 6;
                        OH[base + d] = f2bf(x1 * c - x2 * sn);
                        OH[base + d + 32] = f2bf(x2 * c + x1 * sn);
                    }
                }
            } else {
                #pragma unroll
                for (int j = 0; j < 4; j++) {
                    int col = bn + wc * 64 + j * 16 + lc;
                    float v = acc[i][j][r];
                    if (EPI == 2) {
                        OF[(size_t)row * ldC + col] += v;
                    } else if (EPI == 3) {
                        float t = v + bias[col];
                        OH[(size_t)row * ldC + col] = f2bf(t / (1.0f + expf(-t)));
                    } else if (EPI == 4) {
                        OF[(size_t)row * ldC + col] += v + bias[col];
                    } else {
                        OF[(size_t)row * ldC + col] = v;
                    }
                }
            }
        }
    }
}

// ---------------- flash attention (routed bias), S^T orientation ----------------
__global__ __launch_bounds__(256) void attn_kernel(const unsigned short* __restrict__ q16,
                                                   const unsigned short* __restrict__ k16,
                                                   const unsigned short* __restrict__ v16,
                                                   const float* __restrict__ biasA,
                                                   unsigned short* __restrict__ o16) {
    const int qb = blockIdx.x;   // 0..15 (64 q rows each)
    const int bh = blockIdx.y;   // 0..31
    const int tid = threadIdx.x;
    const int w = tid >> 6, lane = tid & 63;
    const int lg = lane >> 4, lc = lane & 15;

    __shared__ unsigned short Kt[64][72];      // [t][d]
    __shared__ unsigned short Vt[64][72];      // [d][t]  (V transposed)
    __shared__ unsigned short Pq[4][16][72];   // per wave: [q][t]
    __shared__ float sb[64];

    const int qrow = qb * 64 + w * 16 + lc;
    const unsigned short* qbase = q16 + ((size_t)bh * Sdim + qrow) * Ddim;
    bf16x8 qf[2];
    qf[0] = *(const bf16x8*)(qbase + lg * 8);
    qf[1] = *(const bf16x8*)(qbase + 32 + lg * 8);

    float m_i = -1e30f, l_i = 0.0f;
    f32x4 ot[4];
    f32x4 zero = {0.0f, 0.0f, 0.0f, 0.0f};
    #pragma unroll
    for (int fd = 0; fd < 4; fd++) ot[fd] = zero;

    const int srow = tid >> 2;
    const int sc0 = (tid & 3) * 16;

    for (int t0 = 0; t0 < Sdim; t0 += 64) {
        const unsigned short* kg = k16 + ((size_t)bh * Sdim + t0 + srow) * Ddim + sc0;
        *(bf16x8*)&Kt[srow][sc0] = *(const bf16x8*)kg;
        *(bf16x8*)&Kt[srow][sc0 + 8] = *(const bf16x8*)(kg + 8);
        const unsigned short* vg = v16 + ((size_t)bh * Sdim + t0 + srow) * Ddim + sc0;
        bf16x8 v0 = *(const bf16x8*)vg;
        bf16x8 v1 = *(const bf16x8*)(vg + 8);
        #pragma unroll
        for (int i2 = 0; i2 < 8; i2++) Vt[sc0 + i2][srow] = (unsigned short)v0[i2];
        #pragma unroll
        for (int i2 = 0; i2 < 8; i2++) Vt[sc0 + 8 + i2][srow] = (unsigned short)v1[i2];
        if (tid < 64) sb[tid] = biasA[(size_t)bh * Sdim + t0 + tid];
        __syncthreads();

        // S^T = K * Q^T ; frag f covers t-local [16f,16f+16)
        f32x4 sf[4];
        #pragma unroll
        for (int f = 0; f < 4; f++) {
            f32x4 a = zero;
            #pragma unroll
            for (int ks = 0; ks < 2; ks++) {
                bf16x8 kfr = *(bf16x8*)&Kt[f * 16 + lc][ks * 32 + lg * 8];
                a = MFMA16(kfr, qf[ks], a);
            }
            sf[f] = a;
        }
        // scale + bias, online softmax (per-lane state for column q = lc)
        float tmax = -1e30f;
        #pragma unroll
        for (int f = 0; f < 4; f++)
            #pragma unroll
            for (int j = 0; j < 4; j++) {
                float v = sf[f][j] * 0.125f + sb[f * 16 + lg * 4 + j];
                sf[f][j] = v;
                tmax = fmaxf(tmax, v);
            }
        tmax = fmaxf(tmax, __shfl_xor(tmax, 16));
        tmax = fmaxf(tmax, __shfl_xor(tmax, 32));
        float mnew = fmaxf(m_i, tmax);
        float alpha = expf(m_i - mnew);
        float lsum = 0.0f;
        #pragma unroll
        for (int f = 0; f < 4; f++)
            #pragma unroll
            for (int j = 0; j < 4; j++) {
                float p = expf(sf[f][j] - mnew);
                sf[f][j] = p;
                lsum += p;
            }
        lsum += __shfl_xor(lsum, 16);
        lsum += __shfl_xor(lsum, 32);
        l_i = l_i * alpha + lsum;
        m_i = mnew;
        #pragma unroll
        for (int fd = 0; fd < 4; fd++)
            #pragma unroll
            for (int j = 0; j < 4; j++) ot[fd][j] *= alpha;
        // P -> LDS (per-wave) in [q][t] layout
        #pragma unroll
        for (int f = 0; f < 4; f++)
            #pragma unroll
            for (int j = 0; j < 4; j++) Pq[w][lc][f * 16 + lg * 4 + j] = f2bf(sf[f][j]);
        // O^T += V^T * P^T
        #pragma unroll
        for (int ks = 0; ks < 2; ks++) {
            bf16x8 pf = *(bf16x8*)&Pq[w][lc][ks * 32 + lg * 8];
            #pragma unroll
            for (int fd = 0; fd < 4; fd++) {
                bf16x8 vfr = *(bf16x8*)&Vt[fd * 16 + lc][ks * 32 + lg * 8];
                ot[fd] = MFMA16(vfr, pf, ot[fd]);
            }
        }
        __syncthreads();
    }
    float rl = 1.0f / l_i;
    int b = bh >> 4, h = bh & 15;
    #pragma unroll
    for (int fd = 0; fd < 4; fd++)
        #pragma unroll
        for (int j = 0; j < 4; j++) {
            int d = fd * 16 + lg * 4 + j;
            o16[((size_t)b * Sdim + qrow) * HDdim + h * 64 + d] = f2bf(ot[fd][j] * rl);
        }
}

extern "C" void kernel_launch(void* const* d_in, const int* in_sizes, int n_in,
                              void* d_out, int out_size, void* d_ws, size_t ws_size,
                              hipStream_t stream) {
    const int* ids = (const int*)d_in[0];
    const float* amask = (const float*)d_in[1];
    const float* emb = (const float*)d_in[2];
    const float* ln1w = (const float*)d_in[3];
    const float* ln1b = (const float*)d_in[4];
    const float* Wq = (const float*)d_in[5];
    const float* Wk = (const float*)d_in[6];
    const float* Wv = (const float*)d_in[7];
    const float* Wo = (const float*)d_in[8];
    const float* Wr = (const float*)d_in[9];
    const float* ln2w = (const float*)d_in[10];
    const float* ln2b = (const float*)d_in[11];
    const float* W1 = (const float*)d_in[12];
    const float* b1 = (const float*)d_in[13];
    const float* W2 = (const float*)d_in[14];
    const float* b2 = (const float*)d_in[15];
    const float* nw = (const float*)d_in[16];
    const float* nb = (const float*)d_in[17];
    const float* lmh = (const float*)d_in[18];
    float* out = (float*)d_out;

    char* p = (char*)d_ws;
    size_t off = 0;
    auto alloc = [&](size_t bytes) -> void* {
        void* r = p + off;
        off += (bytes + 255) & ~(size_t)255;
        return r;
    };
    float* cosT = (float*)alloc((size_t)Sdim * Ddim * 4);
    float* sinT = (float*)alloc((size_t)Sdim * Ddim * 4);
    float* x = (float*)alloc((size_t)BSdim * HDdim * 4);
    float* h32 = (float*)alloc((size_t)BSdim * HDdim * 4);
    unsigned short* h16 = (unsigned short*)alloc((size_t)BSdim * HDdim * 2);
    unsigned short* o16 = (unsigned short*)alloc((size_t)BSdim * HDdim * 2);
    unsigned short* m16 = (unsigned short*)alloc((size_t)BSdim * Idim * 2);
    unsigned short* q16 = (unsigned short*)alloc((size_t)Bdim * Hdim * Sdim * Ddim * 2);
    unsigned short* k16 = (unsigned short*)alloc((size_t)Bdim * Hdim * Sdim * Ddim * 2);
    unsigned short* v16 = (unsigned short*)alloc((size_t)Bdim * Hdim * Sdim * Ddim * 2);
    float* router = (float*)alloc((size_t)Bdim * Hdim * Sdim * 4);
    float* biasA = (float*)alloc((size_t)Bdim * Hdim * Sdim * 4);
    unsigned short* wts = (unsigned short*)alloc((size_t)16000 * 1024 * 2 * 2);  // 16M elems (32MB) reuse buffer

    const size_t M1 = 1u << 20;  // 1M elems

    tables_kernel<<<256, 256, 0, stream>>>(cosT, sinT);
    embed_kernel<<<BSdim, 256, 0, stream>>>(ids, emb, x);

    for (int l = 0; l < Ldim; l++) {
        const float* Wq_l = Wq + (size_t)l * HDdim * HDdim;
        const float* Wk_l = Wk + (size_t)l * HDdim * HDdim;
        const float* Wv_l = Wv + (size_t)l * HDdim * HDdim;
        const float* Wo_l = Wo + (size_t)l * HDdim * HDdim;
        const float* Wr_l = Wr + (size_t)l * HDdim * Hdim;
        const float* W1_l = W1 + (size_t)l * HDdim * Idim;
        const float* W2_l = W2 + (size_t)l * Idim * HDdim;
        const float* b1_l = b1 + (size_t)l * Idim;
        const float* b2_l = b2 + (size_t)l * HDdim;

        // weight prepass: QKVO -> wts[0..4M), W1t -> wts[4M..8M), W2t -> wts[8M..12M)
        tconv_kernel<<<dim3(32, 32, 4), 256, 0, stream>>>(Wq_l, Wk_l, Wv_l, Wo_l, wts, HDdim, HDdim, M1);
        tconv_kernel<<<dim3(128, 32, 1), 256, 0, stream>>>(W1_l, W1_l, W1_l, W1_l, wts + 4 * M1, HDdim, Idim, 0);
        tconv_kernel<<<dim3(32, 128, 1), 256, 0, stream>>>(W2_l, W2_l, W2_l, W2_l, wts + 8 * M1, Idim, HDdim, 0);

        ln_kernel<<<BSdim, 256, 0, stream>>>(x, ln1w + l * HDdim, ln1b + l * HDdim, h16, h32);
        router_kernel<<<BSdim, 256, 0, stream>>>(h32, Wr_l, router);
        topk_kernel<<<Bdim * Hdim, 1024, 0, stream>>>(router, amask, biasA);
        gemm_bt<1, 128><<<dim3(8, 16, 3), 256, 0, stream>>>(h16, wts, M1, nullptr, q16, k16, v16,
                                                            nullptr, cosT, sinT, BSdim, HDdim, HDdim, HDdim);
        attn_kernel<<<dim3(16, 32), 256, 0, stream>>>(q16, k16, v16, biasA, o16);
        gemm_bt<2, 64><<<dim3(16, 16, 1), 256, 0, stream>>>(o16, wts + 3 * M1, 0, x, nullptr, nullptr, nullptr,
                                                            nullptr, nullptr, nullptr, BSdim, HDdim, HDdim, HDdim);
        ln_kernel<<<BSdim, 256, 0, stream>>>(x, ln2w + l * HDdim, ln2b + l * HDdim, h16, nullptr);
        gemm_bt<3, 128><<<dim3(32, 16, 1), 256, 0, stream>>>(h16, wts + 4 * M1, 0, nullptr, m16, m16, m16,
                                                             b1_l, nullptr, nullptr, BSdim, Idim, HDdim, Idim);
        gemm_bt<4, 64><<<dim3(16, 16, 1), 256, 0, stream>>>(m16, wts + 8 * M1, 0, x, nullptr, nullptr, nullptr,
                                                            b2_l, nullptr, nullptr, BSdim, HDdim, Idim, HDdim);
    }

    ln_kernel<<<BSdim, 256, 0, stream>>>(x, nw, nb, h16, nullptr);
    // lm_head in two 16000-column chunks: convert chunk -> wts, then GEMM into out columns
    for (int c = 0; c < 2; c++) {
        int c0 = c * 16000;
        tconv_kernel<<<dim3(500, 32, 1), 256, 0, stream>>>(lmh + c0, lmh + c0, lmh + c0, lmh + c0,
                                                           wts, HDdim, Vdim, 0);
        gemm_bt<5, 128><<<dim3(125, 16, 1), 256, 0, stream>>>(h16, wts, 0, out + c0, nullptr, nullptr, nullptr,
                                                              nullptr, nullptr, nullptr, BSdim, 16000, HDdim, Vdim);
    }
}

// Round 3
// 1381.402 us; speedup vs baseline: 1.5837x; 1.0181x over previous
//
#include <hip/hip_runtime.h>
#include <hip/hip_bf16.h>

#define Bdim 2
#define Sdim 1024
#define Vdim 32000
#define HDdim 1024
#define Ldim 4
#define Hdim 16
#define Ddim 64
#define Idim 4096
#define BSdim 2048

typedef __attribute__((ext_vector_type(8))) short bf16x8;
typedef __attribute__((ext_vector_type(4))) float f32x4;

__device__ __forceinline__ unsigned short f2bf(float f) {
    __hip_bfloat16 h = __float2bfloat16(f);
    return *reinterpret_cast<unsigned short*>(&h);
}

#define MFMA16(a, b, c) __builtin_amdgcn_mfma_f32_16x16x32_bf16((a), (b), (c), 0, 0, 0)

#define GLD16(gp, lp)                                                            \
    __builtin_amdgcn_global_load_lds((const __attribute__((address_space(1))) void*)(gp), \
                                     (__attribute__((address_space(3))) void*)(lp), 16, 0, 0)

// ---------------- rope tables ----------------
__global__ __launch_bounds__(256) void tables_kernel(float* __restrict__ cosT, float* __restrict__ sinT) {
    int i = blockIdx.x * 256 + threadIdx.x;   // 65536 = S*D
    int d = i & 63;
    int s = i >> 6;
    float inv = powf(1.0e6f, -((float)(2 * (d & 31))) / 64.0f);
    float f = (float)s * inv;
    cosT[i] = cosf(f);
    sinT[i] = sinf(f);
}

// ---------------- embedding gather ----------------
__global__ __launch_bounds__(256) void embed_kernel(const int* __restrict__ ids, const float* __restrict__ emb,
                                                    float* __restrict__ x) {
    int m = blockIdx.x;
    int tid = threadIdx.x;
    int id = ids[m];
    const float4* src = (const float4*)(emb + (size_t)id * HDdim);
    ((float4*)(x + (size_t)m * HDdim))[tid] = src[tid];
}

// ---------------- layernorm -> bf16 (+ optional f32 copy) ----------------
__global__ __launch_bounds__(256) void ln_kernel(const float* __restrict__ x, const float* __restrict__ w,
                                                 const float* __restrict__ bw, unsigned short* __restrict__ outH,
                                                 float* __restrict__ out32) {
    int m = blockIdx.x;
    int tid = threadIdx.x;
    float4 a = ((const float4*)(x + (size_t)m * HDdim))[tid];
    float s = a.x + a.y + a.z + a.w;
    #pragma unroll
    for (int o = 1; o < 64; o <<= 1) s += __shfl_xor(s, o);
    __shared__ float red[4], red2[4];
    if ((tid & 63) == 0) red[tid >> 6] = s;
    __syncthreads();
    float mean = (red[0] + red[1] + red[2] + red[3]) * (1.0f / 1024.0f);
    float dx = a.x - mean, dy = a.y - mean, dz = a.z - mean, dw = a.w - mean;
    float s2 = dx * dx + dy * dy + dz * dz + dw * dw;
    #pragma unroll
    for (int o = 1; o < 64; o <<= 1) s2 += __shfl_xor(s2, o);
    if ((tid & 63) == 0) red2[tid >> 6] = s2;
    __syncthreads();
    float var = (red2[0] + red2[1] + red2[2] + red2[3]) * (1.0f / 1024.0f);
    float rs = rsqrtf(var + 1e-6f);
    float4 wv = ((const float4*)w)[tid];
    float4 bv = ((const float4*)bw)[tid];
    float v0 = dx * rs * wv.x + bv.x;
    float v1 = dy * rs * wv.y + bv.y;
    float v2 = dz * rs * wv.z + bv.z;
    float v3 = dw * rs * wv.w + bv.w;
    short4 st = make_short4((short)f2bf(v0), (short)f2bf(v1), (short)f2bf(v2), (short)f2bf(v3));
    *(short4*)(outH + (size_t)m * HDdim + tid * 4) = st;
    if (out32) ((float4*)(out32 + (size_t)m * HDdim))[tid] = make_float4(v0, v1, v2, v3);
}

// ---------------- router GEMM: router[b,h,s] = h32[b,s,:] . Wr[:,h] ----------------
__global__ __launch_bounds__(256) void router_kernel(const float* __restrict__ h32, const float* __restrict__ Wr,
                                                     float* __restrict__ router) {
    int m = blockIdx.x;                 // b*S + s
    int tid = threadIdx.x;
    int hh = tid & 15, eg = tid >> 4;
    const float* hr = h32 + (size_t)m * HDdim;
    float sum = 0.0f;
    for (int e = eg; e < HDdim; e += 16) sum += hr[e] * Wr[e * Hdim + hh];
    __shared__ float red[256];
    red[tid] = sum;
    __syncthreads();
    if (tid < 16) {
        float s = 0.0f;
        #pragma unroll
        for (int g = 0; g < 16; g++) s += red[g * 16 + tid];
        router[((size_t)((m >> 10) * Hdim + tid)) * Sdim + (m & 1023)] = s;
    }
}

// ---------------- exact top-k threshold + bias ----------------
__global__ __launch_bounds__(1024) void topk_kernel(const float* __restrict__ router, const float* __restrict__ amask,
                                                    float* __restrict__ biasA) {
    int bh = blockIdx.x;
    int t = threadIdx.x;
    __shared__ float r[1024];
    __shared__ float kths;
    float v = router[(size_t)bh * Sdim + t];
    r[t] = v;
    __syncthreads();
    int gt = 0, eq = 0;
    for (int j = 0; j < 1024; j++) {
        float xv = r[j];
        gt += (xv > v) ? 1 : 0;
        eq += (xv == v) ? 1 : 0;
    }
    if (gt < 512 && gt + eq >= 512) kths = v;
    __syncthreads();
    float kth = kths;
    float bias;
    if (v >= kth) {
        bias = (v >= 0.0f) ? -log1pf(expf(-v)) : (v - log1pf(expf(v)));
    } else {
        bias = -1e9f;
    }
    int b = bh >> 4;
    bias += (1.0f - amask[b * Sdim + t]) * (-1e9f);
    biasA[(size_t)bh * Sdim + t] = bias;
}

// ---------------- transpose + f32->bf16 convert: S [K][N] f32 -> D [N][K] bf16 ----------------
__global__ __launch_bounds__(256) void tconv_kernel(const float* __restrict__ S0, const float* __restrict__ S1,
                                                    const float* __restrict__ S2, const float* __restrict__ S3,
                                                    unsigned short* __restrict__ D, int K, int ldS, size_t dstride) {
    const float* S = (blockIdx.z == 0) ? S0 : (blockIdx.z == 1) ? S1 : (blockIdx.z == 2) ? S2 : S3;
    unsigned short* dz = D + (size_t)blockIdx.z * dstride;
    __shared__ float t[32][33];
    int kt = blockIdx.y * 32, nt = blockIdx.x * 32;
    int r = threadIdx.x >> 3, c4 = (threadIdx.x & 7) * 4;
    float4 v = *(const float4*)(S + (size_t)(kt + r) * ldS + nt + c4);
    t[r][c4] = v.x; t[r][c4 + 1] = v.y; t[r][c4 + 2] = v.z; t[r][c4 + 3] = v.w;
    __syncthreads();
    short4 o = make_short4((short)f2bf(t[c4][r]), (short)f2bf(t[c4 + 1][r]),
                           (short)f2bf(t[c4 + 2][r]), (short)f2bf(t[c4 + 3][r]));
    *(short4*)(dz + (size_t)(nt + r) * K + kt + c4) = o;
}

// ---------------- V transpose: v16 [bh][t][d] -> vT [bh][d][t] with XOR swizzle baked in ----------------
__global__ __launch_bounds__(256) void vtrans_kernel(const unsigned short* __restrict__ v16,
                                                     unsigned short* __restrict__ vT) {
    int t0 = blockIdx.x * 64;   // 16 tiles
    int bh = blockIdx.y;        // 32
    __shared__ unsigned short T[64][72];
    int r = threadIdx.x >> 2;
    int c0 = (threadIdx.x & 3) * 16;
    const unsigned short* src = v16 + ((size_t)bh * Sdim + t0 + r) * Ddim + c0;
    *(bf16x8*)&T[r][c0] = *(const bf16x8*)src;
    *(bf16x8*)&T[r][c0 + 8] = *(const bf16x8*)(src + 8);
    __syncthreads();
    int d = threadIdx.x >> 2;
    int xr = (d & 7) << 3;
    unsigned short* dst = vT + ((size_t)bh * Ddim + d) * Sdim + t0;
    #pragma unroll
    for (int cc = 0; cc < 2; cc++) {
        int tb = (threadIdx.x & 3) * 16 + cc * 8;
        bf16x8 o;
        #pragma unroll
        for (int i = 0; i < 8; i++) o[i] = (short)T[tb + i][d];
        *(bf16x8*)(dst + (tb ^ xr)) = o;
    }
}

// ---------------- MFMA GEMM: C = A(bf16 [M,K]) * Bt(bf16 [N,K])^T ----------------
// grid: x = M/128 tiles (consecutive blocks share the B panel), y = N/BN tiles
// EPI: 1=fused QKV (rope->bf16, K swizzled), 2=residual add f32, 3=bias+silu->bf16, 4=bias+residual, 5=plain f32
template <int EPI, int BN>
__global__ __launch_bounds__(256) void gemm_bt(
    const unsigned short* __restrict__ A,
    const unsigned short* __restrict__ Bt,
    float* __restrict__ OF,
    unsigned short* __restrict__ Hq, unsigned short* __restrict__ Hk, unsigned short* __restrict__ Hv,
    const float* __restrict__ bias, const float* __restrict__ cosT, const float* __restrict__ sinT,
    int K, int ldC) {
    const int bm = blockIdx.x * 128;
    const int bn = blockIdx.y * BN;
    const int tid = threadIdx.x;
    const int lane = tid & 63;
    const int w = tid >> 6;
    constexpr int NWC = (BN == 128) ? 2 : 1;   // wave cols
    constexpr int MI = (BN == 128) ? 4 : 2;    // M frags per wave
    const int wr = w / NWC, wc = w % NWC;
    const int lg = lane >> 4, lc = lane & 15;

    __shared__ unsigned short As[128 * 32];
    __shared__ unsigned short Bs[BN * 32];

    f32x4 acc[MI][4];
    f32x4 zero = {0.0f, 0.0f, 0.0f, 0.0f};
    #pragma unroll
    for (int i = 0; i < MI; i++)
        #pragma unroll
        for (int j = 0; j < 4; j++) acc[i][j] = zero;

    const int srow = tid >> 2;          // 0..63
    const int scol = (tid & 3) * 8;     // element offset (16B chunks)

    for (int kt = 0; kt < K; kt += 32) {
        const unsigned short* ag = A + (size_t)(bm + srow) * K + kt + scol;
        GLD16(ag, &As[tid * 8]);
        GLD16(ag + (size_t)64 * K, &As[2048 + tid * 8]);
        const unsigned short* bg = Bt + (size_t)(bn + srow) * K + kt + scol;
        GLD16(bg, &Bs[tid * 8]);
        if (BN == 128) GLD16(bg + (size_t)64 * K, &Bs[2048 + tid * 8]);
        __syncthreads();

        bf16x8 af[MI], bfr[4];
        #pragma unroll
        for (int i = 0; i < MI; i++) af[i] = *(bf16x8*)&As[(wr * (MI * 16) + i * 16 + lc) * 32 + lg * 8];
        #pragma unroll
        for (int j = 0; j < 4; j++) bfr[j] = *(bf16x8*)&Bs[(wc * 64 + j * 16 + lc) * 32 + lg * 8];
        #pragma unroll
        for (int i = 0; i < MI; i++)
            #pragma unroll
            for (int j = 0; j < 4; j++) acc[i][j] = MFMA16(af[i], bfr[j], acc[i][j]);
        __syncthreads();
    }

    // epilogue. D frag layout: row = lg*4 + r, col = lc
    #pragma unroll
    for (int i = 0; i < MI; i++) {
        if (EPI == 1) {
            const int colbase = bn + wc * 64;
            const int zc = colbase >> 10;                 // 0=q 1=k 2=v
            unsigned short* OH = (zc == 0) ? Hq : (zc == 1) ? Hk : Hv;
            const int hcol = (colbase >> 6) & 15;
            #pragma unroll
            for (int r = 0; r < 4; r++) {
                int row = bm + wr * (MI * 16) + i * 16 + lg * 4 + r;
                int b = row >> 10, s = row & 1023;
                size_t base = ((size_t)(b * Hdim + hcol) * Sdim + s) << 6;
                if (zc == 2) {
                    #pragma unroll
                    for (int j = 0; j < 4; j++) OH[base + j * 16 + lc] = f2bf(acc[i][j][r]);
                } else {
                    int xr = (zc == 1) ? ((s & 7) << 3) : 0;
                    #pragma unroll
                    for (int j = 0; j < 2; j++) {
                        int d = j * 16 + lc;              // [0,32)
                        float x1 = acc[i][j][r];
                        float x2 = acc[i][j + 2][r];
                        float c = cosT[s * 64 + d];
                        float sn = sinT[s * 64 + d];
                        OH[base + (d ^ xr)] = f2bf(x1 * c - x2 * sn);
                        OH[base + ((d + 32) ^ xr)] = f2bf(x2 * c + x1 * sn);
                    }
                }
            }
        } else {
            #pragma unroll
            for (int r = 0; r < 4; r++) {
                int row = bm + wr * (MI * 16) + i * 16 + lg * 4 + r;
                #pragma unroll
                for (int j = 0; j < 4; j++) {
                    int col = bn + wc * 64 + j * 16 + lc;
                    float v = acc[i][j][r];
                    if (EPI == 2) {
                        OF[(size_t)row * ldC + col] += v;
                    } else if (EPI == 3) {
                        float t = v + bias[col];
                        Hq[(size_t)row * ldC + col] = f2bf(t / (1.0f + expf(-t)));
                    } else if (EPI == 4) {
                        OF[(size_t)row * ldC + col] += v + bias[col];
                    } else {
                        OF[(size_t)row * ldC + col] = v;
                    }
                }
            }
        }
    }
}

// ---------------- flash attention (routed bias), S^T orientation ----------------
// K staged from k16 (pre-swizzled by QKV epilogue), V^T staged from vT (pre-swizzled by vtrans).
// Double-buffered GLD staging; one raw barrier + vmcnt(0) per tile.
__global__ __launch_bounds__(256) void attn_kernel(const unsigned short* __restrict__ q16,
                                                   const unsigned short* __restrict__ k16,
                                                   const unsigned short* __restrict__ vT,
                                                   const float* __restrict__ biasA,
                                                   unsigned short* __restrict__ o16) {
    const int qb = blockIdx.x;   // 16 (64 q rows each)
    const int bh = blockIdx.y;   // 32
    const int tid = threadIdx.x;
    const int w = tid >> 6, lane = tid & 63;
    const int lg = lane >> 4, lc = lane & 15;

    __shared__ unsigned short Ks[2][64 * 64];
    __shared__ unsigned short Vs[2][64 * 64];
    __shared__ unsigned short Pq[4][16][72];
    __shared__ float sbAll[1024];

    // bias preload
    {
        const float4 bv = ((const float4*)(biasA + (size_t)bh * Sdim))[tid];
        *(float4*)&sbAll[tid * 4] = bv;
    }

    const int qrow = qb * 64 + w * 16 + lc;
    const unsigned short* qbase = q16 + ((size_t)bh * Sdim + qrow) * Ddim;
    bf16x8 qf[2];
    qf[0] = *(const bf16x8*)(qbase + lg * 8);
    qf[1] = *(const bf16x8*)(qbase + 32 + lg * 8);

    const int grow = tid >> 3;          // 0..31
    const int gc = (tid & 7) * 8;
    const unsigned short* kbase = k16 + (size_t)bh * Sdim * Ddim;
    const unsigned short* vbase = vT + (size_t)bh * Ddim * Sdim;

    // stage tile 0
    {
        const unsigned short* kg = kbase + (size_t)grow * Ddim + gc;
        GLD16(kg, &Ks[0][tid * 8]);
        GLD16(kg + 32 * Ddim, &Ks[0][2048 + tid * 8]);
        const unsigned short* vg = vbase + (size_t)grow * Sdim + gc;
        GLD16(vg, &Vs[0][tid * 8]);
        GLD16(vg + 32 * Sdim, &Vs[0][2048 + tid * 8]);
    }
    __syncthreads();   // drains vmcnt (tile 0, qf, bias) + syncs sbAll

    float m_i = -1e30f, l_i = 0.0f;
    f32x4 ot[4];
    f32x4 zero = {0.0f, 0.0f, 0.0f, 0.0f};
    #pragma unroll
    for (int fd = 0; fd < 4; fd++) ot[fd] = zero;

    const int sw = (lc & 7) << 3;

    for (int tt = 0; tt < 16; tt++) {
        const int cur = tt & 1;
        if (tt > 0) {
            asm volatile("s_waitcnt vmcnt(0)" ::: "memory");
            __builtin_amdgcn_sched_barrier(0);
            __builtin_amdgcn_s_barrier();
        }
        if (tt < 15) {
            const int t1 = (tt + 1) * 64;
            const unsigned short* kg = kbase + (size_t)(t1 + grow) * Ddim + gc;
            GLD16(kg, &Ks[cur ^ 1][tid * 8]);
            GLD16(kg + 32 * Ddim, &Ks[cur ^ 1][2048 + tid * 8]);
            const unsigned short* vg = vbase + (size_t)grow * Sdim + t1 + gc;
            GLD16(vg, &Vs[cur ^ 1][tid * 8]);
            GLD16(vg + 32 * Sdim, &Vs[cur ^ 1][2048 + tid * 8]);
        }

        // S^T = K * Q^T
        f32x4 sf[4];
        #pragma unroll
        for (int f = 0; f < 4; f++) {
            const int trow = f * 16 + lc;
            f32x4 a = zero;
            #pragma unroll
            for (int ks = 0; ks < 2; ks++) {
                bf16x8 kfr = *(bf16x8*)&Ks[cur][trow * 64 + ((ks * 32 + lg * 8) ^ sw)];
                a = MFMA16(kfr, qf[ks], a);
            }
            sf[f] = a;
        }
        // scale + bias, online softmax (per-lane state for column q = lc)
        const int t0 = tt * 64;
        float tmax = -1e30f;
        #pragma unroll
        for (int f = 0; f < 4; f++)
            #pragma unroll
            for (int j = 0; j < 4; j++) {
                float v = sf[f][j] * 0.125f + sbAll[t0 + f * 16 + lg * 4 + j];
                sf[f][j] = v;
                tmax = fmaxf(tmax, v);
            }
        tmax = fmaxf(tmax, __shfl_xor(tmax, 16));
        tmax = fmaxf(tmax, __shfl_xor(tmax, 32));
        float mnew = fmaxf(m_i, tmax);
        float alpha = expf(m_i - mnew);
        float lsum = 0.0f;
        #pragma unroll
        for (int f = 0; f < 4; f++)
            #pragma unroll
            for (int j = 0; j < 4; j++) {
                float p = expf(sf[f][j] - mnew);
                sf[f][j] = p;
                lsum += p;
            }
        lsum += __shfl_xor(lsum, 16);
        lsum += __shfl_xor(lsum, 32);
        l_i = l_i * alpha + lsum;
        m_i = mnew;
        #pragma unroll
        for (int fd = 0; fd < 4; fd++)
            #pragma unroll
            for (int j = 0; j < 4; j++) ot[fd][j] *= alpha;
        // P -> per-wave LDS [q][t] (b64 stores)
        #pragma unroll
        for (int f = 0; f < 4; f++) {
            short4 ps = make_short4((short)f2bf(sf[f][0]), (short)f2bf(sf[f][1]),
                                    (short)f2bf(sf[f][2]), (short)f2bf(sf[f][3]));
            *(short4*)&Pq[w][lc][f * 16 + lg * 4] = ps;
        }
        // O^T += V^T * P^T
        #pragma unroll
        for (int ks = 0; ks < 2; ks++) {
            bf16x8 pf = *(bf16x8*)&Pq[w][lc][ks * 32 + lg * 8];
            #pragma unroll
            for (int fd = 0; fd < 4; fd++) {
                bf16x8 vfr = *(bf16x8*)&Vs[cur][(fd * 16 + lc) * 64 + ((ks * 32 + lg * 8) ^ sw)];
                ot[fd] = MFMA16(vfr, pf, ot[fd]);
            }
        }
    }
    float rl = 1.0f / l_i;
    int b = bh >> 4, h = bh & 15;
    #pragma unroll
    for (int fd = 0; fd < 4; fd++)
        #pragma unroll
        for (int j = 0; j < 4; j++) {
            int d = fd * 16 + lg * 4 + j;
            o16[((size_t)b * Sdim + qrow) * HDdim + h * 64 + d] = f2bf(ot[fd][j] * rl);
        }
}

extern "C" void kernel_launch(void* const* d_in, const int* in_sizes, int n_in,
                              void* d_out, int out_size, void* d_ws, size_t ws_size,
                              hipStream_t stream) {
    const int* ids = (const int*)d_in[0];
    const float* amask = (const float*)d_in[1];
    const float* emb = (const float*)d_in[2];
    const float* ln1w = (const float*)d_in[3];
    const float* ln1b = (const float*)d_in[4];
    const float* Wq = (const float*)d_in[5];
    const float* Wk = (const float*)d_in[6];
    const float* Wv = (const float*)d_in[7];
    const float* Wo = (const float*)d_in[8];
    const float* Wr = (const float*)d_in[9];
    const float* ln2w = (const float*)d_in[10];
    const float* ln2b = (const float*)d_in[11];
    const float* W1 = (const float*)d_in[12];
    const float* b1 = (const float*)d_in[13];
    const float* W2 = (const float*)d_in[14];
    const float* b2 = (const float*)d_in[15];
    const float* nw = (const float*)d_in[16];
    const float* nb = (const float*)d_in[17];
    const float* lmh = (const float*)d_in[18];
    float* out = (float*)d_out;

    char* p = (char*)d_ws;
    size_t off = 0;
    auto alloc = [&](size_t bytes) -> void* {
        void* r = p + off;
        off += (bytes + 255) & ~(size_t)255;
        return r;
    };
    float* cosT = (float*)alloc((size_t)Sdim * Ddim * 4);
    float* sinT = (float*)alloc((size_t)Sdim * Ddim * 4);
    float* x = (float*)alloc((size_t)BSdim * HDdim * 4);
    float* h32 = (float*)alloc((size_t)BSdim * HDdim * 4);
    unsigned short* h16 = (unsigned short*)alloc((size_t)BSdim * HDdim * 2);
    unsigned short* o16 = (unsigned short*)alloc((size_t)BSdim * HDdim * 2);
    unsigned short* m16 = (unsigned short*)alloc((size_t)BSdim * Idim * 2);
    unsigned short* q16 = (unsigned short*)alloc((size_t)Bdim * Hdim * Sdim * Ddim * 2);
    unsigned short* k16 = (unsigned short*)alloc((size_t)Bdim * Hdim * Sdim * Ddim * 2);
    unsigned short* v16 = (unsigned short*)alloc((size_t)Bdim * Hdim * Sdim * Ddim * 2);
    unsigned short* vTs = (unsigned short*)alloc((size_t)Bdim * Hdim * Sdim * Ddim * 2);
    float* router = (float*)alloc((size_t)Bdim * Hdim * Sdim * 4);
    float* biasA = (float*)alloc((size_t)Bdim * Hdim * Sdim * 4);
    unsigned short* wts = (unsigned short*)alloc((size_t)Vdim * HDdim * 2);  // 64MB reuse buffer

    const size_t M1 = 1u << 20;  // 1M elems

    tables_kernel<<<256, 256, 0, stream>>>(cosT, sinT);
    embed_kernel<<<BSdim, 256, 0, stream>>>(ids, emb, x);

    for (int l = 0; l < Ldim; l++) {
        const float* Wq_l = Wq + (size_t)l * HDdim * HDdim;
        const float* Wk_l = Wk + (size_t)l * HDdim * HDdim;
        const float* Wv_l = Wv + (size_t)l * HDdim * HDdim;
        const float* Wo_l = Wo + (size_t)l * HDdim * HDdim;
        const float* Wr_l = Wr + (size_t)l * HDdim * Hdim;
        const float* W1_l = W1 + (size_t)l * HDdim * Idim;
        const float* W2_l = W2 + (size_t)l * Idim * HDdim;
        const float* b1_l = b1 + (size_t)l * Idim;
        const float* b2_l = b2 + (size_t)l * HDdim;

        // weight prepass: QKVO -> wts[0..4M), W1t -> wts[4M..8M), W2t -> wts[8M..12M)
        tconv_kernel<<<dim3(32, 32, 4), 256, 0, stream>>>(Wq_l, Wk_l, Wv_l, Wo_l, wts, HDdim, HDdim, M1);
        tconv_kernel<<<dim3(128, 32, 1), 256, 0, stream>>>(W1_l, W1_l, W1_l, W1_l, wts + 4 * M1, HDdim, Idim, 0);
        tconv_kernel<<<dim3(32, 128, 1), 256, 0, stream>>>(W2_l, W2_l, W2_l, W2_l, wts + 8 * M1, Idim, HDdim, 0);

        ln_kernel<<<BSdim, 256, 0, stream>>>(x, ln1w + l * HDdim, ln1b + l * HDdim, h16, h32);
        router_kernel<<<BSdim, 256, 0, stream>>>(h32, Wr_l, router);
        topk_kernel<<<Bdim * Hdim, 1024, 0, stream>>>(router, amask, biasA);
        // fused QKV GEMM: B = [3072][1024] bf16
        gemm_bt<1, 128><<<dim3(16, 24), 256, 0, stream>>>(h16, wts, nullptr, q16, k16, v16,
                                                          nullptr, cosT, sinT, HDdim, 0);
        vtrans_kernel<<<dim3(16, 32), 256, 0, stream>>>(v16, vTs);
        attn_kernel<<<dim3(16, 32), 256, 0, stream>>>(q16, k16, vTs, biasA, o16);
        gemm_bt<2, 64><<<dim3(16, 16), 256, 0, stream>>>(o16, wts + 3 * M1, x, nullptr, nullptr, nullptr,
                                                         nullptr, nullptr, nullptr, HDdim, HDdim);
        ln_kernel<<<BSdim, 256, 0, stream>>>(x, ln2w + l * HDdim, ln2b + l * HDdim, h16, nullptr);
        gemm_bt<3, 128><<<dim3(16, 32), 256, 0, stream>>>(h16, wts + 4 * M1, nullptr, m16, nullptr, nullptr,
                                                          b1_l, nullptr, nullptr, HDdim, Idim);
        gemm_bt<4, 64><<<dim3(16, 16), 256, 0, stream>>>(m16, wts + 8 * M1, x, nullptr, nullptr, nullptr,
                                                         b2_l, nullptr, nullptr, Idim, HDdim);
    }

    ln_kernel<<<BSdim, 256, 0, stream>>>(x, nw, nb, h16, nullptr);
    // lm_head: one tconv (32000x1024 bf16, 64MB) + one GEMM
    tconv_kernel<<<dim3(1000, 32, 1), 256, 0, stream>>>(lmh, lmh, lmh, lmh, wts, HDdim, Vdim, 0);
    gemm_bt<5, 128><<<dim3(16, 250), 256, 0, stream>>>(h16, wts, out, nullptr, nullptr, nullptr,
                                                       nullptr, nullptr, nullptr, HDdim, Vdim);
}

// Round 5
// 1273.159 us; speedup vs baseline: 1.7184x; 1.0850x over previous
//
#include <hip/hip_runtime.h>
#include <hip/hip_bf16.h>

#define Bdim 2
#define Sdim 1024
#define Vdim 32000
#define HDdim 1024
#define Ldim 4
#define Hdim 16
#define Ddim 64
#define Idim 4096
#define BSdim 2048

typedef __attribute__((ext_vector_type(8))) short bf16x8;
typedef __attribute__((ext_vector_type(4))) float f32x4;

__device__ __forceinline__ unsigned short f2bf(float f) {
    __hip_bfloat16 h = __float2bfloat16(f);
    return *reinterpret_cast<unsigned short*>(&h);
}

#define MFMA16(a, b, c) __builtin_amdgcn_mfma_f32_16x16x32_bf16((a), (b), (c), 0, 0, 0)

#define GLD16(gp, lp)                                                            \
    __builtin_amdgcn_global_load_lds((const __attribute__((address_space(1))) void*)(gp), \
                                     (__attribute__((address_space(3))) void*)(lp), 16, 0, 0)

template <int N>
__device__ __forceinline__ void vwait() {
    if constexpr (N == 3) asm volatile("s_waitcnt vmcnt(3)" ::: "memory");
    else if constexpr (N == 4) asm volatile("s_waitcnt vmcnt(4)" ::: "memory");
    else if constexpr (N == 6) asm volatile("s_waitcnt vmcnt(6)" ::: "memory");
}

// ---------------- rope tables ----------------
__global__ __launch_bounds__(256) void tables_kernel(float* __restrict__ cosT, float* __restrict__ sinT) {
    int i = blockIdx.x * 256 + threadIdx.x;   // 65536 = S*D
    int d = i & 63;
    int s = i >> 6;
    float inv = powf(1.0e6f, -((float)(2 * (d & 31))) / 64.0f);
    float f = (float)s * inv;
    cosT[i] = cosf(f);
    sinT[i] = sinf(f);
}

// ---------------- embedding gather ----------------
__global__ __launch_bounds__(256) void embed_kernel(const int* __restrict__ ids, const float* __restrict__ emb,
                                                    float* __restrict__ x) {
    int m = blockIdx.x;
    int tid = threadIdx.x;
    int id = ids[m];
    const float4* src = (const float4*)(emb + (size_t)id * HDdim);
    ((float4*)(x + (size_t)m * HDdim))[tid] = src[tid];
}

// ---------------- layernorm -> bf16 (+ optional f32 copy) ----------------
__global__ __launch_bounds__(256) void ln_kernel(const float* __restrict__ x, const float* __restrict__ w,
                                                 const float* __restrict__ bw, unsigned short* __restrict__ outH,
                                                 float* __restrict__ out32) {
    int m = blockIdx.x;
    int tid = threadIdx.x;
    float4 a = ((const float4*)(x + (size_t)m * HDdim))[tid];
    float s = a.x + a.y + a.z + a.w;
    #pragma unroll
    for (int o = 1; o < 64; o <<= 1) s += __shfl_xor(s, o);
    __shared__ float red[4], red2[4];
    if ((tid & 63) == 0) red[tid >> 6] = s;
    __syncthreads();
    float mean = (red[0] + red[1] + red[2] + red[3]) * (1.0f / 1024.0f);
    float dx = a.x - mean, dy = a.y - mean, dz = a.z - mean, dw = a.w - mean;
    float s2 = dx * dx + dy * dy + dz * dz + dw * dw;
    #pragma unroll
    for (int o = 1; o < 64; o <<= 1) s2 += __shfl_xor(s2, o);
    if ((tid & 63) == 0) red2[tid >> 6] = s2;
    __syncthreads();
    float var = (red2[0] + red2[1] + red2[2] + red2[3]) * (1.0f / 1024.0f);
    float rs = rsqrtf(var + 1e-6f);
    float4 wv = ((const float4*)w)[tid];
    float4 bv = ((const float4*)bw)[tid];
    float v0 = dx * rs * wv.x + bv.x;
    float v1 = dy * rs * wv.y + bv.y;
    float v2 = dz * rs * wv.z + bv.z;
    float v3 = dw * rs * wv.w + bv.w;
    short4 st = make_short4((short)f2bf(v0), (short)f2bf(v1), (short)f2bf(v2), (short)f2bf(v3));
    *(short4*)(outH + (size_t)m * HDdim + tid * 4) = st;
    if (out32) ((float4*)(out32 + (size_t)m * HDdim))[tid] = make_float4(v0, v1, v2, v3);
}

// ---------------- router GEMM: router[b,h,s] = h32[b,s,:] . Wr[:,h] ----------------
__global__ __launch_bounds__(256) void router_kernel(const float* __restrict__ h32, const float* __restrict__ Wr,
                                                     float* __restrict__ router) {
    int m = blockIdx.x;                 // b*S + s
    int tid = threadIdx.x;
    int hh = tid & 15, eg = tid >> 4;
    const float* hr = h32 + (size_t)m * HDdim;
    float sum = 0.0f;
    for (int e = eg; e < HDdim; e += 16) sum += hr[e] * Wr[e * Hdim + hh];
    __shared__ float red[256];
    red[tid] = sum;
    __syncthreads();
    if (tid < 16) {
        float s = 0.0f;
        #pragma unroll
        for (int g = 0; g < 16; g++) s += red[g * 16 + tid];
        router[((size_t)((m >> 10) * Hdim + tid)) * Sdim + (m & 1023)] = s;
    }
}

// ---------------- exact top-k threshold + bias ----------------
__global__ __launch_bounds__(1024) void topk_kernel(const float* __restrict__ router, const float* __restrict__ amask,
                                                    float* __restrict__ biasA) {
    int bh = blockIdx.x;
    int t = threadIdx.x;
    __shared__ float r[1024];
    __shared__ float kths;
    float v = router[(size_t)bh * Sdim + t];
    r[t] = v;
    __syncthreads();
    int gt = 0, eq = 0;
    for (int j = 0; j < 1024; j++) {
        float xv = r[j];
        gt += (xv > v) ? 1 : 0;
        eq += (xv == v) ? 1 : 0;
    }
    if (gt < 512 && gt + eq >= 512) kths = v;
    __syncthreads();
    float kth = kths;
    float bias;
    if (v >= kth) {
        bias = (v >= 0.0f) ? -log1pf(expf(-v)) : (v - log1pf(expf(v)));
    } else {
        bias = -1e9f;
    }
    int b = bh >> 4;
    bias += (1.0f - amask[b * Sdim + t]) * (-1e9f);
    biasA[(size_t)bh * Sdim + t] = bias;
}

// ---------------- transpose + f32->bf16 convert: S [K][N] f32 -> D [N][K] bf16 ----------------
__global__ __launch_bounds__(256) void tconv_kernel(const float* __restrict__ S0, const float* __restrict__ S1,
                                                    const float* __restrict__ S2, const float* __restrict__ S3,
                                                    unsigned short* __restrict__ D, int K, int ldS, size_t dstride) {
    const float* S = (blockIdx.z == 0) ? S0 : (blockIdx.z == 1) ? S1 : (blockIdx.z == 2) ? S2 : S3;
    unsigned short* dz = D + (size_t)blockIdx.z * dstride;
    __shared__ float t[32][33];
    int kt = blockIdx.y * 32, nt = blockIdx.x * 32;
    int r = threadIdx.x >> 3, c4 = (threadIdx.x & 7) * 4;
    float4 v = *(const float4*)(S + (size_t)(kt + r) * ldS + nt + c4);
    t[r][c4] = v.x; t[r][c4 + 1] = v.y; t[r][c4 + 2] = v.z; t[r][c4 + 3] = v.w;
    __syncthreads();
    short4 o = make_short4((short)f2bf(t[c4][r]), (short)f2bf(t[c4 + 1][r]),
                           (short)f2bf(t[c4 + 2][r]), (short)f2bf(t[c4 + 3][r]));
    *(short4*)(dz + (size_t)(nt + r) * K + kt + c4) = o;
}

// ---------------- V transpose: v16 [bh][t][d] -> vT [bh][d][t] with XOR swizzle baked in ----------------
__global__ __launch_bounds__(256) void vtrans_kernel(const unsigned short* __restrict__ v16,
                                                     unsigned short* __restrict__ vT) {
    int t0 = blockIdx.x * 64;   // 16 tiles
    int bh = blockIdx.y;        // 32
    __shared__ unsigned short T[64][72];
    int r = threadIdx.x >> 2;
    int c0 = (threadIdx.x & 3) * 16;
    const unsigned short* src = v16 + ((size_t)bh * Sdim + t0 + r) * Ddim + c0;
    *(bf16x8*)&T[r][c0] = *(const bf16x8*)src;
    *(bf16x8*)&T[r][c0 + 8] = *(const bf16x8*)(src + 8);
    __syncthreads();
    int d = threadIdx.x >> 2;
    int xr = (d & 7) << 3;
    unsigned short* dst = vT + ((size_t)bh * Ddim + d) * Sdim + t0;
    #pragma unroll
    for (int cc = 0; cc < 2; cc++) {
        int tb = (threadIdx.x & 3) * 16 + cc * 8;
        bf16x8 o;
        #pragma unroll
        for (int i = 0; i < 8; i++) o[i] = (short)T[tb + i][d];
        *(bf16x8*)(dst + (tb ^ xr)) = o;
    }
}

// ================= 8-phase 512-thread MFMA GEMM (T2+T3+T4+T5) =================
// C = A(bf16 [M,K]) * Bt(bf16 [N,K])^T.  8 waves (WM x WN), BK=64, 4 phases/K-tile.
// LDS is HALF-MAJOR: half h of A = union over waves of their half-h frag rows
// (rows r with (r & (BM/WM/2)) == h*(BM/WM/2)); staged via per-lane interleaved
// global source rows (linear LDS dest, m173), XOR-swizzle folded into source col.
// Counted vmcnt (never 0 in the loop); raw barriers; setprio around MFMA.
// EPI: 1 = fused QKV (rope->bf16, K swizzled), 3 = bias+silu->bf16, 5 = plain f32
template <int EPI, int BM, int BN, int WM, int WN>
__global__ __launch_bounds__(512) void gemm8p(
    const unsigned short* __restrict__ A, const unsigned short* __restrict__ Bt,
    float* __restrict__ OF, unsigned short* __restrict__ Hq, unsigned short* __restrict__ Hk,
    unsigned short* __restrict__ Hv, const float* __restrict__ bias,
    const float* __restrict__ cosT, const float* __restrict__ sinT,
    int K, int ldC, int gridM) {
    constexpr int MI = BM / WM / 16, NI = BN / WN / 16;
    constexpr int MH = MI / 2, NH = NI / 2;
    constexpr int LA = BM / 128, LB = BN / 128;
    constexpr int HA = BM / WM / 2;   // A half-selector bit
    constexpr int HB = BN / WN / 2;   // B half-selector bit
    constexpr int ABUF = BM * 64, BBUF = BN * 64;

    __shared__ unsigned short lds[2 * ABUF + 2 * BBUF];

    int bid = blockIdx.x;
    const int nwg = gridDim.x;
    if ((nwg & 7) == 0) bid = (bid & 7) * (nwg >> 3) + (bid >> 3);   // XCD swizzle (bijective: nwg%8==0)
    const int bm = (bid % gridM) * BM;
    const int bn = (bid / gridM) * BN;

    const int tid = threadIdx.x;
    const int lane = tid & 63, wid = tid >> 6;
    const int lc = lane & 15, lg = lane >> 4;
    const int wwm = wid / WN, wwn = wid % WN;

    // staging: LDS linear in (half, idx, chunk); global row interleaved so that
    // LDS half h holds exactly the frag rows of quadrant h. XOR-swizzle on source col.
    const int srow = tid >> 3;                    // 0..63
    const int scol = ((tid & 7) ^ (srow & 7)) * 8;
    // ds_read: LDS row L = half*(BM/2) + ww*H + m*16 + lc  ->  L&7 == lc&7, XOR folds.
    const int ak0 = (lg * 8) ^ ((lc & 7) * 8);
    const int ak1 = (32 + lg * 8) ^ ((lc & 7) * 8);

    f32x4 acc[MI][NI];
    f32x4 zero = {0.0f, 0.0f, 0.0f, 0.0f};
    #pragma unroll
    for (int i = 0; i < MI; i++)
        #pragma unroll
        for (int j = 0; j < NI; j++) acc[i][j] = zero;

    bf16x8 a[MH][2], b0[NH][2], b1[NH][2];

    auto stage_a = [&](int half, int nbuf, int kt) {
        #pragma unroll
        for (int j = 0; j < LA; j++) {
            const int idx = j * 64 + srow;                          // [0, BM/2)
            const int grow = (idx / HA) * (BM / WM) + half * HA + (idx % HA);
            const unsigned short* g = A + (size_t)(bm + grow) * K + kt + scol;
            GLD16(g, &lds[nbuf * ABUF + half * (ABUF / 2) + (j * 512 + tid) * 8]);
        }
    };
    auto stage_b = [&](int half, int nbuf, int kt) {
        #pragma unroll
        for (int j = 0; j < LB; j++) {
            const int idx = j * 64 + srow;                          // [0, BN/2)
            const int grow = (idx / HB) * (BN / WN) + half * HB + (idx % HB);
            const unsigned short* g = Bt + (size_t)(bn + grow) * K + kt + scol;
            GLD16(g, &lds[2 * ABUF + nbuf * BBUF + half * (BBUF / 2) + (j * 512 + tid) * 8]);
        }
    };

#define DS_A(mh_, cur_)                                                                   \
    _Pragma("unroll") for (int m = 0; m < MH; m++) {                                      \
        const int ro = (cur_)*ABUF + (mh_) * (ABUF / 2) + (wwm * HA + m * 16 + lc) * 64;  \
        a[m][0] = *(const bf16x8*)&lds[ro + ak0];                                         \
        a[m][1] = *(const bf16x8*)&lds[ro + ak1];                                         \
    }
#define DS_B(bb_, nh_, cur_)                                                              \
    _Pragma("unroll") for (int n = 0; n < NH; n++) {                                      \
        const int ro = 2 * ABUF + (cur_)*BBUF + (nh_) * (BBUF / 2) + (wwn * HB + n * 16 + lc) * 64; \
        bb_[n][0] = *(const bf16x8*)&lds[ro + ak0];                                       \
        bb_[n][1] = *(const bf16x8*)&lds[ro + ak1];                                       \
    }
#define MFMA_PH(mh_, nh_, bb_)                                                            \
    __builtin_amdgcn_s_setprio(1);                                                        \
    _Pragma("unroll") for (int m = 0; m < MH; m++) _Pragma("unroll") for (int n = 0; n < NH; n++) { \
        acc[(mh_)*MH + m][(nh_)*NH + n] = MFMA16(a[m][0], bb_[n][0], acc[(mh_)*MH + m][(nh_)*NH + n]); \
        acc[(mh_)*MH + m][(nh_)*NH + n] = MFMA16(a[m][1], bb_[n][1], acc[(mh_)*MH + m][(nh_)*NH + n]); \
    }                                                                                     \
    __builtin_amdgcn_s_setprio(0);
#define BAR_PRE()                                                                         \
    __builtin_amdgcn_sched_barrier(0);                                                    \
    __builtin_amdgcn_s_barrier();
#define BAR_END()                                                                         \
    asm volatile("" ::: "memory");                                                        \
    __builtin_amdgcn_s_barrier();                                                         \
    __builtin_amdgcn_sched_barrier(0);

    // prologue: tile 0 half-tiles in steady-state order; leave {Bh1,Ah1} in flight
    stage_a(0, 0, 0);
    stage_b(0, 0, 0);
    stage_b(1, 0, 0);
    stage_a(1, 0, 0);
    vwait<LA + LB>();
    BAR_END();

    const int NT = K >> 6;
    for (int t = 0; t < NT; t++) {
        const int cur = t & 1, nxt = cur ^ 1;
        const int ktn = (t + 1 < NT) ? (t + 1) * 64 : t * 64;
        // phase 1: quadrant (0,0)   [needs A_h0, B_h0 of cur — complete]
        DS_A(0, cur);
        DS_B(b0, 0, cur);
        stage_a(0, nxt, ktn);
        BAR_PRE();
        MFMA_PH(0, 0, b0);
        vwait<2 * LA>();            // completes B_h1(cur)
        BAR_END();
        // phase 2: quadrant (0,1)
        DS_B(b1, 1, cur);
        stage_b(0, nxt, ktn);
        BAR_PRE();
        MFMA_PH(0, 1, b1);
        vwait<LA + LB>();           // completes A_h1(cur)
        BAR_END();
        // phase 3: quadrant (1,1)
        DS_A(1, cur);
        stage_b(1, nxt, ktn);
        BAR_PRE();
        MFMA_PH(1, 1, b1);
        BAR_END();
        // phase 4: quadrant (1,0)  [regs only: a=half1, b0=half0]
        stage_a(1, nxt, ktn);
        BAR_PRE();
        MFMA_PH(1, 0, b0);
        vwait<LA + LB>();           // completes A_h0, B_h0 of nxt
        BAR_END();
    }
    asm volatile("s_waitcnt vmcnt(0)" ::: "memory");   // drain LDS-destined loads before endpgm
#undef DS_A
#undef DS_B
#undef MFMA_PH
#undef BAR_PRE
#undef BAR_END

    // epilogue (contiguous per-wave mapping, same as verified round-3 kernel).
    // D frag layout: row = lg*4 + r, col = lc
    #pragma unroll
    for (int i = 0; i < MI; i++) {
        if (EPI == 1) {
            const int colbase = bn + wwn * (BN / WN);
            const int zc = colbase >> 10;                 // 0=q 1=k 2=v
            unsigned short* OH = (zc == 0) ? Hq : (zc == 1) ? Hk : Hv;
            const int hcol = (colbase >> 6) & 15;
            #pragma unroll
            for (int r = 0; r < 4; r++) {
                int row = bm + wwm * (BM / WM) + i * 16 + lg * 4 + r;
                int b = row >> 10, s = row & 1023;
                size_t base = ((size_t)(b * Hdim + hcol) * Sdim + s) << 6;
                if (zc == 2) {
                    #pragma unroll
                    for (int j = 0; j < 4; j++) OH[base + j * 16 + lc] = f2bf(acc[i][j][r]);
                } else {
                    int xr = (zc == 1) ? ((s & 7) << 3) : 0;
                    #pragma unroll
                    for (int j = 0; j < 2; j++) {
                        int d = j * 16 + lc;              // [0,32)
                        float x1 = acc[i][j][r];
                        float x2 = acc[i][j + 2][r];
                        float c = cosT[s * 64 + d];
                        float sn = sinT[s * 64 + d];
                        OH[base + (d ^ xr)] = f2bf(x1 * c - x2 * sn);
                        OH[base + ((d + 32) ^ xr)] = f2bf(x2 * c + x1 * sn);
                    }
                }
            }
        } else {
            #pragma unroll
            for (int r = 0; r < 4; r++) {
                int row = bm + wwm * (BM / WM) + i * 16 + lg * 4 + r;
                #pragma unroll
                for (int j = 0; j < NI; j++) {
                    int col = bn + wwn * (BN / WN) + j * 16 + lc;
                    float v = acc[i][j][r];
                    if (EPI == 3) {
                        float t = v + bias[col];
                        Hq[(size_t)row * ldC + col] = f2bf(t / (1.0f + expf(-t)));
                    } else {
                        OF[(size_t)row * ldC + col] = v;
                    }
                }
            }
        }
    }
}

// ---------------- legacy MFMA GEMM (Wo, W2): C = A * Bt^T ----------------
// EPI: 2=residual add f32, 4=bias+residual
template <int EPI, int BN>
__global__ __launch_bounds__(256) void gemm_bt(
    const unsigned short* __restrict__ A,
    const unsigned short* __restrict__ Bt,
    float* __restrict__ OF,
    const float* __restrict__ bias,
    int K, int ldC) {
    const int bm = blockIdx.x * 128;
    const int bn = blockIdx.y * BN;
    const int tid = threadIdx.x;
    const int lane = tid & 63;
    const int w = tid >> 6;
    constexpr int NWC = (BN == 128) ? 2 : 1;
    constexpr int MI = (BN == 128) ? 4 : 2;
    const int wr = w / NWC, wc = w % NWC;
    const int lg = lane >> 4, lc = lane & 15;

    __shared__ unsigned short As[128 * 32];
    __shared__ unsigned short Bs[BN * 32];

    f32x4 acc[MI][4];
    f32x4 zero = {0.0f, 0.0f, 0.0f, 0.0f};
    #pragma unroll
    for (int i = 0; i < MI; i++)
        #pragma unroll
        for (int j = 0; j < 4; j++) acc[i][j] = zero;

    const int srow = tid >> 2;
    const int scol = (tid & 3) * 8;

    for (int kt = 0; kt < K; kt += 32) {
        const unsigned short* ag = A + (size_t)(bm + srow) * K + kt + scol;
        GLD16(ag, &As[tid * 8]);
        GLD16(ag + (size_t)64 * K, &As[2048 + tid * 8]);
        const unsigned short* bg = Bt + (size_t)(bn + srow) * K + kt + scol;
        GLD16(bg, &Bs[tid * 8]);
        if (BN == 128) GLD16(bg + (size_t)64 * K, &Bs[2048 + tid * 8]);
        __syncthreads();

        bf16x8 af[MI], bfr[4];
        #pragma unroll
        for (int i = 0; i < MI; i++) af[i] = *(bf16x8*)&As[(wr * (MI * 16) + i * 16 + lc) * 32 + lg * 8];
        #pragma unroll
        for (int j = 0; j < 4; j++) bfr[j] = *(bf16x8*)&Bs[(wc * 64 + j * 16 + lc) * 32 + lg * 8];
        #pragma unroll
        for (int i = 0; i < MI; i++)
            #pragma unroll
            for (int j = 0; j < 4; j++) acc[i][j] = MFMA16(af[i], bfr[j], acc[i][j]);
        __syncthreads();
    }

    #pragma unroll
    for (int i = 0; i < MI; i++) {
        #pragma unroll
        for (int r = 0; r < 4; r++) {
            int row = bm + wr * (MI * 16) + i * 16 + lg * 4 + r;
            #pragma unroll
            for (int j = 0; j < 4; j++) {
                int col = bn + wc * 64 + j * 16 + lc;
                float v = acc[i][j][r];
                if (EPI == 2) {
                    OF[(size_t)row * ldC + col] += v;
                } else {
                    OF[(size_t)row * ldC + col] += v + bias[col];
                }
            }
        }
    }
}

// ---------------- flash attention (routed bias), S^T orientation ----------------
__global__ __launch_bounds__(256) void attn_kernel(const unsigned short* __restrict__ q16,
                                                   const unsigned short* __restrict__ k16,
                                                   const unsigned short* __restrict__ vT,
                                                   const float* __restrict__ biasA,
                                                   unsigned short* __restrict__ o16) {
    const int qb = blockIdx.x;   // 16 (64 q rows each)
    const int bh = blockIdx.y;   // 32
    const int tid = threadIdx.x;
    const int w = tid >> 6, lane = tid & 63;
    const int lg = lane >> 4, lc = lane & 15;

    __shared__ unsigned short Ks[2][64 * 64];
    __shared__ unsigned short Vs[2][64 * 64];
    __shared__ unsigned short Pq[4][16][72];
    __shared__ float sbAll[1024];

    {
        const float4 bv = ((const float4*)(biasA + (size_t)bh * Sdim))[tid];
        *(float4*)&sbAll[tid * 4] = bv;
    }

    const int qrow = qb * 64 + w * 16 + lc;
    const unsigned short* qbase = q16 + ((size_t)bh * Sdim + qrow) * Ddim;
    bf16x8 qf[2];
    qf[0] = *(const bf16x8*)(qbase + lg * 8);
    qf[1] = *(const bf16x8*)(qbase + 32 + lg * 8);

    const int grow = tid >> 3;
    const int gc = (tid & 7) * 8;
    const unsigned short* kbase = k16 + (size_t)bh * Sdim * Ddim;
    const unsigned short* vbase = vT + (size_t)bh * Ddim * Sdim;

    {
        const unsigned short* kg = kbase + (size_t)grow * Ddim + gc;
        GLD16(kg, &Ks[0][tid * 8]);
        GLD16(kg + 32 * Ddim, &Ks[0][2048 + tid * 8]);
        const unsigned short* vg = vbase + (size_t)grow * Sdim + gc;
        GLD16(vg, &Vs[0][tid * 8]);
        GLD16(vg + 32 * Sdim, &Vs[0][2048 + tid * 8]);
    }
    __syncthreads();

    float m_i = -1e30f, l_i = 0.0f;
    f32x4 ot[4];
    f32x4 zero = {0.0f, 0.0f, 0.0f, 0.0f};
    #pragma unroll
    for (int fd = 0; fd < 4; fd++) ot[fd] = zero;

    const int sw = (lc & 7) << 3;

    for (int tt = 0; tt < 16; tt++) {
        const int cur = tt & 1;
        if (tt > 0) {
            asm volatile("s_waitcnt vmcnt(0)" ::: "memory");
            __builtin_amdgcn_sched_barrier(0);
            __builtin_amdgcn_s_barrier();
        }
        if (tt < 15) {
            const int t1 = (tt + 1) * 64;
            const unsigned short* kg = kbase + (size_t)(t1 + grow) * Ddim + gc;
            GLD16(kg, &Ks[cur ^ 1][tid * 8]);
            GLD16(kg + 32 * Ddim, &Ks[cur ^ 1][2048 + tid * 8]);
            const unsigned short* vg = vbase + (size_t)grow * Sdim + t1 + gc;
            GLD16(vg, &Vs[cur ^ 1][tid * 8]);
            GLD16(vg + 32 * Sdim, &Vs[cur ^ 1][2048 + tid * 8]);
        }

        f32x4 sf[4];
        #pragma unroll
        for (int f = 0; f < 4; f++) {
            const int trow = f * 16 + lc;
            f32x4 a = zero;
            #pragma unroll
            for (int ks = 0; ks < 2; ks++) {
                bf16x8 kfr = *(bf16x8*)&Ks[cur][trow * 64 + ((ks * 32 + lg * 8) ^ sw)];
                a = MFMA16(kfr, qf[ks], a);
            }
            sf[f] = a;
        }
        const int t0 = tt * 64;
        float tmax = -1e30f;
        #pragma unroll
        for (int f = 0; f < 4; f++)
            #pragma unroll
            for (int j = 0; j < 4; j++) {
                float v = sf[f][j] * 0.125f + sbAll[t0 + f * 16 + lg * 4 + j];
                sf[f][j] = v;
                tmax = fmaxf(tmax, v);
            }
        tmax = fmaxf(tmax, __shfl_xor(tmax, 16));
        tmax = fmaxf(tmax, __shfl_xor(tmax, 32));
        float mnew = fmaxf(m_i, tmax);
        float alpha = expf(m_i - mnew);
        float lsum = 0.0f;
        #pragma unroll
        for (int f = 0; f < 4; f++)
            #pragma unroll
            for (int j = 0; j < 4; j++) {
                float p = expf(sf[f][j] - mnew);
                sf[f][j] = p;
                lsum += p;
            }
        lsum += __shfl_xor(lsum, 16);
        lsum += __shfl_xor(lsum, 32);
        l_i = l_i * alpha + lsum;
        m_i = mnew;
        #pragma unroll
        for (int fd = 0; fd < 4; fd++)
            #pragma unroll
            for (int j = 0; j < 4; j++) ot[fd][j] *= alpha;
        #pragma unroll
        for (int f = 0; f < 4; f++) {
            short4 ps = make_short4((short)f2bf(sf[f][0]), (short)f2bf(sf[f][1]),
                                    (short)f2bf(sf[f][2]), (short)f2bf(sf[f][3]));
            *(short4*)&Pq[w][lc][f * 16 + lg * 4] = ps;
        }
        #pragma unroll
        for (int ks = 0; ks < 2; ks++) {
            bf16x8 pf = *(bf16x8*)&Pq[w][lc][ks * 32 + lg * 8];
            #pragma unroll
            for (int fd = 0; fd < 4; fd++) {
                bf16x8 vfr = *(bf16x8*)&Vs[cur][(fd * 16 + lc) * 64 + ((ks * 32 + lg * 8) ^ sw)];
                ot[fd] = MFMA16(vfr, pf, ot[fd]);
            }
        }
    }
    float rl = 1.0f / l_i;
    int b = bh >> 4, h = bh & 15;
    #pragma unroll
    for (int fd = 0; fd < 4; fd++)
        #pragma unroll
        for (int j = 0; j < 4; j++) {
            int d = fd * 16 + lg * 4 + j;
            o16[((size_t)b * Sdim + qrow) * HDdim + h * 64 + d] = f2bf(ot[fd][j] * rl);
        }
}

extern "C" void kernel_launch(void* const* d_in, const int* in_sizes, int n_in,
                              void* d_out, int out_size, void* d_ws, size_t ws_size,
                              hipStream_t stream) {
    const int* ids = (const int*)d_in[0];
    const float* amask = (const float*)d_in[1];
    const float* emb = (const float*)d_in[2];
    const float* ln1w = (const float*)d_in[3];
    const float* ln1b = (const float*)d_in[4];
    const float* Wq = (const float*)d_in[5];
    const float* Wk = (const float*)d_in[6];
    const float* Wv = (const float*)d_in[7];
    const float* Wo = (const float*)d_in[8];
    const float* Wr = (const float*)d_in[9];
    const float* ln2w = (const float*)d_in[10];
    const float* ln2b = (const float*)d_in[11];
    const float* W1 = (const float*)d_in[12];
    const float* b1 = (const float*)d_in[13];
    const float* W2 = (const float*)d_in[14];
    const float* b2 = (const float*)d_in[15];
    const float* nw = (const float*)d_in[16];
    const float* nb = (const float*)d_in[17];
    const float* lmh = (const float*)d_in[18];
    float* out = (float*)d_out;

    char* p = (char*)d_ws;
    size_t off = 0;
    auto alloc = [&](size_t bytes) -> void* {
        void* r = p + off;
        off += (bytes + 255) & ~(size_t)255;
        return r;
    };
    float* cosT = (float*)alloc((size_t)Sdim * Ddim * 4);
    float* sinT = (float*)alloc((size_t)Sdim * Ddim * 4);
    float* x = (float*)alloc((size_t)BSdim * HDdim * 4);
    float* h32 = (float*)alloc((size_t)BSdim * HDdim * 4);
    unsigned short* h16 = (unsigned short*)alloc((size_t)BSdim * HDdim * 2);
    unsigned short* o16 = (unsigned short*)alloc((size_t)BSdim * HDdim * 2);
    unsigned short* m16 = (unsigned short*)alloc((size_t)BSdim * Idim * 2);
    unsigned short* q16 = (unsigned short*)alloc((size_t)Bdim * Hdim * Sdim * Ddim * 2);
    unsigned short* k16 = (unsigned short*)alloc((size_t)Bdim * Hdim * Sdim * Ddim * 2);
    unsigned short* v16 = (unsigned short*)alloc((size_t)Bdim * Hdim * Sdim * Ddim * 2);
    unsigned short* vTs = (unsigned short*)alloc((size_t)Bdim * Hdim * Sdim * Ddim * 2);
    float* router = (float*)alloc((size_t)Bdim * Hdim * Sdim * 4);
    float* biasA = (float*)alloc((size_t)Bdim * Hdim * Sdim * 4);
    unsigned short* wts = (unsigned short*)alloc((size_t)Vdim * HDdim * 2);  // 64MB reuse buffer

    const size_t M1 = 1u << 20;  // 1M elems

    tables_kernel<<<256, 256, 0, stream>>>(cosT, sinT);
    embed_kernel<<<BSdim, 256, 0, stream>>>(ids, emb, x);

    for (int l = 0; l < Ldim; l++) {
        const float* Wq_l = Wq + (size_t)l * HDdim * HDdim;
        const float* Wk_l = Wk + (size_t)l * HDdim * HDdim;
        const float* Wv_l = Wv + (size_t)l * HDdim * HDdim;
        const float* Wo_l = Wo + (size_t)l * HDdim * HDdim;
        const float* Wr_l = Wr + (size_t)l * HDdim * Hdim;
        const float* W1_l = W1 + (size_t)l * HDdim * Idim;
        const float* W2_l = W2 + (size_t)l * Idim * HDdim;
        const float* b1_l = b1 + (size_t)l * Idim;
        const float* b2_l = b2 + (size_t)l * HDdim;

        // weight prepass: QKVO -> wts[0..4M), W1t -> wts[4M..8M), W2t -> wts[8M..12M)
        tconv_kernel<<<dim3(32, 32, 4), 256, 0, stream>>>(Wq_l, Wk_l, Wv_l, Wo_l, wts, HDdim, HDdim, M1);
        tconv_kernel<<<dim3(128, 32, 1), 256, 0, stream>>>(W1_l, W1_l, W1_l, W1_l, wts + 4 * M1, HDdim, Idim, 0);
        tconv_kernel<<<dim3(32, 128, 1), 256, 0, stream>>>(W2_l, W2_l, W2_l, W2_l, wts + 8 * M1, Idim, HDdim, 0);

        ln_kernel<<<BSdim, 256, 0, stream>>>(x, ln1w + l * HDdim, ln1b + l * HDdim, h16, h32);
        router_kernel<<<BSdim, 256, 0, stream>>>(h32, Wr_l, router);
        topk_kernel<<<Bdim * Hdim, 1024, 0, stream>>>(router, amask, biasA);
        // fused QKV GEMM (8-phase): B = [3072][1024] bf16, grid 8 x 24
        gemm8p<1, 256, 128, 4, 2><<<192, 512, 0, stream>>>(h16, wts, nullptr, q16, k16, v16,
                                                           nullptr, cosT, sinT, HDdim, 0, 8);
        vtrans_kernel<<<dim3(16, 32), 256, 0, stream>>>(v16, vTs);
        attn_kernel<<<dim3(16, 32), 256, 0, stream>>>(q16, k16, vTs, biasA, o16);
        gemm_bt<2, 64><<<dim3(16, 16), 256, 0, stream>>>(o16, wts + 3 * M1, x, nullptr, HDdim, HDdim);
        ln_kernel<<<BSdim, 256, 0, stream>>>(x, ln2w + l * HDdim, ln2b + l * HDdim, h16, nullptr);
        // W1 GEMM (8-phase): grid 8 x 32
        gemm8p<3, 256, 128, 4, 2><<<256, 512, 0, stream>>>(h16, wts + 4 * M1, nullptr, m16, nullptr, nullptr,
                                                           b1_l, nullptr, nullptr, HDdim, Idim, 8);
        gemm_bt<4, 64><<<dim3(16, 16), 256, 0, stream>>>(m16, wts + 8 * M1, x, b2_l, Idim, HDdim);
    }

    ln_kernel<<<BSdim, 256, 0, stream>>>(x, nw, nb, h16, nullptr);
    // lm_head: one tconv (32000x1024 bf16, 64MB) + one 8-phase GEMM (grid 8 x 125)
    tconv_kernel<<<dim3(1000, 32, 1), 256, 0, stream>>>(lmh, lmh, lmh, lmh, wts, HDdim, Vdim, 0);
    gemm8p<5, 256, 256, 2, 4><<<1000, 512, 0, stream>>>(h16, wts, out, nullptr, nullptr, nullptr,
                                                        nullptr, nullptr, nullptr, HDdim, Vdim, 8);
}

// Round 6
// 1132.755 us; speedup vs baseline: 1.9314x; 1.1239x over previous
//
#include <hip/hip_runtime.h>
#include <hip/hip_bf16.h>

#define Bdim 2
#define Sdim 1024
#define Vdim 32000
#define HDdim 1024
#define Ldim 4
#define Hdim 16
#define Ddim 64
#define Idim 4096
#define BSdim 2048

typedef __attribute__((ext_vector_type(8))) short bf16x8;
typedef __attribute__((ext_vector_type(4))) float f32x4;

__device__ __forceinline__ unsigned short f2bf(float f) {
    __hip_bfloat16 h = __float2bfloat16(f);
    return *reinterpret_cast<unsigned short*>(&h);
}

#define MFMA16(a, b, c) __builtin_amdgcn_mfma_f32_16x16x32_bf16((a), (b), (c), 0, 0, 0)

#define GLD16(gp, lp)                                                            \
    __builtin_amdgcn_global_load_lds((const __attribute__((address_space(1))) void*)(gp), \
                                     (__attribute__((address_space(3))) void*)(lp), 16, 0, 0)

template <int N>
__device__ __forceinline__ void vwait() {
    if constexpr (N == 2) asm volatile("s_waitcnt vmcnt(2)" ::: "memory");
    else if constexpr (N == 3) asm volatile("s_waitcnt vmcnt(3)" ::: "memory");
    else if constexpr (N == 4) asm volatile("s_waitcnt vmcnt(4)" ::: "memory");
    else if constexpr (N == 6) asm volatile("s_waitcnt vmcnt(6)" ::: "memory");
}

// ---------------- rope tables ----------------
__global__ __launch_bounds__(256) void tables_kernel(float* __restrict__ cosT, float* __restrict__ sinT) {
    int i = blockIdx.x * 256 + threadIdx.x;   // 65536 = S*D
    int d = i & 63;
    int s = i >> 6;
    float inv = powf(1.0e6f, -((float)(2 * (d & 31))) / 64.0f);
    float f = (float)s * inv;
    cosT[i] = cosf(f);
    sinT[i] = sinf(f);
}

// ---------------- embedding gather ----------------
__global__ __launch_bounds__(256) void embed_kernel(const int* __restrict__ ids, const float* __restrict__ emb,
                                                    float* __restrict__ x) {
    int m = blockIdx.x;
    int tid = threadIdx.x;
    int id = ids[m];
    const float4* src = (const float4*)(emb + (size_t)id * HDdim);
    ((float4*)(x + (size_t)m * HDdim))[tid] = src[tid];
}

// ---------------- layernorm -> bf16 (+ optional fused router) ----------------
__global__ __launch_bounds__(256) void ln_kernel(const float* __restrict__ x, const float* __restrict__ w,
                                                 const float* __restrict__ bw, unsigned short* __restrict__ outH,
                                                 const float* __restrict__ Wr, float* __restrict__ routerO) {
    int m = blockIdx.x;
    int tid = threadIdx.x;
    float4 a = ((const float4*)(x + (size_t)m * HDdim))[tid];
    float s = a.x + a.y + a.z + a.w;
    #pragma unroll
    for (int o = 1; o < 64; o <<= 1) s += __shfl_xor(s, o);
    __shared__ float red[4], red2[4];
    if ((tid & 63) == 0) red[tid >> 6] = s;
    __syncthreads();
    float mean = (red[0] + red[1] + red[2] + red[3]) * (1.0f / 1024.0f);
    float dx = a.x - mean, dy = a.y - mean, dz = a.z - mean, dw = a.w - mean;
    float s2 = dx * dx + dy * dy + dz * dz + dw * dw;
    #pragma unroll
    for (int o = 1; o < 64; o <<= 1) s2 += __shfl_xor(s2, o);
    if ((tid & 63) == 0) red2[tid >> 6] = s2;
    __syncthreads();
    float var = (red2[0] + red2[1] + red2[2] + red2[3]) * (1.0f / 1024.0f);
    float rs = rsqrtf(var + 1e-6f);
    float4 wv = ((const float4*)w)[tid];
    float4 bv = ((const float4*)bw)[tid];
    float v0 = dx * rs * wv.x + bv.x;
    float v1 = dy * rs * wv.y + bv.y;
    float v2 = dz * rs * wv.z + bv.z;
    float v3 = dw * rs * wv.w + bv.w;
    short4 st = make_short4((short)f2bf(v0), (short)f2bf(v1), (short)f2bf(v2), (short)f2bf(v3));
    *(short4*)(outH + (size_t)m * HDdim + tid * 4) = st;

    if (Wr) {   // fused router: routerO[b][h][s] = h_norm . Wr[:,h]
        __shared__ float rbuf[256][16];
        __shared__ float pbuf[16][17];
        float part[16];
        const float* wr0 = Wr + (size_t)(tid * 4) * Hdim;
        #pragma unroll
        for (int h = 0; h < 16; h++)
            part[h] = v0 * wr0[h] + v1 * wr0[16 + h] + v2 * wr0[32 + h] + v3 * wr0[48 + h];
        #pragma unroll
        for (int h4 = 0; h4 < 4; h4++)
            *(float4*)&rbuf[tid][h4 * 4] = make_float4(part[h4 * 4], part[h4 * 4 + 1], part[h4 * 4 + 2], part[h4 * 4 + 3]);
        __syncthreads();
        {
            int h = tid & 15, g = tid >> 4;
            float sgr = 0.0f;
            #pragma unroll
            for (int i = 0; i < 16; i++) sgr += rbuf[g * 16 + i][h];
            pbuf[g][h] = sgr;
        }
        __syncthreads();
        if (tid < 16) {
            float tot = 0.0f;
            #pragma unroll
            for (int g = 0; g < 16; g++) tot += pbuf[g][tid];
            int b = m >> 10, sI = m & 1023;
            routerO[((size_t)(b * Hdim + tid)) * Sdim + sI] = tot;
        }
    }
}

// ---------------- exact top-k threshold + bias ----------------
__global__ __launch_bounds__(1024) void topk_kernel(const float* __restrict__ router, const float* __restrict__ amask,
                                                    float* __restrict__ biasA) {
    int bh = blockIdx.x;
    int t = threadIdx.x;
    __shared__ float r[1024];
    __shared__ float kths;
    float v = router[(size_t)bh * Sdim + t];
    r[t] = v;
    __syncthreads();
    int gt = 0, eq = 0;
    for (int j = 0; j < 1024; j++) {
        float xv = r[j];
        gt += (xv > v) ? 1 : 0;
        eq += (xv == v) ? 1 : 0;
    }
    if (gt < 512 && gt + eq >= 512) kths = v;
    __syncthreads();
    float kth = kths;
    float bias;
    if (v >= kth) {
        bias = (v >= 0.0f) ? -log1pf(expf(-v)) : (v - log1pf(expf(v)));
    } else {
        bias = -1e9f;
    }
    int b = bh >> 4;
    bias += (1.0f - amask[b * Sdim + t]) * (-1e9f);
    biasA[(size_t)bh * Sdim + t] = bias;
}

// ---------------- transpose + f32->bf16 convert: S [K][N] f32 -> D [N][K] bf16 ----------------
__global__ __launch_bounds__(256) void tconv_kernel(const float* __restrict__ S0,
                                                    unsigned short* __restrict__ D, int K, int ldS) {
    __shared__ float t[32][33];
    int kt = blockIdx.y * 32, nt = blockIdx.x * 32;
    int r = threadIdx.x >> 3, c4 = (threadIdx.x & 7) * 4;
    float4 v = *(const float4*)(S0 + (size_t)(kt + r) * ldS + nt + c4);
    t[r][c4] = v.x; t[r][c4 + 1] = v.y; t[r][c4 + 2] = v.z; t[r][c4 + 3] = v.w;
    __syncthreads();
    short4 o = make_short4((short)f2bf(t[c4][r]), (short)f2bf(t[c4 + 1][r]),
                           (short)f2bf(t[c4 + 2][r]), (short)f2bf(t[c4 + 3][r]));
    *(short4*)(D + (size_t)(nt + r) * K + kt + c4) = o;
}

// ---------------- per-layer weight prepass: QKVO + W1 + W2 in one dispatch ----------------
__global__ __launch_bounds__(256) void tconv_layer(const float* __restrict__ Wq, const float* __restrict__ Wk,
                                                   const float* __restrict__ Wv, const float* __restrict__ Wo,
                                                   const float* __restrict__ W1, const float* __restrict__ W2,
                                                   unsigned short* __restrict__ wts) {
    const size_t M1 = 1u << 20;
    int bid = blockIdx.x;
    const float* S;
    unsigned short* D;
    int K, ldS, nt, kt;
    if (bid < 4096) {            // QKVO: 4 x [1024][1024]
        int z = bid >> 10, t = bid & 1023;
        S = (z == 0) ? Wq : (z == 1) ? Wk : (z == 2) ? Wv : Wo;
        D = wts + (size_t)z * M1;
        K = 1024; ldS = 1024; nt = t & 31; kt = t >> 5;
    } else if (bid < 8192) {     // W1: [1024][4096]
        int t = bid - 4096;
        S = W1; D = wts + 4 * M1;
        K = 1024; ldS = 4096; nt = t % 128; kt = t / 128;
    } else {                     // W2: [4096][1024]
        int t = bid - 8192;
        S = W2; D = wts + 8 * M1;
        K = 4096; ldS = 1024; nt = t % 32; kt = t / 32;
    }
    __shared__ float tb[32][33];
    int ktb = kt * 32, ntb = nt * 32;
    int r = threadIdx.x >> 3, c4 = (threadIdx.x & 7) * 4;
    float4 v = *(const float4*)(S + (size_t)(ktb + r) * ldS + ntb + c4);
    tb[r][c4] = v.x; tb[r][c4 + 1] = v.y; tb[r][c4 + 2] = v.z; tb[r][c4 + 3] = v.w;
    __syncthreads();
    short4 o = make_short4((short)f2bf(tb[c4][r]), (short)f2bf(tb[c4 + 1][r]),
                           (short)f2bf(tb[c4 + 2][r]), (short)f2bf(tb[c4 + 3][r]));
    *(short4*)(D + (size_t)(ntb + r) * K + ktb + c4) = o;
}

// ---------------- V transpose: v16 [bh][t][d] -> vT [bh][d][t] with XOR swizzle baked in ----------------
__global__ __launch_bounds__(256) void vtrans_kernel(const unsigned short* __restrict__ v16,
                                                     unsigned short* __restrict__ vT) {
    int t0 = blockIdx.x * 64;   // 16 tiles
    int bh = blockIdx.y;        // 32
    __shared__ unsigned short T[64][72];
    int r = threadIdx.x >> 2;
    int c0 = (threadIdx.x & 3) * 16;
    const unsigned short* src = v16 + ((size_t)bh * Sdim + t0 + r) * Ddim + c0;
    *(bf16x8*)&T[r][c0] = *(const bf16x8*)src;
    *(bf16x8*)&T[r][c0 + 8] = *(const bf16x8*)(src + 8);
    __syncthreads();
    int d = threadIdx.x >> 2;
    int xr = (d & 7) << 3;
    unsigned short* dst = vT + ((size_t)bh * Ddim + d) * Sdim + t0;
    #pragma unroll
    for (int cc = 0; cc < 2; cc++) {
        int tb = (threadIdx.x & 3) * 16 + cc * 8;
        bf16x8 o;
        #pragma unroll
        for (int i = 0; i < 8; i++) o[i] = (short)T[tb + i][d];
        *(bf16x8*)(dst + (tb ^ xr)) = o;
    }
}

// ================= 8-phase 512-thread MFMA GEMM (T2+T3+T4+T5) =================
// C = A(bf16 [M,ldK]) * Bt(bf16 [N,ldK])^T over K-chunk Kc at offset ks*Kc
// (split-K decoded from flat grid: bid = ks*gridM*gridN + bn*gridM + bm).
// LDS half-major, staged via per-lane interleaved global rows (linear dest),
// XOR-swizzle folded into source col. Counted vmcnt; raw barriers; setprio.
// EPI: 1 = fused QKV (rope->bf16, K swizzled; needs BN/WN==64),
//      3 = bias+silu->bf16, 5 = plain f32, 6 = atomic += (+bias on ks==0)
template <int EPI, int BM, int BN, int WM, int WN>
__global__ __launch_bounds__(512) void gemm8p(
    const unsigned short* __restrict__ A, const unsigned short* __restrict__ Bt,
    float* __restrict__ OF, unsigned short* __restrict__ Hq, unsigned short* __restrict__ Hk,
    unsigned short* __restrict__ Hv, const float* __restrict__ bias,
    const float* __restrict__ cosT, const float* __restrict__ sinT,
    int Kc, int ldK, int ldC, int gridM, int gridN) {
    constexpr int MI = BM / WM / 16, NI = BN / WN / 16;
    constexpr int MH = MI / 2, NH = NI / 2;
    constexpr int LA = BM / 128, LB = BN / 128;
    constexpr int HA = BM / WM / 2;   // A half-selector
    constexpr int HB = BN / WN / 2;   // B half-selector
    constexpr int ABUF = BM * 64, BBUF = BN * 64;

    __shared__ unsigned short lds[2 * ABUF + 2 * BBUF];

    int bid = blockIdx.x;
    const int nwg = gridDim.x;
    if ((nwg & 7) == 0) bid = (bid & 7) * (nwg >> 3) + (bid >> 3);   // XCD swizzle (bijective: nwg%8==0)
    const int mn = gridM * gridN;
    const int ks = bid / mn;
    const int rem = bid - ks * mn;
    const int bm = (rem % gridM) * BM;
    const int bn = (rem / gridM) * BN;
    const unsigned short* Ap = A + (size_t)ks * Kc;
    const unsigned short* Bp = Bt + (size_t)ks * Kc;

    const int tid = threadIdx.x;
    const int lane = tid & 63, wid = tid >> 6;
    const int lc = lane & 15, lg = lane >> 4;
    const int wwm = wid / WN, wwn = wid % WN;

    const int srow = tid >> 3;                    // 0..63
    const int scol = ((tid & 7) ^ (srow & 7)) * 8;
    const int ak0 = (lg * 8) ^ ((lc & 7) * 8);
    const int ak1 = (32 + lg * 8) ^ ((lc & 7) * 8);

    f32x4 acc[MI][NI];
    f32x4 zero = {0.0f, 0.0f, 0.0f, 0.0f};
    #pragma unroll
    for (int i = 0; i < MI; i++)
        #pragma unroll
        for (int j = 0; j < NI; j++) acc[i][j] = zero;

    bf16x8 a[MH][2], b0[NH][2], b1[NH][2];

    auto stage_a = [&](int half, int nbuf, int kt) {
        #pragma unroll
        for (int j = 0; j < LA; j++) {
            const int idx = j * 64 + srow;                          // [0, BM/2)
            const int grow = (idx / HA) * (BM / WM) + half * HA + (idx % HA);
            const unsigned short* g = Ap + (size_t)(bm + grow) * ldK + kt + scol;
            GLD16(g, &lds[nbuf * ABUF + half * (ABUF / 2) + (j * 512 + tid) * 8]);
        }
    };
    auto stage_b = [&](int half, int nbuf, int kt) {
        #pragma unroll
        for (int j = 0; j < LB; j++) {
            const int idx = j * 64 + srow;                          // [0, BN/2)
            const int grow = (idx / HB) * (BN / WN) + half * HB + (idx % HB);
            const unsigned short* g = Bp + (size_t)(bn + grow) * ldK + kt + scol;
            GLD16(g, &lds[2 * ABUF + nbuf * BBUF + half * (BBUF / 2) + (j * 512 + tid) * 8]);
        }
    };

#define DS_A(mh_, cur_)                                                                   \
    _Pragma("unroll") for (int m = 0; m < MH; m++) {                                      \
        const int ro = (cur_)*ABUF + (mh_) * (ABUF / 2) + (wwm * HA + m * 16 + lc) * 64;  \
        a[m][0] = *(const bf16x8*)&lds[ro + ak0];                                         \
        a[m][1] = *(const bf16x8*)&lds[ro + ak1];                                         \
    }
#define DS_B(bb_, nh_, cur_)                                                              \
    _Pragma("unroll") for (int n = 0; n < NH; n++) {                                      \
        const int ro = 2 * ABUF + (cur_)*BBUF + (nh_) * (BBUF / 2) + (wwn * HB + n * 16 + lc) * 64; \
        bb_[n][0] = *(const bf16x8*)&lds[ro + ak0];                                       \
        bb_[n][1] = *(const bf16x8*)&lds[ro + ak1];                                       \
    }
#define MFMA_PH(mh_, nh_, bb_)                                                            \
    __builtin_amdgcn_s_setprio(1);                                                        \
    _Pragma("unroll") for (int m = 0; m < MH; m++) _Pragma("unroll") for (int n = 0; n < NH; n++) { \
        acc[(mh_)*MH + m][(nh_)*NH + n] = MFMA16(a[m][0], bb_[n][0], acc[(mh_)*MH + m][(nh_)*NH + n]); \
        acc[(mh_)*MH + m][(nh_)*NH + n] = MFMA16(a[m][1], bb_[n][1], acc[(mh_)*MH + m][(nh_)*NH + n]); \
    }                                                                                     \
    __builtin_amdgcn_s_setprio(0);
#define BAR_PRE()                                                                         \
    __builtin_amdgcn_sched_barrier(0);                                                    \
    __builtin_amdgcn_s_barrier();
#define BAR_END()                                                                         \
    asm volatile("" ::: "memory");                                                        \
    __builtin_amdgcn_s_barrier();                                                         \
    __builtin_amdgcn_sched_barrier(0);

    // prologue: tile 0 half-tiles in steady-state order; leave {Bh1,Ah1} in flight
    stage_a(0, 0, 0);
    stage_b(0, 0, 0);
    stage_b(1, 0, 0);
    stage_a(1, 0, 0);
    vwait<LA + LB>();
    BAR_END();

    const int NT = Kc >> 6;
    for (int t = 0; t < NT; t++) {
        const int cur = t & 1, nxt = cur ^ 1;
        const int ktn = (t + 1 < NT) ? (t + 1) * 64 : t * 64;
        // phase 1: quadrant (0,0)
        DS_A(0, cur);
        DS_B(b0, 0, cur);
        stage_a(0, nxt, ktn);
        BAR_PRE();
        MFMA_PH(0, 0, b0);
        vwait<2 * LA>();            // completes B_h1(cur)
        BAR_END();
        // phase 2: quadrant (0,1)
        DS_B(b1, 1, cur);
        stage_b(0, nxt, ktn);
        BAR_PRE();
        MFMA_PH(0, 1, b1);
        vwait<LA + LB>();           // completes A_h1(cur)
        BAR_END();
        // phase 3: quadrant (1,1)
        DS_A(1, cur);
        stage_b(1, nxt, ktn);
        BAR_PRE();
        MFMA_PH(1, 1, b1);
        BAR_END();
        // phase 4: quadrant (1,0)
        stage_a(1, nxt, ktn);
        BAR_PRE();
        MFMA_PH(1, 0, b0);
        vwait<LA + LB>();           // completes A_h0, B_h0 of nxt
        BAR_END();
    }
    asm volatile("s_waitcnt vmcnt(0)" ::: "memory");   // drain LDS-destined loads before endpgm
#undef DS_A
#undef DS_B
#undef MFMA_PH
#undef BAR_PRE
#undef BAR_END

    // epilogue. D frag layout: row = lg*4 + r, col = lc
    #pragma unroll
    for (int i = 0; i < MI; i++) {
        if (EPI == 1) {
            const int colbase = bn + wwn * (BN / WN);
            const int zc = colbase >> 10;                 // 0=q 1=k 2=v
            unsigned short* OH = (zc == 0) ? Hq : (zc == 1) ? Hk : Hv;
            const int hcol = (colbase >> 6) & 15;
            #pragma unroll
            for (int r = 0; r < 4; r++) {
                int row = bm + wwm * (BM / WM) + i * 16 + lg * 4 + r;
                int b = row >> 10, s = row & 1023;
                size_t base = ((size_t)(b * Hdim + hcol) * Sdim + s) << 6;
                if (zc == 2) {
                    #pragma unroll
                    for (int j = 0; j < 4; j++) OH[base + j * 16 + lc] = f2bf(acc[i][j][r]);
                } else {
                    int xr = (zc == 1) ? ((s & 7) << 3) : 0;
                    #pragma unroll
                    for (int j = 0; j < 2; j++) {
                        int d = j * 16 + lc;              // [0,32)
                        float x1 = acc[i][j][r];
                        float x2 = acc[i][j + 2][r];
                        float c = cosT[s * 64 + d];
                        float sn = sinT[s * 64 + d];
                        OH[base + (d ^ xr)] = f2bf(x1 * c - x2 * sn);
                        OH[base + ((d + 32) ^ xr)] = f2bf(x2 * c + x1 * sn);
                    }
                }
            }
        } else {
            #pragma unroll
            for (int r = 0; r < 4; r++) {
                int row = bm + wwm * (BM / WM) + i * 16 + lg * 4 + r;
                #pragma unroll
                for (int j = 0; j < NI; j++) {
                    int col = bn + wwn * (BN / WN) + j * 16 + lc;
                    float v = acc[i][j][r];
                    if (EPI == 3) {
                        float t = v + bias[col];
                        Hq[(size_t)row * ldC + col] = f2bf(t / (1.0f + expf(-t)));
                    } else if (EPI == 6) {
                        if (ks == 0) v += bias[col];
                        unsafeAtomicAdd(&OF[(size_t)row * ldC + col], v);
                    } else {
                        OF[(size_t)row * ldC + col] = v;
                    }
                }
            }
        }
    }
}

// ---------------- legacy MFMA GEMM (Wo): C += A * Bt^T ----------------
template <int EPI, int BN>
__global__ __launch_bounds__(256) void gemm_bt(
    const unsigned short* __restrict__ A,
    const unsigned short* __restrict__ Bt,
    float* __restrict__ OF,
    const float* __restrict__ bias,
    int K, int ldC) {
    const int bm = blockIdx.x * 128;
    const int bn = blockIdx.y * BN;
    const int tid = threadIdx.x;
    const int lane = tid & 63;
    const int w = tid >> 6;
    constexpr int NWC = (BN == 128) ? 2 : 1;
    constexpr int MI = (BN == 128) ? 4 : 2;
    const int wr = w / NWC, wc = w % NWC;
    const int lg = lane >> 4, lc = lane & 15;

    __shared__ unsigned short As[128 * 32];
    __shared__ unsigned short Bs[BN * 32];

    f32x4 acc[MI][4];
    f32x4 zero = {0.0f, 0.0f, 0.0f, 0.0f};
    #pragma unroll
    for (int i = 0; i < MI; i++)
        #pragma unroll
        for (int j = 0; j < 4; j++) acc[i][j] = zero;

    const int srow = tid >> 2;
    const int scol = (tid & 3) * 8;

    for (int kt = 0; kt < K; kt += 32) {
        const unsigned short* ag = A + (size_t)(bm + srow) * K + kt + scol;
        GLD16(ag, &As[tid * 8]);
        GLD16(ag + (size_t)64 * K, &As[2048 + tid * 8]);
        const unsigned short* bg = Bt + (size_t)(bn + srow) * K + kt + scol;
        GLD16(bg, &Bs[tid * 8]);
        if (BN == 128) GLD16(bg + (size_t)64 * K, &Bs[2048 + tid * 8]);
        __syncthreads();

        bf16x8 af[MI], bfr[4];
        #pragma unroll
        for (int i = 0; i < MI; i++) af[i] = *(bf16x8*)&As[(wr * (MI * 16) + i * 16 + lc) * 32 + lg * 8];
        #pragma unroll
        for (int j = 0; j < 4; j++) bfr[j] = *(bf16x8*)&Bs[(wc * 64 + j * 16 + lc) * 32 + lg * 8];
        #pragma unroll
        for (int i = 0; i < MI; i++)
            #pragma unroll
            for (int j = 0; j < 4; j++) acc[i][j] = MFMA16(af[i], bfr[j], acc[i][j]);
        __syncthreads();
    }

    #pragma unroll
    for (int i = 0; i < MI; i++) {
        #pragma unroll
        for (int r = 0; r < 4; r++) {
            int row = bm + wr * (MI * 16) + i * 16 + lg * 4 + r;
            #pragma unroll
            for (int j = 0; j < 4; j++) {
                int col = bn + wc * 64 + j * 16 + lc;
                float v = acc[i][j][r];
                if (EPI == 2) {
                    OF[(size_t)row * ldC + col] += v;
                } else {
                    OF[(size_t)row * ldC + col] += v + bias[col];
                }
            }
        }
    }
}

// ---------------- flash attention (routed bias), S^T orientation ----------------
__global__ __launch_bounds__(256) void attn_kernel(const unsigned short* __restrict__ q16,
                                                   const unsigned short* __restrict__ k16,
                                                   const unsigned short* __restrict__ vT,
                                                   const float* __restrict__ biasA,
                                                   unsigned short* __restrict__ o16) {
    const int qb = blockIdx.x;   // 16 (64 q rows each)
    const int bh = blockIdx.y;   // 32
    const int tid = threadIdx.x;
    const int w = tid >> 6, lane = tid & 63;
    const int lg = lane >> 4, lc = lane & 15;

    __shared__ unsigned short Ks[2][64 * 64];
    __shared__ unsigned short Vs[2][64 * 64];
    __shared__ unsigned short Pq[4][16][72];
    __shared__ float sbAll[1024];

    {
        const float4 bv = ((const float4*)(biasA + (size_t)bh * Sdim))[tid];
        *(float4*)&sbAll[tid * 4] = bv;
    }

    const int qrow = qb * 64 + w * 16 + lc;
    const unsigned short* qbase = q16 + ((size_t)bh * Sdim + qrow) * Ddim;
    bf16x8 qf[2];
    qf[0] = *(const bf16x8*)(qbase + lg * 8);
    qf[1] = *(const bf16x8*)(qbase + 32 + lg * 8);

    const int grow = tid >> 3;
    const int gc = (tid & 7) * 8;
    const unsigned short* kbase = k16 + (size_t)bh * Sdim * Ddim;
    const unsigned short* vbase = vT + (size_t)bh * Ddim * Sdim;

    {
        const unsigned short* kg = kbase + (size_t)grow * Ddim + gc;
        GLD16(kg, &Ks[0][tid * 8]);
        GLD16(kg + 32 * Ddim, &Ks[0][2048 + tid * 8]);
        const unsigned short* vg = vbase + (size_t)grow * Sdim + gc;
        GLD16(vg, &Vs[0][tid * 8]);
        GLD16(vg + 32 * Sdim, &Vs[0][2048 + tid * 8]);
    }
    __syncthreads();

    float m_i = -1e30f, l_i = 0.0f;
    f32x4 ot[4];
    f32x4 zero = {0.0f, 0.0f, 0.0f, 0.0f};
    #pragma unroll
    for (int fd = 0; fd < 4; fd++) ot[fd] = zero;

    const int sw = (lc & 7) << 3;

    for (int tt = 0; tt < 16; tt++) {
        const int cur = tt & 1;
        if (tt > 0) {
            asm volatile("s_waitcnt vmcnt(0)" ::: "memory");
            __builtin_amdgcn_sched_barrier(0);
            __builtin_amdgcn_s_barrier();
        }
        if (tt < 15) {
            const int t1 = (tt + 1) * 64;
            const unsigned short* kg = kbase + (size_t)(t1 + grow) * Ddim + gc;
            GLD16(kg, &Ks[cur ^ 1][tid * 8]);
            GLD16(kg + 32 * Ddim, &Ks[cur ^ 1][2048 + tid * 8]);
            const unsigned short* vg = vbase + (size_t)grow * Sdim + t1 + gc;
            GLD16(vg, &Vs[cur ^ 1][tid * 8]);
            GLD16(vg + 32 * Sdim, &Vs[cur ^ 1][2048 + tid * 8]);
        }

        f32x4 sf[4];
        #pragma unroll
        for (int f = 0; f < 4; f++) {
            const int trow = f * 16 + lc;
            f32x4 a = zero;
            #pragma unroll
            for (int ks = 0; ks < 2; ks++) {
                bf16x8 kfr = *(bf16x8*)&Ks[cur][trow * 64 + ((ks * 32 + lg * 8) ^ sw)];
                a = MFMA16(kfr, qf[ks], a);
            }
            sf[f] = a;
        }
        const int t0 = tt * 64;
        float tmax = -1e30f;
        #pragma unroll
        for (int f = 0; f < 4; f++)
            #pragma unroll
            for (int j = 0; j < 4; j++) {
                float v = sf[f][j] * 0.125f + sbAll[t0 + f * 16 + lg * 4 + j];
                sf[f][j] = v;
                tmax = fmaxf(tmax, v);
            }
        tmax = fmaxf(tmax, __shfl_xor(tmax, 16));
        tmax = fmaxf(tmax, __shfl_xor(tmax, 32));
        float mnew = fmaxf(m_i, tmax);
        float alpha = expf(m_i - mnew);
        float lsum = 0.0f;
        #pragma unroll
        for (int f = 0; f < 4; f++)
            #pragma unroll
            for (int j = 0; j < 4; j++) {
                float p = expf(sf[f][j] - mnew);
                sf[f][j] = p;
                lsum += p;
            }
        lsum += __shfl_xor(lsum, 16);
        lsum += __shfl_xor(lsum, 32);
        l_i = l_i * alpha + lsum;
        m_i = mnew;
        #pragma unroll
        for (int fd = 0; fd < 4; fd++)
            #pragma unroll
            for (int j = 0; j < 4; j++) ot[fd][j] *= alpha;
        #pragma unroll
        for (int f = 0; f < 4; f++) {
            short4 ps = make_short4((short)f2bf(sf[f][0]), (short)f2bf(sf[f][1]),
                                    (short)f2bf(sf[f][2]), (short)f2bf(sf[f][3]));
            *(short4*)&Pq[w][lc][f * 16 + lg * 4] = ps;
        }
        #pragma unroll
        for (int ks = 0; ks < 2; ks++) {
            bf16x8 pf = *(bf16x8*)&Pq[w][lc][ks * 32 + lg * 8];
            #pragma unroll
            for (int fd = 0; fd < 4; fd++) {
                bf16x8 vfr = *(bf16x8*)&Vs[cur][(fd * 16 + lc) * 64 + ((ks * 32 + lg * 8) ^ sw)];
                ot[fd] = MFMA16(vfr, pf, ot[fd]);
            }
        }
    }
    float rl = 1.0f / l_i;
    int b = bh >> 4, h = bh & 15;
    #pragma unroll
    for (int fd = 0; fd < 4; fd++)
        #pragma unroll
        for (int j = 0; j < 4; j++) {
            int d = fd * 16 + lg * 4 + j;
            o16[((size_t)b * Sdim + qrow) * HDdim + h * 64 + d] = f2bf(ot[fd][j] * rl);
        }
}

extern "C" void kernel_launch(void* const* d_in, const int* in_sizes, int n_in,
                              void* d_out, int out_size, void* d_ws, size_t ws_size,
                              hipStream_t stream) {
    const int* ids = (const int*)d_in[0];
    const float* amask = (const float*)d_in[1];
    const float* emb = (const float*)d_in[2];
    const float* ln1w = (const float*)d_in[3];
    const float* ln1b = (const float*)d_in[4];
    const float* Wq = (const float*)d_in[5];
    const float* Wk = (const float*)d_in[6];
    const float* Wv = (const float*)d_in[7];
    const float* Wo = (const float*)d_in[8];
    const float* Wr = (const float*)d_in[9];
    const float* ln2w = (const float*)d_in[10];
    const float* ln2b = (const float*)d_in[11];
    const float* W1 = (const float*)d_in[12];
    const float* b1 = (const float*)d_in[13];
    const float* W2 = (const float*)d_in[14];
    const float* b2 = (const float*)d_in[15];
    const float* nw = (const float*)d_in[16];
    const float* nb = (const float*)d_in[17];
    const float* lmh = (const float*)d_in[18];
    float* out = (float*)d_out;

    char* p = (char*)d_ws;
    size_t off = 0;
    auto alloc = [&](size_t bytes) -> void* {
        void* r = p + off;
        off += (bytes + 255) & ~(size_t)255;
        return r;
    };
    float* cosT = (float*)alloc((size_t)Sdim * Ddim * 4);
    float* sinT = (float*)alloc((size_t)Sdim * Ddim * 4);
    float* x = (float*)alloc((size_t)BSdim * HDdim * 4);
    unsigned short* h16 = (unsigned short*)alloc((size_t)BSdim * HDdim * 2);
    unsigned short* o16 = (unsigned short*)alloc((size_t)BSdim * HDdim * 2);
    unsigned short* m16 = (unsigned short*)alloc((size_t)BSdim * Idim * 2);
    unsigned short* q16 = (unsigned short*)alloc((size_t)Bdim * Hdim * Sdim * Ddim * 2);
    unsigned short* k16 = (unsigned short*)alloc((size_t)Bdim * Hdim * Sdim * Ddim * 2);
    unsigned short* v16 = (unsigned short*)alloc((size_t)Bdim * Hdim * Sdim * Ddim * 2);
    unsigned short* vTs = (unsigned short*)alloc((size_t)Bdim * Hdim * Sdim * Ddim * 2);
    float* router = (float*)alloc((size_t)Bdim * Hdim * Sdim * 4);
    float* biasA = (float*)alloc((size_t)Bdim * Hdim * Sdim * 4);
    unsigned short* wts = (unsigned short*)alloc((size_t)Vdim * HDdim * 2);  // 64MB reuse buffer

    const size_t M1 = 1u << 20;  // 1M elems

    tables_kernel<<<256, 256, 0, stream>>>(cosT, sinT);
    embed_kernel<<<BSdim, 256, 0, stream>>>(ids, emb, x);

    for (int l = 0; l < Ldim; l++) {
        const float* Wq_l = Wq + (size_t)l * HDdim * HDdim;
        const float* Wk_l = Wk + (size_t)l * HDdim * HDdim;
        const float* Wv_l = Wv + (size_t)l * HDdim * HDdim;
        const float* Wo_l = Wo + (size_t)l * HDdim * HDdim;
        const float* Wr_l = Wr + (size_t)l * HDdim * Hdim;
        const float* W1_l = W1 + (size_t)l * HDdim * Idim;
        const float* W2_l = W2 + (size_t)l * Idim * HDdim;
        const float* b1_l = b1 + (size_t)l * Idim;
        const float* b2_l = b2 + (size_t)l * HDdim;

        // weight prepass (single dispatch): QKVO -> wts[0..4M), W1t -> [4M..8M), W2t -> [8M..12M)
        tconv_layer<<<12288, 256, 0, stream>>>(Wq_l, Wk_l, Wv_l, Wo_l, W1_l, W2_l, wts);

        // ln1 with fused router
        ln_kernel<<<BSdim, 256, 0, stream>>>(x, ln1w + l * HDdim, ln1b + l * HDdim, h16, Wr_l, router);
        topk_kernel<<<Bdim * Hdim, 1024, 0, stream>>>(router, amask, biasA);
        // fused QKV GEMM (8-phase, 128x128, 8-wave): grid 16 x 24 = 384
        gemm8p<1, 128, 128, 4, 2><<<384, 512, 0, stream>>>(h16, wts, nullptr, q16, k16, v16,
                                                           nullptr, cosT, sinT, HDdim, HDdim, 0, 16, 24);
        vtrans_kernel<<<dim3(16, 32), 256, 0, stream>>>(v16, vTs);
        attn_kernel<<<dim3(16, 32), 256, 0, stream>>>(q16, k16, vTs, biasA, o16);
        gemm_bt<2, 64><<<dim3(16, 16), 256, 0, stream>>>(o16, wts + 3 * M1, x, nullptr, HDdim, HDdim);
        ln_kernel<<<BSdim, 256, 0, stream>>>(x, ln2w + l * HDdim, ln2b + l * HDdim, h16, nullptr, nullptr);
        // W1 GEMM (8-phase): grid 8 x 32 = 256
        gemm8p<3, 256, 128, 4, 2><<<256, 512, 0, stream>>>(h16, wts + 4 * M1, nullptr, m16, nullptr, nullptr,
                                                           b1_l, nullptr, nullptr, HDdim, HDdim, Idim, 8, 32);
        // W2 GEMM (8-phase, split-K=4 x 1024, atomic accumulate into residual): grid 8 x 8 x 4 = 256
        gemm8p<6, 256, 128, 4, 2><<<256, 512, 0, stream>>>(m16, wts + 8 * M1, x, nullptr, nullptr, nullptr,
                                                           b2_l, nullptr, nullptr, 1024, Idim, HDdim, 8, 8);
    }

    ln_kernel<<<BSdim, 256, 0, stream>>>(x, nw, nb, h16, nullptr, nullptr);
    // lm_head: one tconv (32000x1024 bf16, 64MB) + one 8-phase GEMM (grid 8 x 125)
    tconv_kernel<<<dim3(1000, 32, 1), 256, 0, stream>>>(lmh, wts, HDdim, Vdim);
    gemm8p<5, 256, 256, 2, 4><<<1000, 512, 0, stream>>>(h16, wts, out, nullptr, nullptr, nullptr,
                                                        nullptr, nullptr, nullptr, HDdim, HDdim, Vdim, 8, 125);
}

// Round 7
// 1071.180 us; speedup vs baseline: 2.0424x; 1.0575x over previous
//
#include <hip/hip_runtime.h>
#include <hip/hip_bf16.h>

#define Bdim 2
#define Sdim 1024
#define Vdim 32000
#define HDdim 1024
#define Ldim 4
#define Hdim 16
#define Ddim 64
#define Idim 4096
#define BSdim 2048

typedef __attribute__((ext_vector_type(8))) short bf16x8;
typedef __attribute__((ext_vector_type(4))) float f32x4;

__device__ __forceinline__ unsigned short f2bf(float f) {
    __hip_bfloat16 h = __float2bfloat16(f);
    return *reinterpret_cast<unsigned short*>(&h);
}

#define MFMA16(a, b, c) __builtin_amdgcn_mfma_f32_16x16x32_bf16((a), (b), (c), 0, 0, 0)

#define GLD16(gp, lp)                                                            \
    __builtin_amdgcn_global_load_lds((const __attribute__((address_space(1))) void*)(gp), \
                                     (__attribute__((address_space(3))) void*)(lp), 16, 0, 0)

template <int N>
__device__ __forceinline__ void vwait() {
    if constexpr (N == 2) asm volatile("s_waitcnt vmcnt(2)" ::: "memory");
    else if constexpr (N == 3) asm volatile("s_waitcnt vmcnt(3)" ::: "memory");
    else if constexpr (N == 4) asm volatile("s_waitcnt vmcnt(4)" ::: "memory");
    else if constexpr (N == 6) asm volatile("s_waitcnt vmcnt(6)" ::: "memory");
}

// ---------------- rope tables ----------------
__global__ __launch_bounds__(256) void tables_kernel(float* __restrict__ cosT, float* __restrict__ sinT) {
    int i = blockIdx.x * 256 + threadIdx.x;   // 65536 = S*D
    int d = i & 63;
    int s = i >> 6;
    float inv = powf(1.0e6f, -((float)(2 * (d & 31))) / 64.0f);
    float f = (float)s * inv;
    cosT[i] = cosf(f);
    sinT[i] = sinf(f);
}

// ---------------- embedding gather ----------------
__global__ __launch_bounds__(256) void embed_kernel(const int* __restrict__ ids, const float* __restrict__ emb,
                                                    float* __restrict__ x) {
    int m = blockIdx.x;
    int tid = threadIdx.x;
    int id = ids[m];
    const float4* src = (const float4*)(emb + (size_t)id * HDdim);
    ((float4*)(x + (size_t)m * HDdim))[tid] = src[tid];
}

// ---------------- layernorm -> bf16 (+ optional fused router) ----------------
__global__ __launch_bounds__(256) void ln_kernel(const float* __restrict__ x, const float* __restrict__ w,
                                                 const float* __restrict__ bw, unsigned short* __restrict__ outH,
                                                 const float* __restrict__ Wr, float* __restrict__ routerO) {
    int m = blockIdx.x;
    int tid = threadIdx.x;
    float4 a = ((const float4*)(x + (size_t)m * HDdim))[tid];
    float s = a.x + a.y + a.z + a.w;
    #pragma unroll
    for (int o = 1; o < 64; o <<= 1) s += __shfl_xor(s, o);
    __shared__ float red[4], red2[4];
    if ((tid & 63) == 0) red[tid >> 6] = s;
    __syncthreads();
    float mean = (red[0] + red[1] + red[2] + red[3]) * (1.0f / 1024.0f);
    float dx = a.x - mean, dy = a.y - mean, dz = a.z - mean, dw = a.w - mean;
    float s2 = dx * dx + dy * dy + dz * dz + dw * dw;
    #pragma unroll
    for (int o = 1; o < 64; o <<= 1) s2 += __shfl_xor(s2, o);
    if ((tid & 63) == 0) red2[tid >> 6] = s2;
    __syncthreads();
    float var = (red2[0] + red2[1] + red2[2] + red2[3]) * (1.0f / 1024.0f);
    float rs = rsqrtf(var + 1e-6f);
    float4 wv = ((const float4*)w)[tid];
    float4 bv = ((const float4*)bw)[tid];
    float v0 = dx * rs * wv.x + bv.x;
    float v1 = dy * rs * wv.y + bv.y;
    float v2 = dz * rs * wv.z + bv.z;
    float v3 = dw * rs * wv.w + bv.w;
    short4 st = make_short4((short)f2bf(v0), (short)f2bf(v1), (short)f2bf(v2), (short)f2bf(v3));
    *(short4*)(outH + (size_t)m * HDdim + tid * 4) = st;

    if (Wr) {   // fused router: routerO[b][h][s] = h_norm . Wr[:,h]
        __shared__ float rbuf[256][16];
        __shared__ float pbuf[16][17];
        float part[16];
        const float* wr0 = Wr + (size_t)(tid * 4) * Hdim;
        #pragma unroll
        for (int h = 0; h < 16; h++)
            part[h] = v0 * wr0[h] + v1 * wr0[16 + h] + v2 * wr0[32 + h] + v3 * wr0[48 + h];
        #pragma unroll
        for (int h4 = 0; h4 < 4; h4++)
            *(float4*)&rbuf[tid][h4 * 4] = make_float4(part[h4 * 4], part[h4 * 4 + 1], part[h4 * 4 + 2], part[h4 * 4 + 3]);
        __syncthreads();
        {
            int h = tid & 15, g = tid >> 4;
            float sgr = 0.0f;
            #pragma unroll
            for (int i = 0; i < 16; i++) sgr += rbuf[g * 16 + i][h];
            pbuf[g][h] = sgr;
        }
        __syncthreads();
        if (tid < 16) {
            float tot = 0.0f;
            #pragma unroll
            for (int g = 0; g < 16; g++) tot += pbuf[g][tid];
            int b = m >> 10, sI = m & 1023;
            routerO[((size_t)(b * Hdim + tid)) * Sdim + sI] = tot;
        }
    }
}

// ---------------- exact top-k threshold + compacted bias/index ----------------
__global__ __launch_bounds__(1024) void topk_kernel(const float* __restrict__ router, const float* __restrict__ amask,
                                                    float* __restrict__ biasC, int* __restrict__ idxC,
                                                    int* __restrict__ ntA) {
    int bh = blockIdx.x;
    int t = threadIdx.x;
    __shared__ float r[1024];
    __shared__ float kths;
    __shared__ int wcnt[16];
    float v = router[(size_t)bh * Sdim + t];
    r[t] = v;
    __syncthreads();
    int gt = 0, eq = 0;
    for (int j = 0; j < 1024; j++) {
        float xv = r[j];
        gt += (xv > v) ? 1 : 0;
        eq += (xv == v) ? 1 : 0;
    }
    if (gt < 512 && gt + eq >= 512) kths = v;
    // init pad region (ordered before scatter by the barrier below)
    biasC[(size_t)bh * Sdim + t] = -1e9f;
    idxC[(size_t)bh * Sdim + t] = 0;
    __syncthreads();
    float kth = kths;
    bool sel = (v >= kth);
    unsigned long long m = __ballot(sel);
    int wid = t >> 6, lane = t & 63;
    if (lane == 0) wcnt[wid] = __popcll(m);
    __syncthreads();
    int base = 0;
    for (int w = 0; w < wid; w++) base += wcnt[w];
    if (sel) {
        int rank = base + (int)__popcll(m & ((1ull << lane) - 1ull));
        float bias = (v >= 0.0f) ? -log1pf(expf(-v)) : (v - log1pf(expf(v)));
        int b = bh >> 4;
        bias += (1.0f - amask[b * Sdim + t]) * (-1e9f);
        biasC[(size_t)bh * Sdim + rank] = bias;
        idxC[(size_t)bh * Sdim + rank] = t;
    }
    if (t == 0) {
        int tot = 0;
        #pragma unroll
        for (int w = 0; w < 16; w++) tot += wcnt[w];
        ntA[bh] = (tot + 63) >> 6;
    }
}

// ---------------- transpose + f32->bf16 convert: S [K][N] f32 -> D [N][K] bf16 ----------------
__global__ __launch_bounds__(256) void tconv_kernel(const float* __restrict__ S0,
                                                    unsigned short* __restrict__ D, int K, int ldS) {
    __shared__ float t[32][33];
    int kt = blockIdx.y * 32, nt = blockIdx.x * 32;
    int r = threadIdx.x >> 3, c4 = (threadIdx.x & 7) * 4;
    float4 v = *(const float4*)(S0 + (size_t)(kt + r) * ldS + nt + c4);
    t[r][c4] = v.x; t[r][c4 + 1] = v.y; t[r][c4 + 2] = v.z; t[r][c4 + 3] = v.w;
    __syncthreads();
    short4 o = make_short4((short)f2bf(t[c4][r]), (short)f2bf(t[c4 + 1][r]),
                           (short)f2bf(t[c4 + 2][r]), (short)f2bf(t[c4 + 3][r]));
    *(short4*)(D + (size_t)(nt + r) * K + kt + c4) = o;
}

// ---------------- per-layer weight prepass: QKVO + W1 + W2 in one dispatch ----------------
__global__ __launch_bounds__(256) void tconv_layer(const float* __restrict__ Wq, const float* __restrict__ Wk,
                                                   const float* __restrict__ Wv, const float* __restrict__ Wo,
                                                   const float* __restrict__ W1, const float* __restrict__ W2,
                                                   unsigned short* __restrict__ wts) {
    const size_t M1 = 1u << 20;
    int bid = blockIdx.x;
    const float* S;
    unsigned short* D;
    int K, ldS, nt, kt;
    if (bid < 4096) {            // QKVO: 4 x [1024][1024]
        int z = bid >> 10, t = bid & 1023;
        S = (z == 0) ? Wq : (z == 1) ? Wk : (z == 2) ? Wv : Wo;
        D = wts + (size_t)z * M1;
        K = 1024; ldS = 1024; nt = t & 31; kt = t >> 5;
    } else if (bid < 8192) {     // W1: [1024][4096]
        int t = bid - 4096;
        S = W1; D = wts + 4 * M1;
        K = 1024; ldS = 4096; nt = t % 128; kt = t / 128;
    } else {                     // W2: [4096][1024]
        int t = bid - 8192;
        S = W2; D = wts + 8 * M1;
        K = 4096; ldS = 1024; nt = t % 32; kt = t / 32;
    }
    __shared__ float tb[32][33];
    int ktb = kt * 32, ntb = nt * 32;
    int r = threadIdx.x >> 3, c4 = (threadIdx.x & 7) * 4;
    float4 v = *(const float4*)(S + (size_t)(ktb + r) * ldS + ntb + c4);
    tb[r][c4] = v.x; tb[r][c4 + 1] = v.y; tb[r][c4 + 2] = v.z; tb[r][c4 + 3] = v.w;
    __syncthreads();
    short4 o = make_short4((short)f2bf(tb[c4][r]), (short)f2bf(tb[c4 + 1][r]),
                           (short)f2bf(tb[c4 + 2][r]), (short)f2bf(tb[c4 + 3][r]));
    *(short4*)(D + (size_t)(ntb + r) * K + ktb + c4) = o;
}

// ---------------- compacted K / V^T gather ----------------
// kc[bh][j][d] = k16[bh][idx[j]][d]  (chunk XOR-swizzle by j&7 baked in)
// vTc[bh][d][j] = v16[bh][idx[j]][d] (chunk XOR-swizzle by d&7 baked in)
__global__ __launch_bounds__(256) void kvgather_kernel(const unsigned short* __restrict__ k16,
                                                       const unsigned short* __restrict__ v16,
                                                       const int* __restrict__ idxC, const int* __restrict__ ntA,
                                                       unsigned short* __restrict__ kc,
                                                       unsigned short* __restrict__ vTc) {
    int jt = blockIdx.x;        // 16
    int bh = blockIdx.y;        // 32
    if (jt >= ntA[bh]) return;
    __shared__ unsigned short T[64][72];
    int tid = threadIdx.x;
    int jl = tid >> 2;
    int part = tid & 3;
    int j = jt * 64 + jl;
    int src = idxC[(size_t)bh * Sdim + j];
    const unsigned short* kr = k16 + ((size_t)bh * Sdim + src) * Ddim + part * 16;
    bf16x8 k0 = *(const bf16x8*)kr;
    bf16x8 k1 = *(const bf16x8*)(kr + 8);
    int swj = (j & 7) << 3;
    unsigned short* kd = kc + ((size_t)bh * Sdim + j) * Ddim;
    *(bf16x8*)(kd + ((part * 16) ^ swj)) = k0;
    *(bf16x8*)(kd + ((part * 16 + 8) ^ swj)) = k1;
    const unsigned short* vr = v16 + ((size_t)bh * Sdim + src) * Ddim + part * 16;
    *(bf16x8*)&T[jl][part * 16] = *(const bf16x8*)vr;
    *(bf16x8*)&T[jl][part * 16 + 8] = *(const bf16x8*)(vr + 8);
    __syncthreads();
    int d = tid >> 2;
    int xr = (d & 7) << 3;
    unsigned short* dst = vTc + ((size_t)bh * Ddim + d) * Sdim + jt * 64;
    #pragma unroll
    for (int cc = 0; cc < 2; cc++) {
        int tb = (tid & 3) * 16 + cc * 8;
        bf16x8 o;
        #pragma unroll
        for (int i = 0; i < 8; i++) o[i] = (short)T[tb + i][d];
        *(bf16x8*)(dst + (tb ^ xr)) = o;
    }
}

// ================= 8-phase 512-thread MFMA GEMM (T2+T3+T4+T5) =================
// C = A(bf16 [M,ldK]) * Bt(bf16 [N,ldK])^T over K-chunk Kc at offset ks*Kc
// (split-K decoded from flat grid: bid = ks*gridM*gridN + bn*gridM + bm).
// LDS half-major, staged via per-lane interleaved global rows (linear dest),
// XOR-swizzle folded into source col. Counted vmcnt; raw barriers; setprio.
// EPI: 1 = fused QKV (rope->bf16; needs BN/WN==64),
//      3 = bias+silu->bf16, 5 = plain f32, 6 = atomic += (+bias on ks==0 if bias)
template <int EPI, int BM, int BN, int WM, int WN>
__global__ __launch_bounds__(512) void gemm8p(
    const unsigned short* __restrict__ A, const unsigned short* __restrict__ Bt,
    float* __restrict__ OF, unsigned short* __restrict__ Hq, unsigned short* __restrict__ Hk,
    unsigned short* __restrict__ Hv, const float* __restrict__ bias,
    const float* __restrict__ cosT, const float* __restrict__ sinT,
    int Kc, int ldK, int ldC, int gridM, int gridN) {
    constexpr int MI = BM / WM / 16, NI = BN / WN / 16;
    constexpr int MH = MI / 2, NH = NI / 2;
    constexpr int LA = BM / 128, LB = BN / 128;
    constexpr int HA = BM / WM / 2;   // A half-selector
    constexpr int HB = BN / WN / 2;   // B half-selector
    constexpr int ABUF = BM * 64, BBUF = BN * 64;

    __shared__ unsigned short lds[2 * ABUF + 2 * BBUF];

    int bid = blockIdx.x;
    const int nwg = gridDim.x;
    if ((nwg & 7) == 0) bid = (bid & 7) * (nwg >> 3) + (bid >> 3);   // XCD swizzle (bijective: nwg%8==0)
    const int mn = gridM * gridN;
    const int ks = bid / mn;
    const int rem = bid - ks * mn;
    const int bm = (rem % gridM) * BM;
    const int bn = (rem / gridM) * BN;
    const unsigned short* Ap = A + (size_t)ks * Kc;
    const unsigned short* Bp = Bt + (size_t)ks * Kc;

    const int tid = threadIdx.x;
    const int lane = tid & 63, wid = tid >> 6;
    const int lc = lane & 15, lg = lane >> 4;
    const int wwm = wid / WN, wwn = wid % WN;

    const int srow = tid >> 3;                    // 0..63
    const int scol = ((tid & 7) ^ (srow & 7)) * 8;
    const int ak0 = (lg * 8) ^ ((lc & 7) * 8);
    const int ak1 = (32 + lg * 8) ^ ((lc & 7) * 8);

    f32x4 acc[MI][NI];
    f32x4 zero = {0.0f, 0.0f, 0.0f, 0.0f};
    #pragma unroll
    for (int i = 0; i < MI; i++)
        #pragma unroll
        for (int j = 0; j < NI; j++) acc[i][j] = zero;

    bf16x8 a[MH][2], b0[NH][2], b1[NH][2];

    auto stage_a = [&](int half, int nbuf, int kt) {
        #pragma unroll
        for (int j = 0; j < LA; j++) {
            const int idx = j * 64 + srow;                          // [0, BM/2)
            const int grow = (idx / HA) * (BM / WM) + half * HA + (idx % HA);
            const unsigned short* g = Ap + (size_t)(bm + grow) * ldK + kt + scol;
            GLD16(g, &lds[nbuf * ABUF + half * (ABUF / 2) + (j * 512 + tid) * 8]);
        }
    };
    auto stage_b = [&](int half, int nbuf, int kt) {
        #pragma unroll
        for (int j = 0; j < LB; j++) {
            const int idx = j * 64 + srow;                          // [0, BN/2)
            const int grow = (idx / HB) * (BN / WN) + half * HB + (idx % HB);
            const unsigned short* g = Bp + (size_t)(bn + grow) * ldK + kt + scol;
            GLD16(g, &lds[2 * ABUF + nbuf * BBUF + half * (BBUF / 2) + (j * 512 + tid) * 8]);
        }
    };

#define DS_A(mh_, cur_)                                                                   \
    _Pragma("unroll") for (int m = 0; m < MH; m++) {                                      \
        const int ro = (cur_)*ABUF + (mh_) * (ABUF / 2) + (wwm * HA + m * 16 + lc) * 64;  \
        a[m][0] = *(const bf16x8*)&lds[ro + ak0];                                         \
        a[m][1] = *(const bf16x8*)&lds[ro + ak1];                                         \
    }
#define DS_B(bb_, nh_, cur_)                                                              \
    _Pragma("unroll") for (int n = 0; n < NH; n++) {                                      \
        const int ro = 2 * ABUF + (cur_)*BBUF + (nh_) * (BBUF / 2) + (wwn * HB + n * 16 + lc) * 64; \
        bb_[n][0] = *(const bf16x8*)&lds[ro + ak0];                                       \
        bb_[n][1] = *(const bf16x8*)&lds[ro + ak1];                                       \
    }
#define MFMA_PH(mh_, nh_, bb_)                                                            \
    __builtin_amdgcn_s_setprio(1);                                                        \
    _Pragma("unroll") for (int m = 0; m < MH; m++) _Pragma("unroll") for (int n = 0; n < NH; n++) { \
        acc[(mh_)*MH + m][(nh_)*NH + n] = MFMA16(a[m][0], bb_[n][0], acc[(mh_)*MH + m][(nh_)*NH + n]); \
        acc[(mh_)*MH + m][(nh_)*NH + n] = MFMA16(a[m][1], bb_[n][1], acc[(mh_)*MH + m][(nh_)*NH + n]); \
    }                                                                                     \
    __builtin_amdgcn_s_setprio(0);
#define BAR_PRE()                                                                         \
    __builtin_amdgcn_sched_barrier(0);                                                    \
    __builtin_amdgcn_s_barrier();
#define BAR_END()                                                                         \
    asm volatile("" ::: "memory");                                                        \
    __builtin_amdgcn_s_barrier();                                                         \
    __builtin_amdgcn_sched_barrier(0);

    // prologue: tile 0 half-tiles in steady-state order; leave {Bh1,Ah1} in flight
    stage_a(0, 0, 0);
    stage_b(0, 0, 0);
    stage_b(1, 0, 0);
    stage_a(1, 0, 0);
    vwait<LA + LB>();
    BAR_END();

    const int NT = Kc >> 6;
    for (int t = 0; t < NT; t++) {
        const int cur = t & 1, nxt = cur ^ 1;
        const int ktn = (t + 1 < NT) ? (t + 1) * 64 : t * 64;
        // phase 1: quadrant (0,0)
        DS_A(0, cur);
        DS_B(b0, 0, cur);
        stage_a(0, nxt, ktn);
        BAR_PRE();
        MFMA_PH(0, 0, b0);
        vwait<2 * LA>();            // completes B_h1(cur)
        BAR_END();
        // phase 2: quadrant (0,1)
        DS_B(b1, 1, cur);
        stage_b(0, nxt, ktn);
        BAR_PRE();
        MFMA_PH(0, 1, b1);
        vwait<LA + LB>();           // completes A_h1(cur)
        BAR_END();
        // phase 3: quadrant (1,1)
        DS_A(1, cur);
        stage_b(1, nxt, ktn);
        BAR_PRE();
        MFMA_PH(1, 1, b1);
        BAR_END();
        // phase 4: quadrant (1,0)
        stage_a(1, nxt, ktn);
        BAR_PRE();
        MFMA_PH(1, 0, b0);
        vwait<LA + LB>();           // completes A_h0, B_h0 of nxt
        BAR_END();
    }
    asm volatile("s_waitcnt vmcnt(0)" ::: "memory");   // drain LDS-destined loads before endpgm
#undef DS_A
#undef DS_B
#undef MFMA_PH
#undef BAR_PRE
#undef BAR_END

    // epilogue. D frag layout: row = lg*4 + r, col = lc
    #pragma unroll
    for (int i = 0; i < MI; i++) {
        if (EPI == 1) {
            const int colbase = bn + wwn * (BN / WN);
            const int zc = colbase >> 10;                 // 0=q 1=k 2=v
            unsigned short* OH = (zc == 0) ? Hq : (zc == 1) ? Hk : Hv;
            const int hcol = (colbase >> 6) & 15;
            #pragma unroll
            for (int r = 0; r < 4; r++) {
                int row = bm + wwm * (BM / WM) + i * 16 + lg * 4 + r;
                int b = row >> 10, s = row & 1023;
                size_t base = ((size_t)(b * Hdim + hcol) * Sdim + s) << 6;
                if (zc == 2) {
                    #pragma unroll
                    for (int j = 0; j < 4; j++) OH[base + j * 16 + lc] = f2bf(acc[i][j][r]);
                } else {
                    #pragma unroll
                    for (int j = 0; j < 2; j++) {
                        int d = j * 16 + lc;              // [0,32)
                        float x1 = acc[i][j][r];
                        float x2 = acc[i][j + 2][r];
                        float c = cosT[s * 64 + d];
                        float sn = sinT[s * 64 + d];
                        OH[base + d] = f2bf(x1 * c - x2 * sn);
                        OH[base + d + 32] = f2bf(x2 * c + x1 * sn);
                    }
                }
            }
        } else {
            #pragma unroll
            for (int r = 0; r < 4; r++) {
                int row = bm + wwm * (BM / WM) + i * 16 + lg * 4 + r;
                #pragma unroll
                for (int j = 0; j < NI; j++) {
                    int col = bn + wwn * (BN / WN) + j * 16 + lc;
                    float v = acc[i][j][r];
                    if (EPI == 3) {
                        float t = v + bias[col];
                        Hq[(size_t)row * ldC + col] = f2bf(t / (1.0f + expf(-t)));
                    } else if (EPI == 6) {
                        if (ks == 0 && bias != nullptr) v += bias[col];
                        unsafeAtomicAdd(&OF[(size_t)row * ldC + col], v);
                    } else {
                        OF[(size_t)row * ldC + col] = v;
                    }
                }
            }
        }
    }
}

// ---------------- flash attention over compacted keys (routed bias) ----------------
__global__ __launch_bounds__(256) void attn_kernel(const unsigned short* __restrict__ q16,
                                                   const unsigned short* __restrict__ kc,
                                                   const unsigned short* __restrict__ vTc,
                                                   const float* __restrict__ biasC,
                                                   const int* __restrict__ ntA,
                                                   unsigned short* __restrict__ o16) {
    const int qb = blockIdx.x;   // 16 (64 q rows each)
    const int bh = blockIdx.y;   // 32
    const int tid = threadIdx.x;
    const int w = tid >> 6, lane = tid & 63;
    const int lg = lane >> 4, lc = lane & 15;
    const int nt = ntA[bh];

    __shared__ unsigned short Ks[2][64 * 64];
    __shared__ unsigned short Vs[2][64 * 64];
    __shared__ unsigned short Pq[4][16][72];
    __shared__ float sbAll[1024];

    {
        const float4 bv = ((const float4*)(biasC + (size_t)bh * Sdim))[tid];
        *(float4*)&sbAll[tid * 4] = bv;
    }

    const int qrow = qb * 64 + w * 16 + lc;
    const unsigned short* qbase = q16 + ((size_t)bh * Sdim + qrow) * Ddim;
    bf16x8 qf[2];
    qf[0] = *(const bf16x8*)(qbase + lg * 8);
    qf[1] = *(const bf16x8*)(qbase + 32 + lg * 8);

    const int grow = tid >> 3;
    const int gc = (tid & 7) * 8;
    const unsigned short* kbase = kc + (size_t)bh * Sdim * Ddim;
    const unsigned short* vbase = vTc + (size_t)bh * Ddim * Sdim;

    {
        const unsigned short* kg = kbase + (size_t)grow * Ddim + gc;
        GLD16(kg, &Ks[0][tid * 8]);
        GLD16(kg + 32 * Ddim, &Ks[0][2048 + tid * 8]);
        const unsigned short* vg = vbase + (size_t)grow * Sdim + gc;
        GLD16(vg, &Vs[0][tid * 8]);
        GLD16(vg + 32 * Sdim, &Vs[0][2048 + tid * 8]);
    }
    __syncthreads();

    float m_i = -1e30f, l_i = 0.0f;
    f32x4 ot[4];
    f32x4 zero = {0.0f, 0.0f, 0.0f, 0.0f};
    #pragma unroll
    for (int fd = 0; fd < 4; fd++) ot[fd] = zero;

    const int sw = (lc & 7) << 3;

    for (int tt = 0; tt < nt; tt++) {
        const int cur = tt & 1;
        if (tt > 0) {
            asm volatile("s_waitcnt vmcnt(0)" ::: "memory");
            __builtin_amdgcn_sched_barrier(0);
            __builtin_amdgcn_s_barrier();
        }
        if (tt < nt - 1) {
            const int t1 = (tt + 1) * 64;
            const unsigned short* kg = kbase + (size_t)(t1 + grow) * Ddim + gc;
            GLD16(kg, &Ks[cur ^ 1][tid * 8]);
            GLD16(kg + 32 * Ddim, &Ks[cur ^ 1][2048 + tid * 8]);
            const unsigned short* vg = vbase + (size_t)grow * Sdim + t1 + gc;
            GLD16(vg, &Vs[cur ^ 1][tid * 8]);
            GLD16(vg + 32 * Sdim, &Vs[cur ^ 1][2048 + tid * 8]);
        }

        f32x4 sf[4];
        #pragma unroll
        for (int f = 0; f < 4; f++) {
            const int trow = f * 16 + lc;
            f32x4 a = zero;
            #pragma unroll
            for (int ks = 0; ks < 2; ks++) {
                bf16x8 kfr = *(bf16x8*)&Ks[cur][trow * 64 + ((ks * 32 + lg * 8) ^ sw)];
                a = MFMA16(kfr, qf[ks], a);
            }
            sf[f] = a;
        }
        const int t0 = tt * 64;
        float tmax = -1e30f;
        #pragma unroll
        for (int f = 0; f < 4; f++)
            #pragma unroll
            for (int j = 0; j < 4; j++) {
                float v = sf[f][j] * 0.125f + sbAll[t0 + f * 16 + lg * 4 + j];
                sf[f][j] = v;
                tmax = fmaxf(tmax, v);
            }
        tmax = fmaxf(tmax, __shfl_xor(tmax, 16));
        tmax = fmaxf(tmax, __shfl_xor(tmax, 32));
        float mnew = fmaxf(m_i, tmax);
        float alpha = expf(m_i - mnew);
        float lsum = 0.0f;
        #pragma unroll
        for (int f = 0; f < 4; f++)
            #pragma unroll
            for (int j = 0; j < 4; j++) {
                float p = expf(sf[f][j] - mnew);
                sf[f][j] = p;
                lsum += p;
            }
        lsum += __shfl_xor(lsum, 16);
        lsum += __shfl_xor(lsum, 32);
        l_i = l_i * alpha + lsum;
        m_i = mnew;
        #pragma unroll
        for (int fd = 0; fd < 4; fd++)
            #pragma unroll
            for (int j = 0; j < 4; j++) ot[fd][j] *= alpha;
        #pragma unroll
        for (int f = 0; f < 4; f++) {
            short4 ps = make_short4((short)f2bf(sf[f][0]), (short)f2bf(sf[f][1]),
                                    (short)f2bf(sf[f][2]), (short)f2bf(sf[f][3]));
            *(short4*)&Pq[w][lc][f * 16 + lg * 4] = ps;
        }
        #pragma unroll
        for (int ks = 0; ks < 2; ks++) {
            bf16x8 pf = *(bf16x8*)&Pq[w][lc][ks * 32 + lg * 8];
            #pragma unroll
            for (int fd = 0; fd < 4; fd++) {
                bf16x8 vfr = *(bf16x8*)&Vs[cur][(fd * 16 + lc) * 64 + ((ks * 32 + lg * 8) ^ sw)];
                ot[fd] = MFMA16(vfr, pf, ot[fd]);
            }
        }
    }
    asm volatile("s_waitcnt vmcnt(0)" ::: "memory");   // drain LDS-destined loads before endpgm
    float rl = 1.0f / l_i;
    int b = bh >> 4, h = bh & 15;
    #pragma unroll
    for (int fd = 0; fd < 4; fd++)
        #pragma unroll
        for (int j = 0; j < 4; j++) {
            int d = fd * 16 + lg * 4 + j;
            o16[((size_t)b * Sdim + qrow) * HDdim + h * 64 + d] = f2bf(ot[fd][j] * rl);
        }
}

extern "C" void kernel_launch(void* const* d_in, const int* in_sizes, int n_in,
                              void* d_out, int out_size, void* d_ws, size_t ws_size,
                              hipStream_t stream) {
    const int* ids = (const int*)d_in[0];
    const float* amask = (const float*)d_in[1];
    const float* emb = (const float*)d_in[2];
    const float* ln1w = (const float*)d_in[3];
    const float* ln1b = (const float*)d_in[4];
    const float* Wq = (const float*)d_in[5];
    const float* Wk = (const float*)d_in[6];
    const float* Wv = (const float*)d_in[7];
    const float* Wo = (const float*)d_in[8];
    const float* Wr = (const float*)d_in[9];
    const float* ln2w = (const float*)d_in[10];
    const float* ln2b = (const float*)d_in[11];
    const float* W1 = (const float*)d_in[12];
    const float* b1 = (const float*)d_in[13];
    const float* W2 = (const float*)d_in[14];
    const float* b2 = (const float*)d_in[15];
    const float* nw = (const float*)d_in[16];
    const float* nb = (const float*)d_in[17];
    const float* lmh = (const float*)d_in[18];
    float* out = (float*)d_out;

    char* p = (char*)d_ws;
    size_t off = 0;
    auto alloc = [&](size_t bytes) -> void* {
        void* r = p + off;
        off += (bytes + 255) & ~(size_t)255;
        return r;
    };
    float* cosT = (float*)alloc((size_t)Sdim * Ddim * 4);
    float* sinT = (float*)alloc((size_t)Sdim * Ddim * 4);
    float* x = (float*)alloc((size_t)BSdim * HDdim * 4);
    unsigned short* h16 = (unsigned short*)alloc((size_t)BSdim * HDdim * 2);
    unsigned short* o16 = (unsigned short*)alloc((size_t)BSdim * HDdim * 2);
    unsigned short* m16 = (unsigned short*)alloc((size_t)BSdim * Idim * 2);
    unsigned short* q16 = (unsigned short*)alloc((size_t)Bdim * Hdim * Sdim * Ddim * 2);
    unsigned short* k16 = (unsigned short*)alloc((size_t)Bdim * Hdim * Sdim * Ddim * 2);
    unsigned short* v16 = (unsigned short*)alloc((size_t)Bdim * Hdim * Sdim * Ddim * 2);
    unsigned short* kcs = (unsigned short*)alloc((size_t)Bdim * Hdim * Sdim * Ddim * 2);
    unsigned short* vTc = (unsigned short*)alloc((size_t)Bdim * Hdim * Sdim * Ddim * 2);
    float* router = (float*)alloc((size_t)Bdim * Hdim * Sdim * 4);
    float* biasC = (float*)alloc((size_t)Bdim * Hdim * Sdim * 4);
    int* idxC = (int*)alloc((size_t)Bdim * Hdim * Sdim * 4);
    int* ntA = (int*)alloc((size_t)Bdim * Hdim * 4);
    unsigned short* wts = (unsigned short*)alloc((size_t)Vdim * HDdim * 2);  // 64MB reuse buffer

    const size_t M1 = 1u << 20;  // 1M elems

    tables_kernel<<<256, 256, 0, stream>>>(cosT, sinT);
    embed_kernel<<<BSdim, 256, 0, stream>>>(ids, emb, x);

    for (int l = 0; l < Ldim; l++) {
        const float* Wq_l = Wq + (size_t)l * HDdim * HDdim;
        const float* Wk_l = Wk + (size_t)l * HDdim * HDdim;
        const float* Wv_l = Wv + (size_t)l * HDdim * HDdim;
        const float* Wo_l = Wo + (size_t)l * HDdim * HDdim;
        const float* Wr_l = Wr + (size_t)l * HDdim * Hdim;
        const float* W1_l = W1 + (size_t)l * HDdim * Idim;
        const float* W2_l = W2 + (size_t)l * Idim * HDdim;
        const float* b1_l = b1 + (size_t)l * Idim;
        const float* b2_l = b2 + (size_t)l * HDdim;

        // weight prepass (single dispatch): QKVO -> wts[0..4M), W1t -> [4M..8M), W2t -> [8M..12M)
        tconv_layer<<<12288, 256, 0, stream>>>(Wq_l, Wk_l, Wv_l, Wo_l, W1_l, W2_l, wts);

        // ln1 with fused router
        ln_kernel<<<BSdim, 256, 0, stream>>>(x, ln1w + l * HDdim, ln1b + l * HDdim, h16, Wr_l, router);
        topk_kernel<<<Bdim * Hdim, 1024, 0, stream>>>(router, amask, biasC, idxC, ntA);
        // fused QKV GEMM (8-phase, 128x128, 8-wave): grid 16 x 24 = 384
        gemm8p<1, 128, 128, 4, 2><<<384, 512, 0, stream>>>(h16, wts, nullptr, q16, k16, v16,
                                                           nullptr, cosT, sinT, HDdim, HDdim, 0, 16, 24);
        // compacted K / V^T gather (sparsity: ~8 of 16 tiles survive)
        kvgather_kernel<<<dim3(16, 32), 256, 0, stream>>>(k16, v16, idxC, ntA, kcs, vTc);
        attn_kernel<<<dim3(16, 32), 256, 0, stream>>>(q16, kcs, vTc, biasC, ntA, o16);
        // Wo GEMM (8-phase, split-K=2, atomic residual add): grid 16 x 8 x 2 = 256
        gemm8p<6, 128, 128, 4, 2><<<256, 512, 0, stream>>>(o16, wts + 3 * M1, x, nullptr, nullptr, nullptr,
                                                           nullptr, nullptr, nullptr, 512, HDdim, HDdim, 16, 8);
        ln_kernel<<<BSdim, 256, 0, stream>>>(x, ln2w + l * HDdim, ln2b + l * HDdim, h16, nullptr, nullptr);
        // W1 GEMM (8-phase): grid 8 x 32 = 256
        gemm8p<3, 256, 128, 4, 2><<<256, 512, 0, stream>>>(h16, wts + 4 * M1, nullptr, m16, nullptr, nullptr,
                                                           b1_l, nullptr, nullptr, HDdim, HDdim, Idim, 8, 32);
        // W2 GEMM (8-phase, split-K=4 x 1024, atomic accumulate into residual): grid 8 x 8 x 4 = 256
        gemm8p<6, 256, 128, 4, 2><<<256, 512, 0, stream>>>(m16, wts + 8 * M1, x, nullptr, nullptr, nullptr,
                                                           b2_l, nullptr, nullptr, 1024, Idim, HDdim, 8, 8);
    }

    ln_kernel<<<BSdim, 256, 0, stream>>>(x, nw, nb, h16, nullptr, nullptr);
    // lm_head: one tconv (32000x1024 bf16, 64MB) + one 8-phase GEMM (grid 8 x 125)
    tconv_kernel<<<dim3(1000, 32, 1), 256, 0, stream>>>(lmh, wts, HDdim, Vdim);
    gemm8p<5, 256, 256, 2, 4><<<1000, 512, 0, stream>>>(h16, wts, out, nullptr, nullptr, nullptr,
                                                        nullptr, nullptr, nullptr, HDdim, HDdim, Vdim, 8, 125);
}

// Round 8
// 1036.339 us; speedup vs baseline: 2.1110x; 1.0336x over previous
//
#include <hip/hip_runtime.h>
#include <hip/hip_bf16.h>

#define Bdim 2
#define Sdim 1024
#define Vdim 32000
#define HDdim 1024
#define Ldim 4
#define Hdim 16
#define Ddim 64
#define Idim 4096
#define BSdim 2048

typedef __attribute__((ext_vector_type(8))) short bf16x8;
typedef __attribute__((ext_vector_type(4))) float f32x4;

__device__ __forceinline__ unsigned short f2bf(float f) {
    __hip_bfloat16 h = __float2bfloat16(f);
    return *reinterpret_cast<unsigned short*>(&h);
}

#define MFMA16(a, b, c) __builtin_amdgcn_mfma_f32_16x16x32_bf16((a), (b), (c), 0, 0, 0)

#define GLD16(gp, lp)                                                            \
    __builtin_amdgcn_global_load_lds((const __attribute__((address_space(1))) void*)(gp), \
                                     (__attribute__((address_space(3))) void*)(lp), 16, 0, 0)

template <int N>
__device__ __forceinline__ void vwait() {
    if constexpr (N == 2) asm volatile("s_waitcnt vmcnt(2)" ::: "memory");
    else if constexpr (N == 3) asm volatile("s_waitcnt vmcnt(3)" ::: "memory");
    else if constexpr (N == 4) asm volatile("s_waitcnt vmcnt(4)" ::: "memory");
    else if constexpr (N == 6) asm volatile("s_waitcnt vmcnt(6)" ::: "memory");
}

// ---------------- rope tables ----------------
__global__ __launch_bounds__(256) void tables_kernel(float* __restrict__ cosT, float* __restrict__ sinT) {
    int i = blockIdx.x * 256 + threadIdx.x;   // 65536 = S*D
    int d = i & 63;
    int s = i >> 6;
    float inv = powf(1.0e6f, -((float)(2 * (d & 31))) / 64.0f);
    float f = (float)s * inv;
    cosT[i] = cosf(f);
    sinT[i] = sinf(f);
}

// ---------------- embedding gather ----------------
__global__ __launch_bounds__(256) void embed_kernel(const int* __restrict__ ids, const float* __restrict__ emb,
                                                    float* __restrict__ x) {
    int m = blockIdx.x;
    int tid = threadIdx.x;
    int id = ids[m];
    const float4* src = (const float4*)(emb + (size_t)id * HDdim);
    ((float4*)(x + (size_t)m * HDdim))[tid] = src[tid];
}

// ---------------- layernorm -> bf16 (+ optional fused router) ----------------
__global__ __launch_bounds__(256) void ln_kernel(const float* __restrict__ x, const float* __restrict__ w,
                                                 const float* __restrict__ bw, unsigned short* __restrict__ outH,
                                                 const float* __restrict__ Wr, float* __restrict__ routerO) {
    int m = blockIdx.x;
    int tid = threadIdx.x;
    float4 a = ((const float4*)(x + (size_t)m * HDdim))[tid];
    float s = a.x + a.y + a.z + a.w;
    #pragma unroll
    for (int o = 1; o < 64; o <<= 1) s += __shfl_xor(s, o);
    __shared__ float red[4], red2[4];
    if ((tid & 63) == 0) red[tid >> 6] = s;
    __syncthreads();
    float mean = (red[0] + red[1] + red[2] + red[3]) * (1.0f / 1024.0f);
    float dx = a.x - mean, dy = a.y - mean, dz = a.z - mean, dw = a.w - mean;
    float s2 = dx * dx + dy * dy + dz * dz + dw * dw;
    #pragma unroll
    for (int o = 1; o < 64; o <<= 1) s2 += __shfl_xor(s2, o);
    if ((tid & 63) == 0) red2[tid >> 6] = s2;
    __syncthreads();
    float var = (red2[0] + red2[1] + red2[2] + red2[3]) * (1.0f / 1024.0f);
    float rs = rsqrtf(var + 1e-6f);
    float4 wv = ((const float4*)w)[tid];
    float4 bv = ((const float4*)bw)[tid];
    float v0 = dx * rs * wv.x + bv.x;
    float v1 = dy * rs * wv.y + bv.y;
    float v2 = dz * rs * wv.z + bv.z;
    float v3 = dw * rs * wv.w + bv.w;
    short4 st = make_short4((short)f2bf(v0), (short)f2bf(v1), (short)f2bf(v2), (short)f2bf(v3));
    *(short4*)(outH + (size_t)m * HDdim + tid * 4) = st;

    if (Wr) {   // fused router: routerO[b][h][s] = h_norm . Wr[:,h]
        __shared__ float rbuf[256][16];
        __shared__ float pbuf[16][17];
        float part[16];
        const float* wr0 = Wr + (size_t)(tid * 4) * Hdim;
        #pragma unroll
        for (int h = 0; h < 16; h++)
            part[h] = v0 * wr0[h] + v1 * wr0[16 + h] + v2 * wr0[32 + h] + v3 * wr0[48 + h];
        #pragma unroll
        for (int h4 = 0; h4 < 4; h4++)
            *(float4*)&rbuf[tid][h4 * 4] = make_float4(part[h4 * 4], part[h4 * 4 + 1], part[h4 * 4 + 2], part[h4 * 4 + 3]);
        __syncthreads();
        {
            int h = tid & 15, g = tid >> 4;
            float sgr = 0.0f;
            #pragma unroll
            for (int i = 0; i < 16; i++) sgr += rbuf[g * 16 + i][h];
            pbuf[g][h] = sgr;
        }
        __syncthreads();
        if (tid < 16) {
            float tot = 0.0f;
            #pragma unroll
            for (int g = 0; g < 16; g++) tot += pbuf[g][tid];
            int b = m >> 10, sI = m & 1023;
            routerO[((size_t)(b * Hdim + tid)) * Sdim + sI] = tot;
        }
    }
}

// ---------------- exact top-k threshold + compacted bias/index ----------------
__global__ __launch_bounds__(1024) void topk_kernel(const float* __restrict__ router, const float* __restrict__ amask,
                                                    float* __restrict__ biasC, int* __restrict__ idxC,
                                                    int* __restrict__ ntA) {
    int bh = blockIdx.x;
    int t = threadIdx.x;
    __shared__ float r[1024];
    __shared__ float kths;
    __shared__ int wcnt[16];
    float v = router[(size_t)bh * Sdim + t];
    r[t] = v;
    __syncthreads();
    int gt = 0, eq = 0;
    for (int j = 0; j < 1024; j++) {
        float xv = r[j];
        gt += (xv > v) ? 1 : 0;
        eq += (xv == v) ? 1 : 0;
    }
    if (gt < 512 && gt + eq >= 512) kths = v;
    // init pad region (ordered before scatter by the barrier below)
    biasC[(size_t)bh * Sdim + t] = -1e9f;
    idxC[(size_t)bh * Sdim + t] = 0;
    __syncthreads();
    float kth = kths;
    bool sel = (v >= kth);
    unsigned long long m = __ballot(sel);
    int wid = t >> 6, lane = t & 63;
    if (lane == 0) wcnt[wid] = __popcll(m);
    __syncthreads();
    int base = 0;
    for (int w = 0; w < wid; w++) base += wcnt[w];
    if (sel) {
        int rank = base + (int)__popcll(m & ((1ull << lane) - 1ull));
        float bias = (v >= 0.0f) ? -log1pf(expf(-v)) : (v - log1pf(expf(v)));
        int b = bh >> 4;
        bias += (1.0f - amask[b * Sdim + t]) * (-1e9f);
        biasC[(size_t)bh * Sdim + rank] = bias;
        idxC[(size_t)bh * Sdim + rank] = t;
    }
    if (t == 0) {
        int tot = 0;
        #pragma unroll
        for (int w = 0; w < 16; w++) tot += wcnt[w];
        ntA[bh] = (tot + 63) >> 6;
    }
}

// ---------------- transpose + f32->bf16 convert: S [K][N] f32 -> D [N][K] bf16 ----------------
__global__ __launch_bounds__(256) void tconv_kernel(const float* __restrict__ S0,
                                                    unsigned short* __restrict__ D, int K, int ldS) {
    __shared__ float t[32][33];
    int kt = blockIdx.y * 32, nt = blockIdx.x * 32;
    int r = threadIdx.x >> 3, c4 = (threadIdx.x & 7) * 4;
    float4 v = *(const float4*)(S0 + (size_t)(kt + r) * ldS + nt + c4);
    t[r][c4] = v.x; t[r][c4 + 1] = v.y; t[r][c4 + 2] = v.z; t[r][c4 + 3] = v.w;
    __syncthreads();
    short4 o = make_short4((short)f2bf(t[c4][r]), (short)f2bf(t[c4 + 1][r]),
                           (short)f2bf(t[c4 + 2][r]), (short)f2bf(t[c4 + 3][r]));
    *(short4*)(D + (size_t)(nt + r) * K + kt + c4) = o;
}

// ---------------- per-layer weight prepass: QKVO + W1 + W2 in one dispatch ----------------
__global__ __launch_bounds__(256) void tconv_layer(const float* __restrict__ Wq, const float* __restrict__ Wk,
                                                   const float* __restrict__ Wv, const float* __restrict__ Wo,
                                                   const float* __restrict__ W1, const float* __restrict__ W2,
                                                   unsigned short* __restrict__ wts) {
    const size_t M1 = 1u << 20;
    int bid = blockIdx.x;
    const float* S;
    unsigned short* D;
    int K, ldS, nt, kt;
    if (bid < 4096) {            // QKVO: 4 x [1024][1024]
        int z = bid >> 10, t = bid & 1023;
        S = (z == 0) ? Wq : (z == 1) ? Wk : (z == 2) ? Wv : Wo;
        D = wts + (size_t)z * M1;
        K = 1024; ldS = 1024; nt = t & 31; kt = t >> 5;
    } else if (bid < 8192) {     // W1: [1024][4096]
        int t = bid - 4096;
        S = W1; D = wts + 4 * M1;
        K = 1024; ldS = 4096; nt = t % 128; kt = t / 128;
    } else {                     // W2: [4096][1024]
        int t = bid - 8192;
        S = W2; D = wts + 8 * M1;
        K = 4096; ldS = 1024; nt = t % 32; kt = t / 32;
    }
    __shared__ float tb[32][33];
    int ktb = kt * 32, ntb = nt * 32;
    int r = threadIdx.x >> 3, c4 = (threadIdx.x & 7) * 4;
    float4 v = *(const float4*)(S + (size_t)(ktb + r) * ldS + ntb + c4);
    tb[r][c4] = v.x; tb[r][c4 + 1] = v.y; tb[r][c4 + 2] = v.z; tb[r][c4 + 3] = v.w;
    __syncthreads();
    short4 o = make_short4((short)f2bf(tb[c4][r]), (short)f2bf(tb[c4 + 1][r]),
                           (short)f2bf(tb[c4 + 2][r]), (short)f2bf(tb[c4 + 3][r]));
    *(short4*)(D + (size_t)(ntb + r) * K + ktb + c4) = o;
}

// ---------------- compacted K / V^T gather ----------------
__global__ __launch_bounds__(256) void kvgather_kernel(const unsigned short* __restrict__ k16,
                                                       const unsigned short* __restrict__ v16,
                                                       const int* __restrict__ idxC, const int* __restrict__ ntA,
                                                       unsigned short* __restrict__ kc,
                                                       unsigned short* __restrict__ vTc) {
    int jt = blockIdx.x;        // 16
    int bh = blockIdx.y;        // 32
    if (jt >= ntA[bh]) return;
    __shared__ unsigned short T[64][72];
    int tid = threadIdx.x;
    int jl = tid >> 2;
    int part = tid & 3;
    int j = jt * 64 + jl;
    int src = idxC[(size_t)bh * Sdim + j];
    const unsigned short* kr = k16 + ((size_t)bh * Sdim + src) * Ddim + part * 16;
    bf16x8 k0 = *(const bf16x8*)kr;
    bf16x8 k1 = *(const bf16x8*)(kr + 8);
    int swj = (j & 7) << 3;
    unsigned short* kd = kc + ((size_t)bh * Sdim + j) * Ddim;
    *(bf16x8*)(kd + ((part * 16) ^ swj)) = k0;
    *(bf16x8*)(kd + ((part * 16 + 8) ^ swj)) = k1;
    const unsigned short* vr = v16 + ((size_t)bh * Sdim + src) * Ddim + part * 16;
    *(bf16x8*)&T[jl][part * 16] = *(const bf16x8*)vr;
    *(bf16x8*)&T[jl][part * 16 + 8] = *(const bf16x8*)(vr + 8);
    __syncthreads();
    int d = tid >> 2;
    int xr = (d & 7) << 3;
    unsigned short* dst = vTc + ((size_t)bh * Ddim + d) * Sdim + jt * 64;
    #pragma unroll
    for (int cc = 0; cc < 2; cc++) {
        int tb = (tid & 3) * 16 + cc * 8;
        bf16x8 o;
        #pragma unroll
        for (int i = 0; i < 8; i++) o[i] = (short)T[tb + i][d];
        *(bf16x8*)(dst + (tb ^ xr)) = o;
    }
}

// ================= 8-phase 512-thread MFMA GEMM (T2+T3+T4+T5) =================
// C = A(bf16 [M,ldK]) * Bt(bf16 [N,ldK])^T over K-chunk Kc at offset ks*Kc
// (split-K decoded from flat grid: bid = ks*gridM*gridN + bn*gridM + bm).
// LDS half-major, staged via per-lane interleaved global rows (linear dest),
// XOR-swizzle folded into source col. Counted vmcnt; raw barriers; setprio.
// EPI: 1 = fused QKV (rope->bf16; needs BN/WN==64),
//      3 = bias+silu->bf16, 5 = plain f32, 6 = atomic += (+bias on ks==0 if bias)
template <int EPI, int BM, int BN, int WM, int WN>
__global__ __launch_bounds__(512) void gemm8p(
    const unsigned short* __restrict__ A, const unsigned short* __restrict__ Bt,
    float* __restrict__ OF, unsigned short* __restrict__ Hq, unsigned short* __restrict__ Hk,
    unsigned short* __restrict__ Hv, const float* __restrict__ bias,
    const float* __restrict__ cosT, const float* __restrict__ sinT,
    int Kc, int ldK, int ldC, int gridM, int gridN) {
    constexpr int MI = BM / WM / 16, NI = BN / WN / 16;
    constexpr int MH = MI / 2, NH = NI / 2;
    constexpr int LA = BM / 128, LB = BN / 128;
    constexpr int HA = BM / WM / 2;   // A half-selector
    constexpr int HB = BN / WN / 2;   // B half-selector
    constexpr int ABUF = BM * 64, BBUF = BN * 64;

    __shared__ unsigned short lds[2 * ABUF + 2 * BBUF];

    int bid = blockIdx.x;
    const int nwg = gridDim.x;
    if ((nwg & 7) == 0) bid = (bid & 7) * (nwg >> 3) + (bid >> 3);   // XCD swizzle (bijective: nwg%8==0)
    const int mn = gridM * gridN;
    const int ks = bid / mn;
    const int rem = bid - ks * mn;
    const int bm = (rem % gridM) * BM;
    const int bn = (rem / gridM) * BN;
    const unsigned short* Ap = A + (size_t)ks * Kc;
    const unsigned short* Bp = Bt + (size_t)ks * Kc;

    const int tid = threadIdx.x;
    const int lane = tid & 63, wid = tid >> 6;
    const int lc = lane & 15, lg = lane >> 4;
    const int wwm = wid / WN, wwn = wid % WN;

    const int srow = tid >> 3;                    // 0..63
    const int scol = ((tid & 7) ^ (srow & 7)) * 8;
    const int ak0 = (lg * 8) ^ ((lc & 7) * 8);
    const int ak1 = (32 + lg * 8) ^ ((lc & 7) * 8);

    f32x4 acc[MI][NI];
    f32x4 zero = {0.0f, 0.0f, 0.0f, 0.0f};
    #pragma unroll
    for (int i = 0; i < MI; i++)
        #pragma unroll
        for (int j = 0; j < NI; j++) acc[i][j] = zero;

    bf16x8 a[MH][2], b0[NH][2], b1[NH][2];

    auto stage_a = [&](int half, int nbuf, int kt) {
        #pragma unroll
        for (int j = 0; j < LA; j++) {
            const int idx = j * 64 + srow;                          // [0, BM/2)
            const int grow = (idx / HA) * (BM / WM) + half * HA + (idx % HA);
            const unsigned short* g = Ap + (size_t)(bm + grow) * ldK + kt + scol;
            GLD16(g, &lds[nbuf * ABUF + half * (ABUF / 2) + (j * 512 + tid) * 8]);
        }
    };
    auto stage_b = [&](int half, int nbuf, int kt) {
        #pragma unroll
        for (int j = 0; j < LB; j++) {
            const int idx = j * 64 + srow;                          // [0, BN/2)
            const int grow = (idx / HB) * (BN / WN) + half * HB + (idx % HB);
            const unsigned short* g = Bp + (size_t)(bn + grow) * ldK + kt + scol;
            GLD16(g, &lds[2 * ABUF + nbuf * BBUF + half * (BBUF / 2) + (j * 512 + tid) * 8]);
        }
    };

#define DS_A(mh_, cur_)                                                                   \
    _Pragma("unroll") for (int m = 0; m < MH; m++) {                                      \
        const int ro = (cur_)*ABUF + (mh_) * (ABUF / 2) + (wwm * HA + m * 16 + lc) * 64;  \
        a[m][0] = *(const bf16x8*)&lds[ro + ak0];                                         \
        a[m][1] = *(const bf16x8*)&lds[ro + ak1];                                         \
    }
#define DS_B(bb_, nh_, cur_)                                                              \
    _Pragma("unroll") for (int n = 0; n < NH; n++) {                                      \
        const int ro = 2 * ABUF + (cur_)*BBUF + (nh_) * (BBUF / 2) + (wwn * HB + n * 16 + lc) * 64; \
        bb_[n][0] = *(const bf16x8*)&lds[ro + ak0];                                       \
        bb_[n][1] = *(const bf16x8*)&lds[ro + ak1];                                       \
    }
#define MFMA_PH(mh_, nh_, bb_)                                                            \
    __builtin_amdgcn_s_setprio(1);                                                        \
    _Pragma("unroll") for (int m = 0; m < MH; m++) _Pragma("unroll") for (int n = 0; n < NH; n++) { \
        acc[(mh_)*MH + m][(nh_)*NH + n] = MFMA16(a[m][0], bb_[n][0], acc[(mh_)*MH + m][(nh_)*NH + n]); \
        acc[(mh_)*MH + m][(nh_)*NH + n] = MFMA16(a[m][1], bb_[n][1], acc[(mh_)*MH + m][(nh_)*NH + n]); \
    }                                                                                     \
    __builtin_amdgcn_s_setprio(0);
#define BAR_PRE()                                                                         \
    __builtin_amdgcn_sched_barrier(0);                                                    \
    __builtin_amdgcn_s_barrier();
#define BAR_END()                                                                         \
    asm volatile("" ::: "memory");                                                        \
    __builtin_amdgcn_s_barrier();                                                         \
    __builtin_amdgcn_sched_barrier(0);

    // prologue: tile 0 half-tiles in steady-state order; leave {Bh1,Ah1} in flight
    stage_a(0, 0, 0);
    stage_b(0, 0, 0);
    stage_b(1, 0, 0);
    stage_a(1, 0, 0);
    vwait<LA + LB>();
    BAR_END();

    const int NT = Kc >> 6;
    for (int t = 0; t < NT; t++) {
        const int cur = t & 1, nxt = cur ^ 1;
        const int ktn = (t + 1 < NT) ? (t + 1) * 64 : t * 64;
        // phase 1: quadrant (0,0)
        DS_A(0, cur);
        DS_B(b0, 0, cur);
        stage_a(0, nxt, ktn);
        BAR_PRE();
        MFMA_PH(0, 0, b0);
        vwait<2 * LA>();            // completes B_h1(cur)
        BAR_END();
        // phase 2: quadrant (0,1)
        DS_B(b1, 1, cur);
        stage_b(0, nxt, ktn);
        BAR_PRE();
        MFMA_PH(0, 1, b1);
        vwait<LA + LB>();           // completes A_h1(cur)
        BAR_END();
        // phase 3: quadrant (1,1)
        DS_A(1, cur);
        stage_b(1, nxt, ktn);
        BAR_PRE();
        MFMA_PH(1, 1, b1);
        BAR_END();
        // phase 4: quadrant (1,0)
        stage_a(1, nxt, ktn);
        BAR_PRE();
        MFMA_PH(1, 0, b0);
        vwait<LA + LB>();           // completes A_h0, B_h0 of nxt
        BAR_END();
    }
    asm volatile("s_waitcnt vmcnt(0)" ::: "memory");   // drain LDS-destined loads before endpgm
#undef DS_A
#undef DS_B
#undef MFMA_PH
#undef BAR_PRE
#undef BAR_END

    // epilogue. D frag layout: row = lg*4 + r, col = lc
    #pragma unroll
    for (int i = 0; i < MI; i++) {
        if (EPI == 1) {
            const int colbase = bn + wwn * (BN / WN);
            const int zc = colbase >> 10;                 // 0=q 1=k 2=v
            unsigned short* OH = (zc == 0) ? Hq : (zc == 1) ? Hk : Hv;
            const int hcol = (colbase >> 6) & 15;
            #pragma unroll
            for (int r = 0; r < 4; r++) {
                int row = bm + wwm * (BM / WM) + i * 16 + lg * 4 + r;
                int b = row >> 10, s = row & 1023;
                size_t base = ((size_t)(b * Hdim + hcol) * Sdim + s) << 6;
                if (zc == 2) {
                    #pragma unroll
                    for (int j = 0; j < 4; j++) OH[base + j * 16 + lc] = f2bf(acc[i][j][r]);
                } else {
                    #pragma unroll
                    for (int j = 0; j < 2; j++) {
                        int d = j * 16 + lc;              // [0,32)
                        float x1 = acc[i][j][r];
                        float x2 = acc[i][j + 2][r];
                        float c = cosT[s * 64 + d];
                        float sn = sinT[s * 64 + d];
                        OH[base + d] = f2bf(x1 * c - x2 * sn);
                        OH[base + d + 32] = f2bf(x2 * c + x1 * sn);
                    }
                }
            }
        } else {
            #pragma unroll
            for (int r = 0; r < 4; r++) {
                int row = bm + wwm * (BM / WM) + i * 16 + lg * 4 + r;
                #pragma unroll
                for (int j = 0; j < NI; j++) {
                    int col = bn + wwn * (BN / WN) + j * 16 + lc;
                    float v = acc[i][j][r];
                    if (EPI == 3) {
                        float t = v + bias[col];
                        Hq[(size_t)row * ldC + col] = f2bf(t / (1.0f + expf(-t)));
                    } else if (EPI == 6) {
                        if (ks == 0 && bias != nullptr) v += bias[col];
                        unsafeAtomicAdd(&OF[(size_t)row * ldC + col], v);
                    } else {
                        OF[(size_t)row * ldC + col] = v;
                    }
                }
            }
        }
    }
}

// ---------------- flash attention over compacted keys (routed bias) ----------------
__global__ __launch_bounds__(256) void attn_kernel(const unsigned short* __restrict__ q16,
                                                   const unsigned short* __restrict__ kc,
                                                   const unsigned short* __restrict__ vTc,
                                                   const float* __restrict__ biasC,
                                                   const int* __restrict__ ntA,
                                                   unsigned short* __restrict__ o16) {
    const int qb = blockIdx.x;   // 16 (64 q rows each)
    const int bh = blockIdx.y;   // 32
    const int tid = threadIdx.x;
    const int w = tid >> 6, lane = tid & 63;
    const int lg = lane >> 4, lc = lane & 15;
    const int nt = ntA[bh];

    __shared__ unsigned short Ks[2][64 * 64];
    __shared__ unsigned short Vs[2][64 * 64];
    __shared__ unsigned short Pq[4][16][72];
    __shared__ float sbAll[1024];

    {
        const float4 bv = ((const float4*)(biasC + (size_t)bh * Sdim))[tid];
        *(float4*)&sbAll[tid * 4] = bv;
    }

    const int qrow = qb * 64 + w * 16 + lc;
    const unsigned short* qbase = q16 + ((size_t)bh * Sdim + qrow) * Ddim;
    bf16x8 qf[2];
    qf[0] = *(const bf16x8*)(qbase + lg * 8);
    qf[1] = *(const bf16x8*)(qbase + 32 + lg * 8);

    const int grow = tid >> 3;
    const int gc = (tid & 7) * 8;
    const unsigned short* kbase = kc + (size_t)bh * Sdim * Ddim;
    const unsigned short* vbase = vTc + (size_t)bh * Ddim * Sdim;

    {
        const unsigned short* kg = kbase + (size_t)grow * Ddim + gc;
        GLD16(kg, &Ks[0][tid * 8]);
        GLD16(kg + 32 * Ddim, &Ks[0][2048 + tid * 8]);
        const unsigned short* vg = vbase + (size_t)grow * Sdim + gc;
        GLD16(vg, &Vs[0][tid * 8]);
        GLD16(vg + 32 * Sdim, &Vs[0][2048 + tid * 8]);
    }
    __syncthreads();

    float m_i = -1e30f, l_i = 0.0f;
    f32x4 ot[4];
    f32x4 zero = {0.0f, 0.0f, 0.0f, 0.0f};
    #pragma unroll
    for (int fd = 0; fd < 4; fd++) ot[fd] = zero;

    const int sw = (lc & 7) << 3;

    for (int tt = 0; tt < nt; tt++) {
        const int cur = tt & 1;
        if (tt > 0) {
            asm volatile("s_waitcnt vmcnt(0)" ::: "memory");
            __builtin_amdgcn_sched_barrier(0);
            __builtin_amdgcn_s_barrier();
        }
        if (tt < nt - 1) {
            const int t1 = (tt + 1) * 64;
            const unsigned short* kg = kbase + (size_t)(t1 + grow) * Ddim + gc;
            GLD16(kg, &Ks[cur ^ 1][tid * 8]);
            GLD16(kg + 32 * Ddim, &Ks[cur ^ 1][2048 + tid * 8]);
            const unsigned short* vg = vbase + (size_t)grow * Sdim + t1 + gc;
            GLD16(vg, &Vs[cur ^ 1][tid * 8]);
            GLD16(vg + 32 * Sdim, &Vs[cur ^ 1][2048 + tid * 8]);
        }

        f32x4 sf[4];
        #pragma unroll
        for (int f = 0; f < 4; f++) {
            const int trow = f * 16 + lc;
            f32x4 a = zero;
            #pragma unroll
            for (int ks = 0; ks < 2; ks++) {
                bf16x8 kfr = *(bf16x8*)&Ks[cur][trow * 64 + ((ks * 32 + lg * 8) ^ sw)];
                a = MFMA16(kfr, qf[ks], a);
            }
            sf[f] = a;
        }
        const int t0 = tt * 64;
        float tmax = -1e30f;
        #pragma unroll
        for (int f = 0; f < 4; f++)
            #pragma unroll
            for (int j = 0; j < 4; j++) {
                float v = sf[f][j] * 0.125f + sbAll[t0 + f * 16 + lg * 4 + j];
                sf[f][j] = v;
                tmax = fmaxf(tmax, v);
            }
        tmax = fmaxf(tmax, __shfl_xor(tmax, 16));
        tmax = fmaxf(tmax, __shfl_xor(tmax, 32));
        float mnew = fmaxf(m_i, tmax);
        float alpha = expf(m_i - mnew);
        float lsum = 0.0f;
        #pragma unroll
        for (int f = 0; f < 4; f++)
            #pragma unroll
            for (int j = 0; j < 4; j++) {
                float p = expf(sf[f][j] - mnew);
                sf[f][j] = p;
                lsum += p;
            }
        lsum += __shfl_xor(lsum, 16);
        lsum += __shfl_xor(lsum, 32);
        l_i = l_i * alpha + lsum;
        m_i = mnew;
        #pragma unroll
        for (int fd = 0; fd < 4; fd++)
            #pragma unroll
            for (int j = 0; j < 4; j++) ot[fd][j] *= alpha;
        #pragma unroll
        for (int f = 0; f < 4; f++) {
            short4 ps = make_short4((short)f2bf(sf[f][0]), (short)f2bf(sf[f][1]),
                                    (short)f2bf(sf[f][2]), (short)f2bf(sf[f][3]));
            *(short4*)&Pq[w][lc][f * 16 + lg * 4] = ps;
        }
        #pragma unroll
        for (int ks = 0; ks < 2; ks++) {
            bf16x8 pf = *(bf16x8*)&Pq[w][lc][ks * 32 + lg * 8];
            #pragma unroll
            for (int fd = 0; fd < 4; fd++) {
                bf16x8 vfr = *(bf16x8*)&Vs[cur][(fd * 16 + lc) * 64 + ((ks * 32 + lg * 8) ^ sw)];
                ot[fd] = MFMA16(vfr, pf, ot[fd]);
            }
        }
    }
    asm volatile("s_waitcnt vmcnt(0)" ::: "memory");   // drain LDS-destined loads before endpgm
    float rl = 1.0f / l_i;
    int b = bh >> 4, h = bh & 15;
    #pragma unroll
    for (int fd = 0; fd < 4; fd++)
        #pragma unroll
        for (int j = 0; j < 4; j++) {
            int d = fd * 16 + lg * 4 + j;
            o16[((size_t)b * Sdim + qrow) * HDdim + h * 64 + d] = f2bf(ot[fd][j] * rl);
        }
}

extern "C" void kernel_launch(void* const* d_in, const int* in_sizes, int n_in,
                              void* d_out, int out_size, void* d_ws, size_t ws_size,
                              hipStream_t stream) {
    const int* ids = (const int*)d_in[0];
    const float* amask = (const float*)d_in[1];
    const float* emb = (const float*)d_in[2];
    const float* ln1w = (const float*)d_in[3];
    const float* ln1b = (const float*)d_in[4];
    const float* Wq = (const float*)d_in[5];
    const float* Wk = (const float*)d_in[6];
    const float* Wv = (const float*)d_in[7];
    const float* Wo = (const float*)d_in[8];
    const float* Wr = (const float*)d_in[9];
    const float* ln2w = (const float*)d_in[10];
    const float* ln2b = (const float*)d_in[11];
    const float* W1 = (const float*)d_in[12];
    const float* b1 = (const float*)d_in[13];
    const float* W2 = (const float*)d_in[14];
    const float* b2 = (const float*)d_in[15];
    const float* nw = (const float*)d_in[16];
    const float* nb = (const float*)d_in[17];
    const float* lmh = (const float*)d_in[18];
    float* out = (float*)d_out;

    char* p = (char*)d_ws;
    size_t off = 0;
    auto alloc = [&](size_t bytes) -> void* {
        void* r = p + off;
        off += (bytes + 255) & ~(size_t)255;
        return r;
    };
    float* cosT = (float*)alloc((size_t)Sdim * Ddim * 4);
    float* sinT = (float*)alloc((size_t)Sdim * Ddim * 4);
    float* x = (float*)alloc((size_t)BSdim * HDdim * 4);
    unsigned short* h16 = (unsigned short*)alloc((size_t)BSdim * HDdim * 2);
    unsigned short* o16 = (unsigned short*)alloc((size_t)BSdim * HDdim * 2);
    unsigned short* m16 = (unsigned short*)alloc((size_t)BSdim * Idim * 2);
    unsigned short* q16 = (unsigned short*)alloc((size_t)Bdim * Hdim * Sdim * Ddim * 2);
    unsigned short* k16 = (unsigned short*)alloc((size_t)Bdim * Hdim * Sdim * Ddim * 2);
    unsigned short* v16 = (unsigned short*)alloc((size_t)Bdim * Hdim * Sdim * Ddim * 2);
    unsigned short* kcs = (unsigned short*)alloc((size_t)Bdim * Hdim * Sdim * Ddim * 2);
    unsigned short* vTc = (unsigned short*)alloc((size_t)Bdim * Hdim * Sdim * Ddim * 2);
    float* router = (float*)alloc((size_t)Bdim * Hdim * Sdim * 4);
    float* biasC = (float*)alloc((size_t)Bdim * Hdim * Sdim * 4);
    int* idxC = (int*)alloc((size_t)Bdim * Hdim * Sdim * 4);
    int* ntA = (int*)alloc((size_t)Bdim * Hdim * 4);
    unsigned short* wts = (unsigned short*)alloc((size_t)Vdim * HDdim * 2);  // 64MB reuse buffer

    const size_t M1 = 1u << 20;  // 1M elems

    tables_kernel<<<256, 256, 0, stream>>>(cosT, sinT);
    embed_kernel<<<BSdim, 256, 0, stream>>>(ids, emb, x);

    for (int l = 0; l < Ldim; l++) {
        const float* Wq_l = Wq + (size_t)l * HDdim * HDdim;
        const float* Wk_l = Wk + (size_t)l * HDdim * HDdim;
        const float* Wv_l = Wv + (size_t)l * HDdim * HDdim;
        const float* Wo_l = Wo + (size_t)l * HDdim * HDdim;
        const float* Wr_l = Wr + (size_t)l * HDdim * Hdim;
        const float* W1_l = W1 + (size_t)l * HDdim * Idim;
        const float* W2_l = W2 + (size_t)l * Idim * HDdim;
        const float* b1_l = b1 + (size_t)l * Idim;
        const float* b2_l = b2 + (size_t)l * HDdim;

        // weight prepass (single dispatch): QKVO -> wts[0..4M), W1t -> [4M..8M), W2t -> [8M..12M)
        tconv_layer<<<12288, 256, 0, stream>>>(Wq_l, Wk_l, Wv_l, Wo_l, W1_l, W2_l, wts);

        // ln1 with fused router
        ln_kernel<<<BSdim, 256, 0, stream>>>(x, ln1w + l * HDdim, ln1b + l * HDdim, h16, Wr_l, router);
        topk_kernel<<<Bdim * Hdim, 1024, 0, stream>>>(router, amask, biasC, idxC, ntA);
        // fused QKV GEMM (8-phase, 128x128, 8-wave): grid 16 x 24 = 384
        gemm8p<1, 128, 128, 4, 2><<<384, 512, 0, stream>>>(h16, wts, nullptr, q16, k16, v16,
                                                           nullptr, cosT, sinT, HDdim, HDdim, 0, 16, 24);
        // compacted K / V^T gather (sparsity: ~8 of 16 tiles survive)
        kvgather_kernel<<<dim3(16, 32), 256, 0, stream>>>(k16, v16, idxC, ntA, kcs, vTc);
        attn_kernel<<<dim3(16, 32), 256, 0, stream>>>(q16, kcs, vTc, biasC, ntA, o16);
        // Wo GEMM (8-phase, split-K=2, atomic residual add): grid 16 x 8 x 2 = 256
        gemm8p<6, 128, 128, 4, 2><<<256, 512, 0, stream>>>(o16, wts + 3 * M1, x, nullptr, nullptr, nullptr,
                                                           nullptr, nullptr, nullptr, 512, HDdim, HDdim, 16, 8);
        ln_kernel<<<BSdim, 256, 0, stream>>>(x, ln2w + l * HDdim, ln2b + l * HDdim, h16, nullptr, nullptr);
        // W1 GEMM (8-phase, 128x128 -> 2 blocks/CU): grid 16 x 32 = 512
        gemm8p<3, 128, 128, 4, 2><<<512, 512, 0, stream>>>(h16, wts + 4 * M1, nullptr, m16, nullptr, nullptr,
                                                           b1_l, nullptr, nullptr, HDdim, HDdim, Idim, 16, 32);
        // W2 GEMM (8-phase, 128x128, split-K=4, atomic accumulate): grid 16 x 8 x 4 = 512
        gemm8p<6, 128, 128, 4, 2><<<512, 512, 0, stream>>>(m16, wts + 8 * M1, x, nullptr, nullptr, nullptr,
                                                           b2_l, nullptr, nullptr, 1024, Idim, HDdim, 16, 8);
    }

    ln_kernel<<<BSdim, 256, 0, stream>>>(x, nw, nb, h16, nullptr, nullptr);
    // lm_head: one tconv (32000x1024 bf16, 64MB) + one 8-phase GEMM (128x128, 2 blocks/CU): grid 16 x 250
    tconv_kernel<<<dim3(1000, 32, 1), 256, 0, stream>>>(lmh, wts, HDdim, Vdim);
    gemm8p<5, 128, 128, 4, 2><<<4000, 512, 0, stream>>>(h16, wts, out, nullptr, nullptr, nullptr,
                                                        nullptr, nullptr, nullptr, HDdim, HDdim, Vdim, 16, 250);
}

// Round 9
// 1027.681 us; speedup vs baseline: 2.1288x; 1.0084x over previous
//
#include <hip/hip_runtime.h>
#include <hip/hip_bf16.h>

#define Bdim 2
#define Sdim 1024
#define Vdim 32000
#define HDdim 1024
#define Ldim 4
#define Hdim 16
#define Ddim 64
#define Idim 4096
#define BSdim 2048

typedef __attribute__((ext_vector_type(8))) short bf16x8;
typedef __attribute__((ext_vector_type(4))) float f32x4;

__device__ __forceinline__ unsigned short f2bf(float f) {
    __hip_bfloat16 h = __float2bfloat16(f);
    return *reinterpret_cast<unsigned short*>(&h);
}

#define MFMA16(a, b, c) __builtin_amdgcn_mfma_f32_16x16x32_bf16((a), (b), (c), 0, 0, 0)

#define GLD16(gp, lp)                                                            \
    __builtin_amdgcn_global_load_lds((const __attribute__((address_space(1))) void*)(gp), \
                                     (__attribute__((address_space(3))) void*)(lp), 16, 0, 0)

template <int N>
__device__ __forceinline__ void vwait() {
    if constexpr (N == 2) asm volatile("s_waitcnt vmcnt(2)" ::: "memory");
    else if constexpr (N == 3) asm volatile("s_waitcnt vmcnt(3)" ::: "memory");
    else if constexpr (N == 4) asm volatile("s_waitcnt vmcnt(4)" ::: "memory");
    else if constexpr (N == 6) asm volatile("s_waitcnt vmcnt(6)" ::: "memory");
}

// ---------------- rope tables ----------------
__global__ __launch_bounds__(256) void tables_kernel(float* __restrict__ cosT, float* __restrict__ sinT) {
    int i = blockIdx.x * 256 + threadIdx.x;   // 65536 = S*D
    int d = i & 63;
    int s = i >> 6;
    float inv = powf(1.0e6f, -((float)(2 * (d & 31))) / 64.0f);
    float f = (float)s * inv;
    cosT[i] = cosf(f);
    sinT[i] = sinf(f);
}

// ---------------- embedding gather ----------------
__global__ __launch_bounds__(256) void embed_kernel(const int* __restrict__ ids, const float* __restrict__ emb,
                                                    float* __restrict__ x) {
    int m = blockIdx.x;
    int tid = threadIdx.x;
    int id = ids[m];
    const float4* src = (const float4*)(emb + (size_t)id * HDdim);
    ((float4*)(x + (size_t)m * HDdim))[tid] = src[tid];
}

// ---------------- layernorm -> bf16 (+ optional fused router) ----------------
__global__ __launch_bounds__(256) void ln_kernel(const float* __restrict__ x, const float* __restrict__ w,
                                                 const float* __restrict__ bw, unsigned short* __restrict__ outH,
                                                 const float* __restrict__ Wr, float* __restrict__ routerO) {
    int m = blockIdx.x;
    int tid = threadIdx.x;
    float4 a = ((const float4*)(x + (size_t)m * HDdim))[tid];
    float s = a.x + a.y + a.z + a.w;
    #pragma unroll
    for (int o = 1; o < 64; o <<= 1) s += __shfl_xor(s, o);
    __shared__ float red[4], red2[4];
    if ((tid & 63) == 0) red[tid >> 6] = s;
    __syncthreads();
    float mean = (red[0] + red[1] + red[2] + red[3]) * (1.0f / 1024.0f);
    float dx = a.x - mean, dy = a.y - mean, dz = a.z - mean, dw = a.w - mean;
    float s2 = dx * dx + dy * dy + dz * dz + dw * dw;
    #pragma unroll
    for (int o = 1; o < 64; o <<= 1) s2 += __shfl_xor(s2, o);
    if ((tid & 63) == 0) red2[tid >> 6] = s2;
    __syncthreads();
    float var = (red2[0] + red2[1] + red2[2] + red2[3]) * (1.0f / 1024.0f);
    float rs = rsqrtf(var + 1e-6f);
    float4 wv = ((const float4*)w)[tid];
    float4 bv = ((const float4*)bw)[tid];
    float v0 = dx * rs * wv.x + bv.x;
    float v1 = dy * rs * wv.y + bv.y;
    float v2 = dz * rs * wv.z + bv.z;
    float v3 = dw * rs * wv.w + bv.w;
    short4 st = make_short4((short)f2bf(v0), (short)f2bf(v1), (short)f2bf(v2), (short)f2bf(v3));
    *(short4*)(outH + (size_t)m * HDdim + tid * 4) = st;

    if (Wr) {   // fused router: routerO[b][h][s] = h_norm . Wr[:,h]
        __shared__ float rbuf[256][16];
        __shared__ float pbuf[16][17];
        float part[16];
        const float* wr0 = Wr + (size_t)(tid * 4) * Hdim;
        #pragma unroll
        for (int h = 0; h < 16; h++)
            part[h] = v0 * wr0[h] + v1 * wr0[16 + h] + v2 * wr0[32 + h] + v3 * wr0[48 + h];
        #pragma unroll
        for (int h4 = 0; h4 < 4; h4++)
            *(float4*)&rbuf[tid][h4 * 4] = make_float4(part[h4 * 4], part[h4 * 4 + 1], part[h4 * 4 + 2], part[h4 * 4 + 3]);
        __syncthreads();
        {
            int h = tid & 15, g = tid >> 4;
            float sgr = 0.0f;
            #pragma unroll
            for (int i = 0; i < 16; i++) sgr += rbuf[g * 16 + i][h];
            pbuf[g][h] = sgr;
        }
        __syncthreads();
        if (tid < 16) {
            float tot = 0.0f;
            #pragma unroll
            for (int g = 0; g < 16; g++) tot += pbuf[g][tid];
            int b = m >> 10, sI = m & 1023;
            routerO[((size_t)(b * Hdim + tid)) * Sdim + sI] = tot;
        }
    }
}

// ---------------- exact top-k threshold + compacted bias/index ----------------
__global__ __launch_bounds__(1024) void topk_kernel(const float* __restrict__ router, const float* __restrict__ amask,
                                                    float* __restrict__ biasC, int* __restrict__ idxC,
                                                    int* __restrict__ ntA) {
    int bh = blockIdx.x;
    int t = threadIdx.x;
    __shared__ float r[1024];
    __shared__ float kths;
    __shared__ int wcnt[16];
    float v = router[(size_t)bh * Sdim + t];
    r[t] = v;
    __syncthreads();
    int gt = 0, eq = 0;
    for (int j = 0; j < 1024; j++) {
        float xv = r[j];
        gt += (xv > v) ? 1 : 0;
        eq += (xv == v) ? 1 : 0;
    }
    if (gt < 512 && gt + eq >= 512) kths = v;
    // init pad region (ordered before scatter by the barrier below)
    biasC[(size_t)bh * Sdim + t] = -1e9f;
    idxC[(size_t)bh * Sdim + t] = 0;
    __syncthreads();
    float kth = kths;
    bool sel = (v >= kth);
    unsigned long long m = __ballot(sel);
    int wid = t >> 6, lane = t & 63;
    if (lane == 0) wcnt[wid] = __popcll(m);
    __syncthreads();
    int base = 0;
    for (int w = 0; w < wid; w++) base += wcnt[w];
    if (sel) {
        int rank = base + (int)__popcll(m & ((1ull << lane) - 1ull));
        float bias = (v >= 0.0f) ? -log1pf(expf(-v)) : (v - log1pf(expf(v)));
        int b = bh >> 4;
        bias += (1.0f - amask[b * Sdim + t]) * (-1e9f);
        biasC[(size_t)bh * Sdim + rank] = bias;
        idxC[(size_t)bh * Sdim + rank] = t;
    }
    if (t == 0) {
        int tot = 0;
        #pragma unroll
        for (int w = 0; w < 16; w++) tot += wcnt[w];
        ntA[bh] = (tot + 63) >> 6;
    }
}

// ---------------- transpose + f32->bf16 convert: S [K][N] f32 -> D [N][K] bf16 ----------------
__global__ __launch_bounds__(256) void tconv_kernel(const float* __restrict__ S0,
                                                    unsigned short* __restrict__ D, int K, int ldS) {
    __shared__ float t[32][33];
    int kt = blockIdx.y * 32, nt = blockIdx.x * 32;
    int r = threadIdx.x >> 3, c4 = (threadIdx.x & 7) * 4;
    float4 v = *(const float4*)(S0 + (size_t)(kt + r) * ldS + nt + c4);
    t[r][c4] = v.x; t[r][c4 + 1] = v.y; t[r][c4 + 2] = v.z; t[r][c4 + 3] = v.w;
    __syncthreads();
    short4 o = make_short4((short)f2bf(t[c4][r]), (short)f2bf(t[c4 + 1][r]),
                           (short)f2bf(t[c4 + 2][r]), (short)f2bf(t[c4 + 3][r]));
    *(short4*)(D + (size_t)(nt + r) * K + kt + c4) = o;
}

// ---------------- all-layer weight prepass: 4 x (QKVO + W1 + W2) in one dispatch ----------------
__global__ __launch_bounds__(256) void tconv_all(const float* __restrict__ Wq, const float* __restrict__ Wk,
                                                 const float* __restrict__ Wv, const float* __restrict__ Wo,
                                                 const float* __restrict__ W1, const float* __restrict__ W2,
                                                 unsigned short* __restrict__ wtsL) {
    const size_t M1 = 1u << 20;
    int bid = blockIdx.x;
    int lid = bid / 12288, sub = bid - lid * 12288;
    unsigned short* wl = wtsL + (size_t)lid * 12 * M1;
    const float* S;
    unsigned short* D;
    int K, ldS, nt, kt;
    if (sub < 4096) {            // QKVO: 4 x [1024][1024]
        int z = sub >> 10, t = sub & 1023;
        S = ((z == 0) ? Wq : (z == 1) ? Wk : (z == 2) ? Wv : Wo) + (size_t)lid * M1;
        D = wl + (size_t)z * M1;
        K = 1024; ldS = 1024; nt = t & 31; kt = t >> 5;
    } else if (sub < 8192) {     // W1: [1024][4096]
        int t = sub - 4096;
        S = W1 + (size_t)lid * 4 * M1; D = wl + 4 * M1;
        K = 1024; ldS = 4096; nt = t % 128; kt = t / 128;
    } else {                     // W2: [4096][1024]
        int t = sub - 8192;
        S = W2 + (size_t)lid * 4 * M1; D = wl + 8 * M1;
        K = 4096; ldS = 1024; nt = t % 32; kt = t / 32;
    }
    __shared__ float tb[32][33];
    int ktb = kt * 32, ntb = nt * 32;
    int r = threadIdx.x >> 3, c4 = (threadIdx.x & 7) * 4;
    float4 v = *(const float4*)(S + (size_t)(ktb + r) * ldS + ntb + c4);
    tb[r][c4] = v.x; tb[r][c4 + 1] = v.y; tb[r][c4 + 2] = v.z; tb[r][c4 + 3] = v.w;
    __syncthreads();
    short4 o = make_short4((short)f2bf(tb[c4][r]), (short)f2bf(tb[c4 + 1][r]),
                           (short)f2bf(tb[c4 + 2][r]), (short)f2bf(tb[c4 + 3][r]));
    *(short4*)(D + (size_t)(ntb + r) * K + ktb + c4) = o;
}

// ---------------- compacted V^T gather (XOR swizzle baked in) ----------------
__global__ __launch_bounds__(256) void vgather_kernel(const unsigned short* __restrict__ v16,
                                                      const int* __restrict__ idxC, const int* __restrict__ ntA,
                                                      unsigned short* __restrict__ vTc) {
    int jt = blockIdx.x;        // 16
    int bh = blockIdx.y;        // 32
    if (jt >= ntA[bh]) return;
    __shared__ unsigned short T[64][72];
    int tid = threadIdx.x;
    int jl = tid >> 2;
    int part = tid & 3;
    int j = jt * 64 + jl;
    int src = idxC[(size_t)bh * Sdim + j];
    const unsigned short* vr = v16 + ((size_t)bh * Sdim + src) * Ddim + part * 16;
    *(bf16x8*)&T[jl][part * 16] = *(const bf16x8*)vr;
    *(bf16x8*)&T[jl][part * 16 + 8] = *(const bf16x8*)(vr + 8);
    __syncthreads();
    int d = tid >> 2;
    int xr = (d & 7) << 3;
    unsigned short* dst = vTc + ((size_t)bh * Ddim + d) * Sdim + jt * 64;
    #pragma unroll
    for (int cc = 0; cc < 2; cc++) {
        int tb = (tid & 3) * 16 + cc * 8;
        bf16x8 o;
        #pragma unroll
        for (int i = 0; i < 8; i++) o[i] = (short)T[tb + i][d];
        *(bf16x8*)(dst + (tb ^ xr)) = o;
    }
}

// ================= 8-phase 512-thread MFMA GEMM (T2+T3+T4+T5) =================
// C = A(bf16 [M,ldK]) * Bt(bf16 [N,ldK])^T over K-chunk Kc at offset ks*Kc
// (split-K decoded from flat grid: bid = ks*gridM*gridN + bn*gridM + bm).
// LDS half-major, staged via per-lane interleaved global rows (linear dest),
// XOR-swizzle folded into source col. Counted vmcnt; raw barriers; setprio.
// EPI: 1 = fused QKV (rope->bf16; needs BN/WN==64),
//      3 = bias+silu->bf16, 5 = plain f32, 6 = atomic += (+bias on ks==0 if bias)
template <int EPI, int BM, int BN, int WM, int WN>
__global__ __launch_bounds__(512) void gemm8p(
    const unsigned short* __restrict__ A, const unsigned short* __restrict__ Bt,
    float* __restrict__ OF, unsigned short* __restrict__ Hq, unsigned short* __restrict__ Hk,
    unsigned short* __restrict__ Hv, const float* __restrict__ bias,
    const float* __restrict__ cosT, const float* __restrict__ sinT,
    int Kc, int ldK, int ldC, int gridM, int gridN) {
    constexpr int MI = BM / WM / 16, NI = BN / WN / 16;
    constexpr int MH = MI / 2, NH = NI / 2;
    constexpr int LA = BM / 128, LB = BN / 128;
    constexpr int HA = BM / WM / 2;   // A half-selector
    constexpr int HB = BN / WN / 2;   // B half-selector
    constexpr int ABUF = BM * 64, BBUF = BN * 64;

    __shared__ unsigned short lds[2 * ABUF + 2 * BBUF];

    int bid = blockIdx.x;
    const int nwg = gridDim.x;
    if ((nwg & 7) == 0) bid = (bid & 7) * (nwg >> 3) + (bid >> 3);   // XCD swizzle (bijective: nwg%8==0)
    const int mn = gridM * gridN;
    const int ks = bid / mn;
    const int rem = bid - ks * mn;
    const int bm = (rem % gridM) * BM;
    const int bn = (rem / gridM) * BN;
    const unsigned short* Ap = A + (size_t)ks * Kc;
    const unsigned short* Bp = Bt + (size_t)ks * Kc;

    const int tid = threadIdx.x;
    const int lane = tid & 63, wid = tid >> 6;
    const int lc = lane & 15, lg = lane >> 4;
    const int wwm = wid / WN, wwn = wid % WN;

    const int srow = tid >> 3;                    // 0..63
    const int scol = ((tid & 7) ^ (srow & 7)) * 8;
    const int ak0 = (lg * 8) ^ ((lc & 7) * 8);
    const int ak1 = (32 + lg * 8) ^ ((lc & 7) * 8);

    f32x4 acc[MI][NI];
    f32x4 zero = {0.0f, 0.0f, 0.0f, 0.0f};
    #pragma unroll
    for (int i = 0; i < MI; i++)
        #pragma unroll
        for (int j = 0; j < NI; j++) acc[i][j] = zero;

    bf16x8 a[MH][2], b0[NH][2], b1[NH][2];

    auto stage_a = [&](int half, int nbuf, int kt) {
        #pragma unroll
        for (int j = 0; j < LA; j++) {
            const int idx = j * 64 + srow;                          // [0, BM/2)
            const int grow = (idx / HA) * (BM / WM) + half * HA + (idx % HA);
            const unsigned short* g = Ap + (size_t)(bm + grow) * ldK + kt + scol;
            GLD16(g, &lds[nbuf * ABUF + half * (ABUF / 2) + (j * 512 + tid) * 8]);
        }
    };
    auto stage_b = [&](int half, int nbuf, int kt) {
        #pragma unroll
        for (int j = 0; j < LB; j++) {
            const int idx = j * 64 + srow;                          // [0, BN/2)
            const int grow = (idx / HB) * (BN / WN) + half * HB + (idx % HB);
            const unsigned short* g = Bp + (size_t)(bn + grow) * ldK + kt + scol;
            GLD16(g, &lds[2 * ABUF + nbuf * BBUF + half * (BBUF / 2) + (j * 512 + tid) * 8]);
        }
    };

#define DS_A(mh_, cur_)                                                                   \
    _Pragma("unroll") for (int m = 0; m < MH; m++) {                                      \
        const int ro = (cur_)*ABUF + (mh_) * (ABUF / 2) + (wwm * HA + m * 16 + lc) * 64;  \
        a[m][0] = *(const bf16x8*)&lds[ro + ak0];                                         \
        a[m][1] = *(const bf16x8*)&lds[ro + ak1];                                         \
    }
#define DS_B(bb_, nh_, cur_)                                                              \
    _Pragma("unroll") for (int n = 0; n < NH; n++) {                                      \
        const int ro = 2 * ABUF + (cur_)*BBUF + (nh_) * (BBUF / 2) + (wwn * HB + n * 16 + lc) * 64; \
        bb_[n][0] = *(const bf16x8*)&lds[ro + ak0];                                       \
        bb_[n][1] = *(const bf16x8*)&lds[ro + ak1];                                       \
    }
#define MFMA_PH(mh_, nh_, bb_)                                                            \
    __builtin_amdgcn_s_setprio(1);                                                        \
    _Pragma("unroll") for (int m = 0; m < MH; m++) _Pragma("unroll") for (int n = 0; n < NH; n++) { \
        acc[(mh_)*MH + m][(nh_)*NH + n] = MFMA16(a[m][0], bb_[n][0], acc[(mh_)*MH + m][(nh_)*NH + n]); \
        acc[(mh_)*MH + m][(nh_)*NH + n] = MFMA16(a[m][1], bb_[n][1], acc[(mh_)*MH + m][(nh_)*NH + n]); \
    }                                                                                     \
    __builtin_amdgcn_s_setprio(0);
#define BAR_PRE()                                                                         \
    __builtin_amdgcn_sched_barrier(0);                                                    \
    __builtin_amdgcn_s_barrier();
#define BAR_END()                                                                         \
    asm volatile("" ::: "memory");                                                        \
    __builtin_amdgcn_s_barrier();                                                         \
    __builtin_amdgcn_sched_barrier(0);

    // prologue: tile 0 half-tiles in steady-state order; leave {Bh1,Ah1} in flight
    stage_a(0, 0, 0);
    stage_b(0, 0, 0);
    stage_b(1, 0, 0);
    stage_a(1, 0, 0);
    vwait<LA + LB>();
    BAR_END();

    const int NT = Kc >> 6;
    for (int t = 0; t < NT; t++) {
        const int cur = t & 1, nxt = cur ^ 1;
        const int ktn = (t + 1 < NT) ? (t + 1) * 64 : t * 64;
        // phase 1: quadrant (0,0)
        DS_A(0, cur);
        DS_B(b0, 0, cur);
        stage_a(0, nxt, ktn);
        BAR_PRE();
        MFMA_PH(0, 0, b0);
        vwait<2 * LA>();            // completes B_h1(cur)
        BAR_END();
        // phase 2: quadrant (0,1)
        DS_B(b1, 1, cur);
        stage_b(0, nxt, ktn);
        BAR_PRE();
        MFMA_PH(0, 1, b1);
        vwait<LA + LB>();           // completes A_h1(cur)
        BAR_END();
        // phase 3: quadrant (1,1)
        DS_A(1, cur);
        stage_b(1, nxt, ktn);
        BAR_PRE();
        MFMA_PH(1, 1, b1);
        BAR_END();
        // phase 4: quadrant (1,0)
        stage_a(1, nxt, ktn);
        BAR_PRE();
        MFMA_PH(1, 0, b0);
        vwait<LA + LB>();           // completes A_h0, B_h0 of nxt
        BAR_END();
    }
    asm volatile("s_waitcnt vmcnt(0)" ::: "memory");   // drain LDS-destined loads before endpgm
#undef DS_A
#undef DS_B
#undef MFMA_PH
#undef BAR_PRE
#undef BAR_END

    // epilogue. D frag layout: row = lg*4 + r, col = lc
    #pragma unroll
    for (int i = 0; i < MI; i++) {
        if (EPI == 1) {
            const int colbase = bn + wwn * (BN / WN);
            const int zc = colbase >> 10;                 // 0=q 1=k 2=v
            unsigned short* OH = (zc == 0) ? Hq : (zc == 1) ? Hk : Hv;
            const int hcol = (colbase >> 6) & 15;
            #pragma unroll
            for (int r = 0; r < 4; r++) {
                int row = bm + wwm * (BM / WM) + i * 16 + lg * 4 + r;
                int b = row >> 10, s = row & 1023;
                size_t base = ((size_t)(b * Hdim + hcol) * Sdim + s) << 6;
                if (zc == 2) {
                    #pragma unroll
                    for (int j = 0; j < 4; j++) OH[base + j * 16 + lc] = f2bf(acc[i][j][r]);
                } else {
                    #pragma unroll
                    for (int j = 0; j < 2; j++) {
                        int d = j * 16 + lc;              // [0,32)
                        float x1 = acc[i][j][r];
                        float x2 = acc[i][j + 2][r];
                        float c = cosT[s * 64 + d];
                        float sn = sinT[s * 64 + d];
                        OH[base + d] = f2bf(x1 * c - x2 * sn);
                        OH[base + d + 32] = f2bf(x2 * c + x1 * sn);
                    }
                }
            }
        } else {
            #pragma unroll
            for (int r = 0; r < 4; r++) {
                int row = bm + wwm * (BM / WM) + i * 16 + lg * 4 + r;
                #pragma unroll
                for (int j = 0; j < NI; j++) {
                    int col = bn + wwn * (BN / WN) + j * 16 + lc;
                    float v = acc[i][j][r];
                    if (EPI == 3) {
                        float t = v + bias[col];
                        Hq[(size_t)row * ldC + col] = f2bf(t / (1.0f + expf(-t)));
                    } else if (EPI == 6) {
                        if (ks == 0 && bias != nullptr) v += bias[col];
                        unsafeAtomicAdd(&OF[(size_t)row * ldC + col], v);
                    } else {
                        OF[(size_t)row * ldC + col] = v;
                    }
                }
            }
        }
    }
}

// ---------------- flash attention over compacted keys (routed bias) ----------------
// K staged directly from k16 via per-lane gathered global addresses (idxC), swizzle
// folded into source column; V^T from pre-gathered vTc.
__global__ __launch_bounds__(256) void attn_kernel(const unsigned short* __restrict__ q16,
                                                   const unsigned short* __restrict__ k16,
                                                   const unsigned short* __restrict__ vTc,
                                                   const int* __restrict__ idxC,
                                                   const float* __restrict__ biasC,
                                                   const int* __restrict__ ntA,
                                                   unsigned short* __restrict__ o16) {
    const int qb = blockIdx.x;   // 16 (64 q rows each)
    const int bh = blockIdx.y;   // 32
    const int tid = threadIdx.x;
    const int w = tid >> 6, lane = tid & 63;
    const int lg = lane >> 4, lc = lane & 15;
    const int nt = ntA[bh];

    __shared__ unsigned short Ks[2][64 * 64];
    __shared__ unsigned short Vs[2][64 * 64];
    __shared__ unsigned short Pq[4][16][72];
    __shared__ float sbAll[1024];

    {
        const float4 bv = ((const float4*)(biasC + (size_t)bh * Sdim))[tid];
        *(float4*)&sbAll[tid * 4] = bv;
    }

    const int qrow = qb * 64 + w * 16 + lc;
    const unsigned short* qbase = q16 + ((size_t)bh * Sdim + qrow) * Ddim;
    bf16x8 qf[2];
    qf[0] = *(const bf16x8*)(qbase + lg * 8);
    qf[1] = *(const bf16x8*)(qbase + 32 + lg * 8);

    const int grow = tid >> 3;                 // 0..31
    const int gc = (tid & 7) * 8;
    const int ksw = (grow & 7) << 3;           // K source-col swizzle ((grow+32)&7 == grow&7)
    const unsigned short* kbase = k16 + (size_t)bh * Sdim * Ddim;
    const int* ibase = idxC + (size_t)bh * Sdim;
    const unsigned short* vbase = vTc + (size_t)bh * Ddim * Sdim;

    auto stageK = [&](int buf, int t1) {
        int s0 = ibase[t1 + grow];
        int s1 = ibase[t1 + 32 + grow];
        GLD16(kbase + (size_t)s0 * Ddim + (gc ^ ksw), &Ks[buf][tid * 8]);
        GLD16(kbase + (size_t)s1 * Ddim + (gc ^ ksw), &Ks[buf][2048 + tid * 8]);
    };

    {
        stageK(0, 0);
        const unsigned short* vg = vbase + (size_t)grow * Sdim + gc;
        GLD16(vg, &Vs[0][tid * 8]);
        GLD16(vg + 32 * Sdim, &Vs[0][2048 + tid * 8]);
    }
    __syncthreads();

    float m_i = -1e30f, l_i = 0.0f;
    f32x4 ot[4];
    f32x4 zero = {0.0f, 0.0f, 0.0f, 0.0f};
    #pragma unroll
    for (int fd = 0; fd < 4; fd++) ot[fd] = zero;

    const int sw = (lc & 7) << 3;

    for (int tt = 0; tt < nt; tt++) {
        const int cur = tt & 1;
        if (tt > 0) {
            asm volatile("s_waitcnt vmcnt(0)" ::: "memory");
            __builtin_amdgcn_sched_barrier(0);
            __builtin_amdgcn_s_barrier();
        }
        if (tt < nt - 1) {
            const int t1 = (tt + 1) * 64;
            stageK(cur ^ 1, t1);
            const unsigned short* vg = vbase + (size_t)grow * Sdim + t1 + gc;
            GLD16(vg, &Vs[cur ^ 1][tid * 8]);
            GLD16(vg + 32 * Sdim, &Vs[cur ^ 1][2048 + tid * 8]);
        }

        f32x4 sf[4];
        #pragma unroll
        for (int f = 0; f < 4; f++) {
            const int trow = f * 16 + lc;
            f32x4 a = zero;
            #pragma unroll
            for (int ks = 0; ks < 2; ks++) {
                bf16x8 kfr = *(bf16x8*)&Ks[cur][trow * 64 + ((ks * 32 + lg * 8) ^ sw)];
                a = MFMA16(kfr, qf[ks], a);
            }
            sf[f] = a;
        }
        const int t0 = tt * 64;
        float tmax = -1e30f;
        #pragma unroll
        for (int f = 0; f < 4; f++)
            #pragma unroll
            for (int j = 0; j < 4; j++) {
                float v = sf[f][j] * 0.125f + sbAll[t0 + f * 16 + lg * 4 + j];
                sf[f][j] = v;
                tmax = fmaxf(tmax, v);
            }
        tmax = fmaxf(tmax, __shfl_xor(tmax, 16));
        tmax = fmaxf(tmax, __shfl_xor(tmax, 32));
        float mnew = fmaxf(m_i, tmax);
        float alpha = expf(m_i - mnew);
        float lsum = 0.0f;
        #pragma unroll
        for (int f = 0; f < 4; f++)
            #pragma unroll
            for (int j = 0; j < 4; j++) {
                float p = expf(sf[f][j] - mnew);
                sf[f][j] = p;
                lsum += p;
            }
        lsum += __shfl_xor(lsum, 16);
        lsum += __shfl_xor(lsum, 32);
        l_i = l_i * alpha + lsum;
        m_i = mnew;
        #pragma unroll
        for (int fd = 0; fd < 4; fd++)
            #pragma unroll
            for (int j = 0; j < 4; j++) ot[fd][j] *= alpha;
        #pragma unroll
        for (int f = 0; f < 4; f++) {
            short4 ps = make_short4((short)f2bf(sf[f][0]), (short)f2bf(sf[f][1]),
                                    (short)f2bf(sf[f][2]), (short)f2bf(sf[f][3]));
            *(short4*)&Pq[w][lc][f * 16 + lg * 4] = ps;
        }
        #pragma unroll
        for (int ks = 0; ks < 2; ks++) {
            bf16x8 pf = *(bf16x8*)&Pq[w][lc][ks * 32 + lg * 8];
            #pragma unroll
            for (int fd = 0; fd < 4; fd++) {
                bf16x8 vfr = *(bf16x8*)&Vs[cur][(fd * 16 + lc) * 64 + ((ks * 32 + lg * 8) ^ sw)];
                ot[fd] = MFMA16(vfr, pf, ot[fd]);
            }
        }
    }
    asm volatile("s_waitcnt vmcnt(0)" ::: "memory");   // drain LDS-destined loads before endpgm
    float rl = 1.0f / l_i;
    int b = bh >> 4, h = bh & 15;
    #pragma unroll
    for (int fd = 0; fd < 4; fd++)
        #pragma unroll
        for (int j = 0; j < 4; j++) {
            int d = fd * 16 + lg * 4 + j;
            o16[((size_t)b * Sdim + qrow) * HDdim + h * 64 + d] = f2bf(ot[fd][j] * rl);
        }
}

extern "C" void kernel_launch(void* const* d_in, const int* in_sizes, int n_in,
                              void* d_out, int out_size, void* d_ws, size_t ws_size,
                              hipStream_t stream) {
    const int* ids = (const int*)d_in[0];
    const float* amask = (const float*)d_in[1];
    const float* emb = (const float*)d_in[2];
    const float* ln1w = (const float*)d_in[3];
    const float* ln1b = (const float*)d_in[4];
    const float* Wq = (const float*)d_in[5];
    const float* Wk = (const float*)d_in[6];
    const float* Wv = (const float*)d_in[7];
    const float* Wo = (const float*)d_in[8];
    const float* Wr = (const float*)d_in[9];
    const float* ln2w = (const float*)d_in[10];
    const float* ln2b = (const float*)d_in[11];
    const float* W1 = (const float*)d_in[12];
    const float* b1 = (const float*)d_in[13];
    const float* W2 = (const float*)d_in[14];
    const float* b2 = (const float*)d_in[15];
    const float* nw = (const float*)d_in[16];
    const float* nb = (const float*)d_in[17];
    const float* lmh = (const float*)d_in[18];
    float* out = (float*)d_out;

    char* p = (char*)d_ws;
    size_t off = 0;
    auto alloc = [&](size_t bytes) -> void* {
        void* r = p + off;
        off += (bytes + 255) & ~(size_t)255;
        return r;
    };
    float* cosT = (float*)alloc((size_t)Sdim * Ddim * 4);
    float* sinT = (float*)alloc((size_t)Sdim * Ddim * 4);
    float* x = (float*)alloc((size_t)BSdim * HDdim * 4);
    unsigned short* h16 = (unsigned short*)alloc((size_t)BSdim * HDdim * 2);
    unsigned short* o16 = (unsigned short*)alloc((size_t)BSdim * HDdim * 2);
    unsigned short* m16 = (unsigned short*)alloc((size_t)BSdim * Idim * 2);
    unsigned short* q16 = (unsigned short*)alloc((size_t)Bdim * Hdim * Sdim * Ddim * 2);
    unsigned short* k16 = (unsigned short*)alloc((size_t)Bdim * Hdim * Sdim * Ddim * 2);
    unsigned short* v16 = (unsigned short*)alloc((size_t)Bdim * Hdim * Sdim * Ddim * 2);
    unsigned short* vTc = (unsigned short*)alloc((size_t)Bdim * Hdim * Sdim * Ddim * 2);
    float* router = (float*)alloc((size_t)Bdim * Hdim * Sdim * 4);
    float* biasC = (float*)alloc((size_t)Bdim * Hdim * Sdim * 4);
    int* idxC = (int*)alloc((size_t)Bdim * Hdim * Sdim * 4);
    int* ntA = (int*)alloc((size_t)Bdim * Hdim * 4);
    unsigned short* wts = (unsigned short*)alloc((size_t)Vdim * HDdim * 2);        // 64MB lm_head
    unsigned short* wtsL = (unsigned short*)alloc((size_t)Ldim * 12 * (1u << 20) * 2);  // 96MB layer weights

    const size_t M1 = 1u << 20;  // 1M elems

    tables_kernel<<<256, 256, 0, stream>>>(cosT, sinT);
    embed_kernel<<<BSdim, 256, 0, stream>>>(ids, emb, x);
    // all weight prepasses up front (off the critical path)
    tconv_kernel<<<dim3(1000, 32, 1), 256, 0, stream>>>(lmh, wts, HDdim, Vdim);
    tconv_all<<<Ldim * 12288, 256, 0, stream>>>(Wq, Wk, Wv, Wo, W1, W2, wtsL);

    for (int l = 0; l < Ldim; l++) {
        unsigned short* wl = wtsL + (size_t)l * 12 * M1;
        const float* Wr_l = Wr + (size_t)l * HDdim * Hdim;
        const float* b1_l = b1 + (size_t)l * Idim;
        const float* b2_l = b2 + (size_t)l * HDdim;

        // ln1 with fused router
        ln_kernel<<<BSdim, 256, 0, stream>>>(x, ln1w + l * HDdim, ln1b + l * HDdim, h16, Wr_l, router);
        topk_kernel<<<Bdim * Hdim, 1024, 0, stream>>>(router, amask, biasC, idxC, ntA);
        // fused QKV GEMM (8-phase, 128x128, 8-wave): grid 16 x 24 = 384
        gemm8p<1, 128, 128, 4, 2><<<384, 512, 0, stream>>>(h16, wl, nullptr, q16, k16, v16,
                                                           nullptr, cosT, sinT, HDdim, HDdim, 0, 16, 24);
        // compacted V^T gather (sparsity: ~8 of 16 tiles survive); K gathered in-attn
        vgather_kernel<<<dim3(16, 32), 256, 0, stream>>>(v16, idxC, ntA, vTc);
        attn_kernel<<<dim3(16, 32), 256, 0, stream>>>(q16, k16, vTc, idxC, biasC, ntA, o16);
        // Wo GEMM (8-phase, split-K=2, atomic residual add): grid 16 x 8 x 2 = 256
        gemm8p<6, 128, 128, 4, 2><<<256, 512, 0, stream>>>(o16, wl + 3 * M1, x, nullptr, nullptr, nullptr,
                                                           nullptr, nullptr, nullptr, 512, HDdim, HDdim, 16, 8);
        ln_kernel<<<BSdim, 256, 0, stream>>>(x, ln2w + l * HDdim, ln2b + l * HDdim, h16, nullptr, nullptr);
        // W1 GEMM (8-phase, 128x128 -> 2 blocks/CU): grid 16 x 32 = 512
        gemm8p<3, 128, 128, 4, 2><<<512, 512, 0, stream>>>(h16, wl + 4 * M1, nullptr, m16, nullptr, nullptr,
                                                           b1_l, nullptr, nullptr, HDdim, HDdim, Idim, 16, 32);
        // W2 GEMM (8-phase, 128x128, split-K=4, atomic accumulate): grid 16 x 8 x 4 = 512
        gemm8p<6, 128, 128, 4, 2><<<512, 512, 0, stream>>>(m16, wl + 8 * M1, x, nullptr, nullptr, nullptr,
                                                           b2_l, nullptr, nullptr, 1024, Idim, HDdim, 16, 8);
    }

    ln_kernel<<<BSdim, 256, 0, stream>>>(x, nw, nb, h16, nullptr, nullptr);
    // lm_head GEMM (8-phase, 256x256 — 128KB LDS, best measured config): grid 8 x 125
    gemm8p<5, 256, 256, 2, 4><<<1000, 512, 0, stream>>>(h16, wts, out, nullptr, nullptr, nullptr,
                                                        nullptr, nullptr, nullptr, HDdim, HDdim, Vdim, 8, 125);
}

// Round 10
// 988.854 us; speedup vs baseline: 2.2124x; 1.0393x over previous
//
#include <hip/hip_runtime.h>
#include <hip/hip_bf16.h>

#define Bdim 2
#define Sdim 1024
#define Vdim 32000
#define HDdim 1024
#define Ldim 4
#define Hdim 16
#define Ddim 64
#define Idim 4096
#define BSdim 2048

typedef __attribute__((ext_vector_type(8))) short bf16x8;
typedef __attribute__((ext_vector_type(4))) float f32x4;

__device__ __forceinline__ unsigned short f2bf(float f) {
    __hip_bfloat16 h = __float2bfloat16(f);
    return *reinterpret_cast<unsigned short*>(&h);
}

#define MFMA16(a, b, c) __builtin_amdgcn_mfma_f32_16x16x32_bf16((a), (b), (c), 0, 0, 0)

#define GLD16(gp, lp)                                                            \
    __builtin_amdgcn_global_load_lds((const __attribute__((address_space(1))) void*)(gp), \
                                     (__attribute__((address_space(3))) void*)(lp), 16, 0, 0)

template <int N>
__device__ __forceinline__ void vwait() {
    if constexpr (N == 2) asm volatile("s_waitcnt vmcnt(2)" ::: "memory");
    else if constexpr (N == 3) asm volatile("s_waitcnt vmcnt(3)" ::: "memory");
    else if constexpr (N == 4) asm volatile("s_waitcnt vmcnt(4)" ::: "memory");
    else if constexpr (N == 6) asm volatile("s_waitcnt vmcnt(6)" ::: "memory");
}

// ---------------- init: embedding gather + rope tables (merged) ----------------
__global__ __launch_bounds__(256) void init_kernel(const int* __restrict__ ids, const float* __restrict__ emb,
                                                   float* __restrict__ x, float* __restrict__ cosT,
                                                   float* __restrict__ sinT) {
    int bid = blockIdx.x;
    int tid = threadIdx.x;
    if (bid < BSdim) {
        int id = ids[bid];
        const float4* src = (const float4*)(emb + (size_t)id * HDdim);
        ((float4*)(x + (size_t)bid * HDdim))[tid] = src[tid];
    } else {
        int i = (bid - BSdim) * 256 + tid;   // 65536 = S*D
        int d = i & 63;
        int s = i >> 6;
        float inv = powf(1.0e6f, -((float)(2 * (d & 31))) / 64.0f);
        float f = (float)s * inv;
        cosT[i] = cosf(f);
        sinT[i] = sinf(f);
    }
}

// ---------------- layernorm (+ fused residual-partial reduction, + optional router) ----------------
// a = x[m] + sum_{p<NP} parts[p][m] + badd  ; optionally write a back to xout; LN(a) -> outH
template <int NP>
__global__ __launch_bounds__(256) void ln_kernel(const float* __restrict__ x, float* __restrict__ xout,
                                                 const float* __restrict__ parts, size_t pstride,
                                                 const float* __restrict__ badd,
                                                 const float* __restrict__ w, const float* __restrict__ bw,
                                                 unsigned short* __restrict__ outH,
                                                 const float* __restrict__ Wr, float* __restrict__ routerO) {
    int m = blockIdx.x;
    int tid = threadIdx.x;
    float4 a = ((const float4*)(x + (size_t)m * HDdim))[tid];
    #pragma unroll
    for (int p = 0; p < NP; p++) {
        float4 q = ((const float4*)(parts + p * pstride + (size_t)m * HDdim))[tid];
        a.x += q.x; a.y += q.y; a.z += q.z; a.w += q.w;
    }
    if (badd) {
        float4 bb = ((const float4*)badd)[tid];
        a.x += bb.x; a.y += bb.y; a.z += bb.z; a.w += bb.w;
    }
    if (xout) ((float4*)(xout + (size_t)m * HDdim))[tid] = a;

    float s = a.x + a.y + a.z + a.w;
    #pragma unroll
    for (int o = 1; o < 64; o <<= 1) s += __shfl_xor(s, o);
    __shared__ float red[4], red2[4];
    if ((tid & 63) == 0) red[tid >> 6] = s;
    __syncthreads();
    float mean = (red[0] + red[1] + red[2] + red[3]) * (1.0f / 1024.0f);
    float dx = a.x - mean, dy = a.y - mean, dz = a.z - mean, dw = a.w - mean;
    float s2 = dx * dx + dy * dy + dz * dz + dw * dw;
    #pragma unroll
    for (int o = 1; o < 64; o <<= 1) s2 += __shfl_xor(s2, o);
    if ((tid & 63) == 0) red2[tid >> 6] = s2;
    __syncthreads();
    float var = (red2[0] + red2[1] + red2[2] + red2[3]) * (1.0f / 1024.0f);
    float rs = rsqrtf(var + 1e-6f);
    float4 wv = ((const float4*)w)[tid];
    float4 bv = ((const float4*)bw)[tid];
    float v0 = dx * rs * wv.x + bv.x;
    float v1 = dy * rs * wv.y + bv.y;
    float v2 = dz * rs * wv.z + bv.z;
    float v3 = dw * rs * wv.w + bv.w;
    short4 st = make_short4((short)f2bf(v0), (short)f2bf(v1), (short)f2bf(v2), (short)f2bf(v3));
    *(short4*)(outH + (size_t)m * HDdim + tid * 4) = st;

    if (Wr) {   // fused router: routerO[b][h][s] = h_norm . Wr[:,h]
        __shared__ float rbuf[256][16];
        __shared__ float pbuf[16][17];
        float part[16];
        const float* wr0 = Wr + (size_t)(tid * 4) * Hdim;
        #pragma unroll
        for (int h = 0; h < 16; h++)
            part[h] = v0 * wr0[h] + v1 * wr0[16 + h] + v2 * wr0[32 + h] + v3 * wr0[48 + h];
        #pragma unroll
        for (int h4 = 0; h4 < 4; h4++)
            *(float4*)&rbuf[tid][h4 * 4] = make_float4(part[h4 * 4], part[h4 * 4 + 1], part[h4 * 4 + 2], part[h4 * 4 + 3]);
        __syncthreads();
        {
            int h = tid & 15, g = tid >> 4;
            float sgr = 0.0f;
            #pragma unroll
            for (int i = 0; i < 16; i++) sgr += rbuf[g * 16 + i][h];
            pbuf[g][h] = sgr;
        }
        __syncthreads();
        if (tid < 16) {
            float tot = 0.0f;
            #pragma unroll
            for (int g = 0; g < 16; g++) tot += pbuf[g][tid];
            int b = m >> 10, sI = m & 1023;
            routerO[((size_t)(b * Hdim + tid)) * Sdim + sI] = tot;
        }
    }
}

// ---------------- exact top-k threshold + compacted bias/index ----------------
__global__ __launch_bounds__(1024) void topk_kernel(const float* __restrict__ router, const float* __restrict__ amask,
                                                    float* __restrict__ biasC, int* __restrict__ idxC,
                                                    int* __restrict__ ntA) {
    int bh = blockIdx.x;
    int t = threadIdx.x;
    __shared__ float r[1024];
    __shared__ float kths;
    __shared__ int wcnt[16];
    float v = router[(size_t)bh * Sdim + t];
    r[t] = v;
    __syncthreads();
    int gt = 0, eq = 0;
    for (int j = 0; j < 1024; j++) {
        float xv = r[j];
        gt += (xv > v) ? 1 : 0;
        eq += (xv == v) ? 1 : 0;
    }
    if (gt < 512 && gt + eq >= 512) kths = v;
    // init pad region (ordered before scatter by the barrier below)
    biasC[(size_t)bh * Sdim + t] = -1e9f;
    idxC[(size_t)bh * Sdim + t] = 0;
    __syncthreads();
    float kth = kths;
    bool sel = (v >= kth);
    unsigned long long m = __ballot(sel);
    int wid = t >> 6, lane = t & 63;
    if (lane == 0) wcnt[wid] = __popcll(m);
    __syncthreads();
    int base = 0;
    for (int w = 0; w < wid; w++) base += wcnt[w];
    if (sel) {
        int rank = base + (int)__popcll(m & ((1ull << lane) - 1ull));
        float bias = (v >= 0.0f) ? -log1pf(expf(-v)) : (v - log1pf(expf(v)));
        int b = bh >> 4;
        bias += (1.0f - amask[b * Sdim + t]) * (-1e9f);
        biasC[(size_t)bh * Sdim + rank] = bias;
        idxC[(size_t)bh * Sdim + rank] = t;
    }
    if (t == 0) {
        int tot = 0;
        #pragma unroll
        for (int w = 0; w < 16; w++) tot += wcnt[w];
        ntA[bh] = (tot + 63) >> 6;
    }
}

// ---------------- all weight prepass: 4 x (QKVO + W1 + W2) + lm_head in one dispatch ----------------
__global__ __launch_bounds__(256) void tconv_all(const float* __restrict__ Wq, const float* __restrict__ Wk,
                                                 const float* __restrict__ Wv, const float* __restrict__ Wo,
                                                 const float* __restrict__ W1, const float* __restrict__ W2,
                                                 const float* __restrict__ lmh,
                                                 unsigned short* __restrict__ wtsL,
                                                 unsigned short* __restrict__ wtsLM) {
    const size_t M1 = 1u << 20;
    int bid = blockIdx.x;
    const float* S;
    unsigned short* D;
    int K, ldS, nt, kt;
    if (bid < 49152) {
        int lid = bid / 12288, sub = bid - lid * 12288;
        unsigned short* wl = wtsL + (size_t)lid * 12 * M1;
        if (sub < 4096) {            // QKVO: 4 x [1024][1024]
            int z = sub >> 10, t = sub & 1023;
            S = ((z == 0) ? Wq : (z == 1) ? Wk : (z == 2) ? Wv : Wo) + (size_t)lid * M1;
            D = wl + (size_t)z * M1;
            K = 1024; ldS = 1024; nt = t & 31; kt = t >> 5;
        } else if (sub < 8192) {     // W1: [1024][4096]
            int t = sub - 4096;
            S = W1 + (size_t)lid * 4 * M1; D = wl + 4 * M1;
            K = 1024; ldS = 4096; nt = t % 128; kt = t / 128;
        } else {                     // W2: [4096][1024]
            int t = sub - 8192;
            S = W2 + (size_t)lid * 4 * M1; D = wl + 8 * M1;
            K = 4096; ldS = 1024; nt = t % 32; kt = t / 32;
        }
    } else {                         // lm_head: [1024][32000]
        int t = bid - 49152;
        S = lmh; D = wtsLM;
        K = 1024; ldS = Vdim; nt = t % 1000; kt = t / 1000;
    }
    __shared__ float tb[32][33];
    int ktb = kt * 32, ntb = nt * 32;
    int r = threadIdx.x >> 3, c4 = (threadIdx.x & 7) * 4;
    float4 v = *(const float4*)(S + (size_t)(ktb + r) * ldS + ntb + c4);
    tb[r][c4] = v.x; tb[r][c4 + 1] = v.y; tb[r][c4 + 2] = v.z; tb[r][c4 + 3] = v.w;
    __syncthreads();
    short4 o = make_short4((short)f2bf(tb[c4][r]), (short)f2bf(tb[c4 + 1][r]),
                           (short)f2bf(tb[c4 + 2][r]), (short)f2bf(tb[c4 + 3][r]));
    *(short4*)(D + (size_t)(ntb + r) * K + ktb + c4) = o;
}

// ---------------- compacted V^T gather (XOR swizzle baked in) ----------------
__global__ __launch_bounds__(256) void vgather_kernel(const unsigned short* __restrict__ v16,
                                                      const int* __restrict__ idxC, const int* __restrict__ ntA,
                                                      unsigned short* __restrict__ vTc) {
    int jt = blockIdx.x;        // 16
    int bh = blockIdx.y;        // 32
    if (jt >= ntA[bh]) return;
    __shared__ unsigned short T[64][72];
    int tid = threadIdx.x;
    int jl = tid >> 2;
    int part = tid & 3;
    int j = jt * 64 + jl;
    int src = idxC[(size_t)bh * Sdim + j];
    const unsigned short* vr = v16 + ((size_t)bh * Sdim + src) * Ddim + part * 16;
    *(bf16x8*)&T[jl][part * 16] = *(const bf16x8*)vr;
    *(bf16x8*)&T[jl][part * 16 + 8] = *(const bf16x8*)(vr + 8);
    __syncthreads();
    int d = tid >> 2;
    int xr = (d & 7) << 3;
    unsigned short* dst = vTc + ((size_t)bh * Ddim + d) * Sdim + jt * 64;
    #pragma unroll
    for (int cc = 0; cc < 2; cc++) {
        int tb = (tid & 3) * 16 + cc * 8;
        bf16x8 o;
        #pragma unroll
        for (int i = 0; i < 8; i++) o[i] = (short)T[tb + i][d];
        *(bf16x8*)(dst + (tb ^ xr)) = o;
    }
}

// ================= 8-phase 512-thread MFMA GEMM (T2+T3+T4+T5) =================
// C = A(bf16 [M,ldK]) * Bt(bf16 [N,ldK])^T over K-chunk Kc at offset ks*Kc
// (split-K decoded from flat grid: bid = ks*gridM*gridN + bn*gridM + bm).
// EPI: 1 = fused QKV (rope->bf16), 3 = bias+silu->bf16,
//      5 = plain f32 write at OF + ks*ksStride (split-K partial buffers)
template <int EPI, int BM, int BN, int WM, int WN>
__global__ __launch_bounds__(512) void gemm8p(
    const unsigned short* __restrict__ A, const unsigned short* __restrict__ Bt,
    float* __restrict__ OF, unsigned short* __restrict__ Hq, unsigned short* __restrict__ Hk,
    unsigned short* __restrict__ Hv, const float* __restrict__ bias,
    const float* __restrict__ cosT, const float* __restrict__ sinT,
    int Kc, int ldK, int ldC, int gridM, int gridN, size_t ksStride) {
    constexpr int MI = BM / WM / 16, NI = BN / WN / 16;
    constexpr int MH = MI / 2, NH = NI / 2;
    constexpr int LA = BM / 128, LB = BN / 128;
    constexpr int HA = BM / WM / 2;   // A half-selector
    constexpr int HB = BN / WN / 2;   // B half-selector
    constexpr int ABUF = BM * 64, BBUF = BN * 64;

    __shared__ unsigned short lds[2 * ABUF + 2 * BBUF];

    int bid = blockIdx.x;
    const int nwg = gridDim.x;
    if ((nwg & 7) == 0) bid = (bid & 7) * (nwg >> 3) + (bid >> 3);   // XCD swizzle (bijective: nwg%8==0)
    const int mn = gridM * gridN;
    const int ks = bid / mn;
    const int rem = bid - ks * mn;
    const int bm = (rem % gridM) * BM;
    const int bn = (rem / gridM) * BN;
    const unsigned short* Ap = A + (size_t)ks * Kc;
    const unsigned short* Bp = Bt + (size_t)ks * Kc;

    const int tid = threadIdx.x;
    const int lane = tid & 63, wid = tid >> 6;
    const int lc = lane & 15, lg = lane >> 4;
    const int wwm = wid / WN, wwn = wid % WN;

    const int srow = tid >> 3;                    // 0..63
    const int scol = ((tid & 7) ^ (srow & 7)) * 8;
    const int ak0 = (lg * 8) ^ ((lc & 7) * 8);
    const int ak1 = (32 + lg * 8) ^ ((lc & 7) * 8);

    f32x4 acc[MI][NI];
    f32x4 zero = {0.0f, 0.0f, 0.0f, 0.0f};
    #pragma unroll
    for (int i = 0; i < MI; i++)
        #pragma unroll
        for (int j = 0; j < NI; j++) acc[i][j] = zero;

    bf16x8 a[MH][2], b0[NH][2], b1[NH][2];

    auto stage_a = [&](int half, int nbuf, int kt) {
        #pragma unroll
        for (int j = 0; j < LA; j++) {
            const int idx = j * 64 + srow;                          // [0, BM/2)
            const int grow = (idx / HA) * (BM / WM) + half * HA + (idx % HA);
            const unsigned short* g = Ap + (size_t)(bm + grow) * ldK + kt + scol;
            GLD16(g, &lds[nbuf * ABUF + half * (ABUF / 2) + (j * 512 + tid) * 8]);
        }
    };
    auto stage_b = [&](int half, int nbuf, int kt) {
        #pragma unroll
        for (int j = 0; j < LB; j++) {
            const int idx = j * 64 + srow;                          // [0, BN/2)
            const int grow = (idx / HB) * (BN / WN) + half * HB + (idx % HB);
            const unsigned short* g = Bp + (size_t)(bn + grow) * ldK + kt + scol;
            GLD16(g, &lds[2 * ABUF + nbuf * BBUF + half * (BBUF / 2) + (j * 512 + tid) * 8]);
        }
    };

#define DS_A(mh_, cur_)                                                                   \
    _Pragma("unroll") for (int m = 0; m < MH; m++) {                                      \
        const int ro = (cur_)*ABUF + (mh_) * (ABUF / 2) + (wwm * HA + m * 16 + lc) * 64;  \
        a[m][0] = *(const bf16x8*)&lds[ro + ak0];                                         \
        a[m][1] = *(const bf16x8*)&lds[ro + ak1];                                         \
    }
#define DS_B(bb_, nh_, cur_)                                                              \
    _Pragma("unroll") for (int n = 0; n < NH; n++) {                                      \
        const int ro = 2 * ABUF + (cur_)*BBUF + (nh_) * (BBUF / 2) + (wwn * HB + n * 16 + lc) * 64; \
        bb_[n][0] = *(const bf16x8*)&lds[ro + ak0];                                       \
        bb_[n][1] = *(const bf16x8*)&lds[ro + ak1];                                       \
    }
#define MFMA_PH(mh_, nh_, bb_)                                                            \
    __builtin_amdgcn_s_setprio(1);                                                        \
    _Pragma("unroll") for (int m = 0; m < MH; m++) _Pragma("unroll") for (int n = 0; n < NH; n++) { \
        acc[(mh_)*MH + m][(nh_)*NH + n] = MFMA16(a[m][0], bb_[n][0], acc[(mh_)*MH + m][(nh_)*NH + n]); \
        acc[(mh_)*MH + m][(nh_)*NH + n] = MFMA16(a[m][1], bb_[n][1], acc[(mh_)*MH + m][(nh_)*NH + n]); \
    }                                                                                     \
    __builtin_amdgcn_s_setprio(0);
#define BAR_PRE()                                                                         \
    __builtin_amdgcn_sched_barrier(0);                                                    \
    __builtin_amdgcn_s_barrier();
#define BAR_END()                                                                         \
    asm volatile("" ::: "memory");                                                        \
    __builtin_amdgcn_s_barrier();                                                         \
    __builtin_amdgcn_sched_barrier(0);

    // prologue: tile 0 half-tiles in steady-state order; leave {Bh1,Ah1} in flight
    stage_a(0, 0, 0);
    stage_b(0, 0, 0);
    stage_b(1, 0, 0);
    stage_a(1, 0, 0);
    vwait<LA + LB>();
    BAR_END();

    const int NT = Kc >> 6;
    for (int t = 0; t < NT; t++) {
        const int cur = t & 1, nxt = cur ^ 1;
        const int ktn = (t + 1 < NT) ? (t + 1) * 64 : t * 64;
        // phase 1: quadrant (0,0)
        DS_A(0, cur);
        DS_B(b0, 0, cur);
        stage_a(0, nxt, ktn);
        BAR_PRE();
        MFMA_PH(0, 0, b0);
        vwait<2 * LA>();            // completes B_h1(cur)
        BAR_END();
        // phase 2: quadrant (0,1)
        DS_B(b1, 1, cur);
        stage_b(0, nxt, ktn);
        BAR_PRE();
        MFMA_PH(0, 1, b1);
        vwait<LA + LB>();           // completes A_h1(cur)
        BAR_END();
        // phase 3: quadrant (1,1)
        DS_A(1, cur);
        stage_b(1, nxt, ktn);
        BAR_PRE();
        MFMA_PH(1, 1, b1);
        BAR_END();
        // phase 4: quadrant (1,0)
        stage_a(1, nxt, ktn);
        BAR_PRE();
        MFMA_PH(1, 0, b0);
        vwait<LA + LB>();           // completes A_h0, B_h0 of nxt
        BAR_END();
    }
    asm volatile("s_waitcnt vmcnt(0)" ::: "memory");   // drain LDS-destined loads before endpgm
#undef DS_A
#undef DS_B
#undef MFMA_PH
#undef BAR_PRE
#undef BAR_END

    // epilogue. D frag layout: row = lg*4 + r, col = lc
    #pragma unroll
    for (int i = 0; i < MI; i++) {
        if (EPI == 1) {
            const int colbase = bn + wwn * (BN / WN);
            const int zc = colbase >> 10;                 // 0=q 1=k 2=v
            unsigned short* OH = (zc == 0) ? Hq : (zc == 1) ? Hk : Hv;
            const int hcol = (colbase >> 6) & 15;
            #pragma unroll
            for (int r = 0; r < 4; r++) {
                int row = bm + wwm * (BM / WM) + i * 16 + lg * 4 + r;
                int b = row >> 10, s = row & 1023;
                size_t base = ((size_t)(b * Hdim + hcol) * Sdim + s) << 6;
                if (zc == 2) {
                    #pragma unroll
                    for (int j = 0; j < 4; j++) OH[base + j * 16 + lc] = f2bf(acc[i][j][r]);
                } else {
                    #pragma unroll
                    for (int j = 0; j < 2; j++) {
                        int d = j * 16 + lc;              // [0,32)
                        float x1 = acc[i][j][r];
                        float x2 = acc[i][j + 2][r];
                        float c = cosT[s * 64 + d];
                        float sn = sinT[s * 64 + d];
                        OH[base + d] = f2bf(x1 * c - x2 * sn);
                        OH[base + d + 32] = f2bf(x2 * c + x1 * sn);
                    }
                }
            }
        } else {
            float* OFk = OF + (size_t)ks * ksStride;
            #pragma unroll
            for (int r = 0; r < 4; r++) {
                int row = bm + wwm * (BM / WM) + i * 16 + lg * 4 + r;
                #pragma unroll
                for (int j = 0; j < NI; j++) {
                    int col = bn + wwn * (BN / WN) + j * 16 + lc;
                    float v = acc[i][j][r];
                    if (EPI == 3) {
                        float t = v + bias[col];
                        Hq[(size_t)row * ldC + col] = f2bf(t / (1.0f + expf(-t)));
                    } else {
                        OFk[(size_t)row * ldC + col] = v;
                    }
                }
            }
        }
    }
}

// ---------------- flash attention over compacted keys (routed bias) ----------------
__global__ __launch_bounds__(256) void attn_kernel(const unsigned short* __restrict__ q16,
                                                   const unsigned short* __restrict__ k16,
                                                   const unsigned short* __restrict__ vTc,
                                                   const int* __restrict__ idxC,
                                                   const float* __restrict__ biasC,
                                                   const int* __restrict__ ntA,
                                                   unsigned short* __restrict__ o16) {
    const int qb = blockIdx.x;   // 16 (64 q rows each)
    const int bh = blockIdx.y;   // 32
    const int tid = threadIdx.x;
    const int w = tid >> 6, lane = tid & 63;
    const int lg = lane >> 4, lc = lane & 15;
    const int nt = ntA[bh];

    __shared__ unsigned short Ks[2][64 * 64];
    __shared__ unsigned short Vs[2][64 * 64];
    __shared__ unsigned short Pq[4][16][72];
    __shared__ float sbAll[1024];

    {
        const float4 bv = ((const float4*)(biasC + (size_t)bh * Sdim))[tid];
        *(float4*)&sbAll[tid * 4] = bv;
    }

    const int qrow = qb * 64 + w * 16 + lc;
    const unsigned short* qbase = q16 + ((size_t)bh * Sdim + qrow) * Ddim;
    bf16x8 qf[2];
    qf[0] = *(const bf16x8*)(qbase + lg * 8);
    qf[1] = *(const bf16x8*)(qbase + 32 + lg * 8);

    const int grow = tid >> 3;                 // 0..31
    const int gc = (tid & 7) * 8;
    const int ksw = (grow & 7) << 3;           // K source-col swizzle
    const unsigned short* kbase = k16 + (size_t)bh * Sdim * Ddim;
    const int* ibase = idxC + (size_t)bh * Sdim;
    const unsigned short* vbase = vTc + (size_t)bh * Ddim * Sdim;

    auto stageK = [&](int buf, int t1) {
        int s0 = ibase[t1 + grow];
        int s1 = ibase[t1 + 32 + grow];
        GLD16(kbase + (size_t)s0 * Ddim + (gc ^ ksw), &Ks[buf][tid * 8]);
        GLD16(kbase + (size_t)s1 * Ddim + (gc ^ ksw), &Ks[buf][2048 + tid * 8]);
    };

    {
        stageK(0, 0);
        const unsigned short* vg = vbase + (size_t)grow * Sdim + gc;
        GLD16(vg, &Vs[0][tid * 8]);
        GLD16(vg + 32 * Sdim, &Vs[0][2048 + tid * 8]);
    }
    __syncthreads();

    float m_i = -1e30f, l_i = 0.0f;
    f32x4 ot[4];
    f32x4 zero = {0.0f, 0.0f, 0.0f, 0.0f};
    #pragma unroll
    for (int fd = 0; fd < 4; fd++) ot[fd] = zero;

    const int sw = (lc & 7) << 3;

    for (int tt = 0; tt < nt; tt++) {
        const int cur = tt & 1;
        if (tt > 0) {
            asm volatile("s_waitcnt vmcnt(0)" ::: "memory");
            __builtin_amdgcn_sched_barrier(0);
            __builtin_amdgcn_s_barrier();
        }
        if (tt < nt - 1) {
            const int t1 = (tt + 1) * 64;
            stageK(cur ^ 1, t1);
            const unsigned short* vg = vbase + (size_t)grow * Sdim + t1 + gc;
            GLD16(vg, &Vs[cur ^ 1][tid * 8]);
            GLD16(vg + 32 * Sdim, &Vs[cur ^ 1][2048 + tid * 8]);
        }

        f32x4 sf[4];
        #pragma unroll
        for (int f = 0; f < 4; f++) {
            const int trow = f * 16 + lc;
            f32x4 a = zero;
            #pragma unroll
            for (int ks = 0; ks < 2; ks++) {
                bf16x8 kfr = *(bf16x8*)&Ks[cur][trow * 64 + ((ks * 32 + lg * 8) ^ sw)];
                a = MFMA16(kfr, qf[ks], a);
            }
            sf[f] = a;
        }
        const int t0 = tt * 64;
        float tmax = -1e30f;
        #pragma unroll
        for (int f = 0; f < 4; f++)
            #pragma unroll
            for (int j = 0; j < 4; j++) {
                float v = sf[f][j] * 0.125f + sbAll[t0 + f * 16 + lg * 4 + j];
                sf[f][j] = v;
                tmax = fmaxf(tmax, v);
            }
        tmax = fmaxf(tmax, __shfl_xor(tmax, 16));
        tmax = fmaxf(tmax, __shfl_xor(tmax, 32));
        float mnew = fmaxf(m_i, tmax);
        float alpha = expf(m_i - mnew);
        float lsum = 0.0f;
        #pragma unroll
        for (int f = 0; f < 4; f++)
            #pragma unroll
            for (int j = 0; j < 4; j++) {
                float p = expf(sf[f][j] - mnew);
                sf[f][j] = p;
                lsum += p;
            }
        lsum += __shfl_xor(lsum, 16);
        lsum += __shfl_xor(lsum, 32);
        l_i = l_i * alpha + lsum;
        m_i = mnew;
        #pragma unroll
        for (int fd = 0; fd < 4; fd++)
            #pragma unroll
            for (int j = 0; j < 4; j++) ot[fd][j] *= alpha;
        #pragma unroll
        for (int f = 0; f < 4; f++) {
            short4 ps = make_short4((short)f2bf(sf[f][0]), (short)f2bf(sf[f][1]),
                                    (short)f2bf(sf[f][2]), (short)f2bf(sf[f][3]));
            *(short4*)&Pq[w][lc][f * 16 + lg * 4] = ps;
        }
        #pragma unroll
        for (int ks = 0; ks < 2; ks++) {
            bf16x8 pf = *(bf16x8*)&Pq[w][lc][ks * 32 + lg * 8];
            #pragma unroll
            for (int fd = 0; fd < 4; fd++) {
                bf16x8 vfr = *(bf16x8*)&Vs[cur][(fd * 16 + lc) * 64 + ((ks * 32 + lg * 8) ^ sw)];
                ot[fd] = MFMA16(vfr, pf, ot[fd]);
            }
        }
    }
    asm volatile("s_waitcnt vmcnt(0)" ::: "memory");   // drain LDS-destined loads before endpgm
    float rl = 1.0f / l_i;
    int b = bh >> 4, h = bh & 15;
    #pragma unroll
    for (int fd = 0; fd < 4; fd++)
        #pragma unroll
        for (int j = 0; j < 4; j++) {
            int d = fd * 16 + lg * 4 + j;
            o16[((size_t)b * Sdim + qrow) * HDdim + h * 64 + d] = f2bf(ot[fd][j] * rl);
        }
}

extern "C" void kernel_launch(void* const* d_in, const int* in_sizes, int n_in,
                              void* d_out, int out_size, void* d_ws, size_t ws_size,
                              hipStream_t stream) {
    const int* ids = (const int*)d_in[0];
    const float* amask = (const float*)d_in[1];
    const float* emb = (const float*)d_in[2];
    const float* ln1w = (const float*)d_in[3];
    const float* ln1b = (const float*)d_in[4];
    const float* Wq = (const float*)d_in[5];
    const float* Wk = (const float*)d_in[6];
    const float* Wv = (const float*)d_in[7];
    const float* Wo = (const float*)d_in[8];
    const float* Wr = (const float*)d_in[9];
    const float* ln2w = (const float*)d_in[10];
    const float* ln2b = (const float*)d_in[11];
    const float* W1 = (const float*)d_in[12];
    const float* b1 = (const float*)d_in[13];
    const float* W2 = (const float*)d_in[14];
    const float* b2 = (const float*)d_in[15];
    const float* nw = (const float*)d_in[16];
    const float* nb = (const float*)d_in[17];
    const float* lmh = (const float*)d_in[18];
    float* out = (float*)d_out;

    char* p = (char*)d_ws;
    size_t off = 0;
    auto alloc = [&](size_t bytes) -> void* {
        void* r = p + off;
        off += (bytes + 255) & ~(size_t)255;
        return r;
    };
    float* cosT = (float*)alloc((size_t)Sdim * Ddim * 4);
    float* sinT = (float*)alloc((size_t)Sdim * Ddim * 4);
    float* x = (float*)alloc((size_t)BSdim * HDdim * 4);
    unsigned short* h16 = (unsigned short*)alloc((size_t)BSdim * HDdim * 2);
    unsigned short* o16 = (unsigned short*)alloc((size_t)BSdim * HDdim * 2);
    unsigned short* m16 = (unsigned short*)alloc((size_t)BSdim * Idim * 2);
    unsigned short* q16 = (unsigned short*)alloc((size_t)Bdim * Hdim * Sdim * Ddim * 2);
    unsigned short* k16 = (unsigned short*)alloc((size_t)Bdim * Hdim * Sdim * Ddim * 2);
    unsigned short* v16 = (unsigned short*)alloc((size_t)Bdim * Hdim * Sdim * Ddim * 2);
    unsigned short* vTc = (unsigned short*)alloc((size_t)Bdim * Hdim * Sdim * Ddim * 2);
    float* router = (float*)alloc((size_t)Bdim * Hdim * Sdim * 4);
    float* biasC = (float*)alloc((size_t)Bdim * Hdim * Sdim * 4);
    int* idxC = (int*)alloc((size_t)Bdim * Hdim * Sdim * 4);
    int* ntA = (int*)alloc((size_t)Bdim * Hdim * 4);
    float* po = (float*)alloc((size_t)2 * BSdim * HDdim * 4);   // Wo split-K partials
    float* pw = (float*)alloc((size_t)4 * BSdim * HDdim * 4);   // W2 split-K partials
    unsigned short* wts = (unsigned short*)alloc((size_t)Vdim * HDdim * 2);        // 64MB lm_head
    unsigned short* wtsL = (unsigned short*)alloc((size_t)Ldim * 12 * (1u << 20) * 2);  // 96MB layer weights

    const size_t M1 = 1u << 20;  // 1M elems
    const size_t PS = (size_t)BSdim * HDdim;

    init_kernel<<<BSdim + 256, 256, 0, stream>>>(ids, emb, x, cosT, sinT);
    tconv_all<<<49152 + 32000, 256, 0, stream>>>(Wq, Wk, Wv, Wo, W1, W2, lmh, wtsL, wts);

    for (int l = 0; l < Ldim; l++) {
        unsigned short* wl = wtsL + (size_t)l * 12 * M1;
        const float* Wr_l = Wr + (size_t)l * HDdim * Hdim;
        const float* b1_l = b1 + (size_t)l * Idim;
        const float* b2_l = b2 + (size_t)l * HDdim;

        // ln1 (+fused router). For l>0 it also folds in prev layer's W2 partials + b2.
        if (l == 0)
            ln_kernel<0><<<BSdim, 256, 0, stream>>>(x, nullptr, nullptr, 0, nullptr,
                                                    ln1w + l * HDdim, ln1b + l * HDdim, h16, Wr_l, router);
        else
            ln_kernel<4><<<BSdim, 256, 0, stream>>>(x, x, pw, PS, b2 + (size_t)(l - 1) * HDdim,
                                                    ln1w + l * HDdim, ln1b + l * HDdim, h16, Wr_l, router);
        topk_kernel<<<Bdim * Hdim, 1024, 0, stream>>>(router, amask, biasC, idxC, ntA);
        // fused QKV GEMM (8-phase, 128x128): grid 16 x 24 = 384
        gemm8p<1, 128, 128, 4, 2><<<384, 512, 0, stream>>>(h16, wl, nullptr, q16, k16, v16,
                                                           nullptr, cosT, sinT, HDdim, HDdim, 0, 16, 24, 0);
        // compacted V^T gather; K gathered in-attn
        vgather_kernel<<<dim3(16, 32), 256, 0, stream>>>(v16, idxC, ntA, vTc);
        attn_kernel<<<dim3(16, 32), 256, 0, stream>>>(q16, k16, vTc, idxC, biasC, ntA, o16);
        // Wo GEMM (split-K=2 partial buffers): grid 16 x 8 x 2 = 256
        gemm8p<5, 128, 128, 4, 2><<<256, 512, 0, stream>>>(o16, wl + 3 * M1, po, nullptr, nullptr, nullptr,
                                                           nullptr, nullptr, nullptr, 512, HDdim, HDdim, 16, 8, PS);
        // ln2 folds in Wo partials (x += po0+po1) and LNs the result
        ln_kernel<2><<<BSdim, 256, 0, stream>>>(x, x, po, PS, nullptr,
                                                ln2w + l * HDdim, ln2b + l * HDdim, h16, nullptr, nullptr);
        // W1 GEMM (bias+silu): grid 16 x 32 = 512
        gemm8p<3, 128, 128, 4, 2><<<512, 512, 0, stream>>>(h16, wl + 4 * M1, nullptr, m16, nullptr, nullptr,
                                                           b1_l, nullptr, nullptr, HDdim, HDdim, Idim, 16, 32, 0);
        // W2 GEMM (split-K=4 partial buffers): grid 16 x 8 x 4 = 512
        gemm8p<5, 128, 128, 4, 2><<<512, 512, 0, stream>>>(m16, wl + 8 * M1, pw, nullptr, nullptr, nullptr,
                                                           nullptr, nullptr, nullptr, 1024, Idim, HDdim, 16, 8, PS);
    }

    // final ln folds in last layer's W2 partials + b2
    ln_kernel<4><<<BSdim, 256, 0, stream>>>(x, nullptr, pw, PS, b2 + (size_t)3 * HDdim,
                                            nw, nb, h16, nullptr, nullptr);
    // lm_head (256x256), split into two dispatches (diagnostic: exposes mid-size kernels in top-5)
    gemm8p<5, 256, 256, 2, 4><<<496, 512, 0, stream>>>(h16, wts, out, nullptr, nullptr, nullptr,
                                                       nullptr, nullptr, nullptr, HDdim, HDdim, Vdim, 8, 62, 0);
    gemm8p<5, 256, 256, 2, 4><<<504, 512, 0, stream>>>(h16, wts + (size_t)62 * 256 * HDdim, out + 62 * 256,
                                                       nullptr, nullptr, nullptr, nullptr, nullptr, nullptr,
                                                       HDdim, HDdim, Vdim, 8, 63, 0);
}

// Round 11
// 987.401 us; speedup vs baseline: 2.2157x; 1.0015x over previous
//
#include <hip/hip_runtime.h>
#include <hip/hip_bf16.h>

#define Bdim 2
#define Sdim 1024
#define Vdim 32000
#define HDdim 1024
#define Ldim 4
#define Hdim 16
#define Ddim 64
#define Idim 4096
#define BSdim 2048

typedef __attribute__((ext_vector_type(8))) short bf16x8;
typedef __attribute__((ext_vector_type(4))) float f32x4;

__device__ __forceinline__ unsigned short f2bf(float f) {
    __hip_bfloat16 h = __float2bfloat16(f);
    return *reinterpret_cast<unsigned short*>(&h);
}

#define MFMA16(a, b, c) __builtin_amdgcn_mfma_f32_16x16x32_bf16((a), (b), (c), 0, 0, 0)

#define GLD16(gp, lp)                                                            \
    __builtin_amdgcn_global_load_lds((const __attribute__((address_space(1))) void*)(gp), \
                                     (__attribute__((address_space(3))) void*)(lp), 16, 0, 0)

template <int N>
__device__ __forceinline__ void vwait() {
    if constexpr (N == 2) asm volatile("s_waitcnt vmcnt(2)" ::: "memory");
    else if constexpr (N == 3) asm volatile("s_waitcnt vmcnt(3)" ::: "memory");
    else if constexpr (N == 4) asm volatile("s_waitcnt vmcnt(4)" ::: "memory");
    else if constexpr (N == 6) asm volatile("s_waitcnt vmcnt(6)" ::: "memory");
}

// ---------------- init: embedding gather + rope tables (merged) ----------------
__global__ __launch_bounds__(256) void init_kernel(const int* __restrict__ ids, const float* __restrict__ emb,
                                                   float* __restrict__ x, float* __restrict__ cosT,
                                                   float* __restrict__ sinT) {
    int bid = blockIdx.x;
    int tid = threadIdx.x;
    if (bid < BSdim) {
        int id = ids[bid];
        const float4* src = (const float4*)(emb + (size_t)id * HDdim);
        ((float4*)(x + (size_t)bid * HDdim))[tid] = src[tid];
    } else {
        int i = (bid - BSdim) * 256 + tid;   // 65536 = S*D
        int d = i & 63;
        int s = i >> 6;
        float inv = powf(1.0e6f, -((float)(2 * (d & 31))) / 64.0f);
        float f = (float)s * inv;
        cosT[i] = cosf(f);
        sinT[i] = sinf(f);
    }
}

// ---------------- layernorm (+ fused residual-partial reduction, + optional router) ----------------
// a = x[m] + sum_{p<NP} parts[p][m] + badd  ; optionally write a back to xout; LN(a) -> outH
template <int NP>
__global__ __launch_bounds__(256) void ln_kernel(const float* __restrict__ x, float* __restrict__ xout,
                                                 const float* __restrict__ parts, size_t pstride,
                                                 const float* __restrict__ badd,
                                                 const float* __restrict__ w, const float* __restrict__ bw,
                                                 unsigned short* __restrict__ outH,
                                                 const float* __restrict__ Wr, float* __restrict__ routerO) {
    int m = blockIdx.x;
    int tid = threadIdx.x;
    float4 a = ((const float4*)(x + (size_t)m * HDdim))[tid];
    #pragma unroll
    for (int p = 0; p < NP; p++) {
        float4 q = ((const float4*)(parts + p * pstride + (size_t)m * HDdim))[tid];
        a.x += q.x; a.y += q.y; a.z += q.z; a.w += q.w;
    }
    if (badd) {
        float4 bb = ((const float4*)badd)[tid];
        a.x += bb.x; a.y += bb.y; a.z += bb.z; a.w += bb.w;
    }
    if (xout) ((float4*)(xout + (size_t)m * HDdim))[tid] = a;

    float s = a.x + a.y + a.z + a.w;
    #pragma unroll
    for (int o = 1; o < 64; o <<= 1) s += __shfl_xor(s, o);
    __shared__ float red[4], red2[4];
    if ((tid & 63) == 0) red[tid >> 6] = s;
    __syncthreads();
    float mean = (red[0] + red[1] + red[2] + red[3]) * (1.0f / 1024.0f);
    float dx = a.x - mean, dy = a.y - mean, dz = a.z - mean, dw = a.w - mean;
    float s2 = dx * dx + dy * dy + dz * dz + dw * dw;
    #pragma unroll
    for (int o = 1; o < 64; o <<= 1) s2 += __shfl_xor(s2, o);
    if ((tid & 63) == 0) red2[tid >> 6] = s2;
    __syncthreads();
    float var = (red2[0] + red2[1] + red2[2] + red2[3]) * (1.0f / 1024.0f);
    float rs = rsqrtf(var + 1e-6f);
    float4 wv = ((const float4*)w)[tid];
    float4 bv = ((const float4*)bw)[tid];
    float v0 = dx * rs * wv.x + bv.x;
    float v1 = dy * rs * wv.y + bv.y;
    float v2 = dz * rs * wv.z + bv.z;
    float v3 = dw * rs * wv.w + bv.w;
    short4 st = make_short4((short)f2bf(v0), (short)f2bf(v1), (short)f2bf(v2), (short)f2bf(v3));
    *(short4*)(outH + (size_t)m * HDdim + tid * 4) = st;

    if (Wr) {   // fused router: routerO[b][h][s] = h_norm . Wr[:,h]
        __shared__ float rbuf[256][16];
        __shared__ float pbuf[16][17];
        float part[16];
        const float* wr0 = Wr + (size_t)(tid * 4) * Hdim;
        #pragma unroll
        for (int h = 0; h < 16; h++)
            part[h] = v0 * wr0[h] + v1 * wr0[16 + h] + v2 * wr0[32 + h] + v3 * wr0[48 + h];
        #pragma unroll
        for (int h4 = 0; h4 < 4; h4++)
            *(float4*)&rbuf[tid][h4 * 4] = make_float4(part[h4 * 4], part[h4 * 4 + 1], part[h4 * 4 + 2], part[h4 * 4 + 3]);
        __syncthreads();
        {
            int h = tid & 15, g = tid >> 4;
            float sgr = 0.0f;
            #pragma unroll
            for (int i = 0; i < 16; i++) sgr += rbuf[g * 16 + i][h];
            pbuf[g][h] = sgr;
        }
        __syncthreads();
        if (tid < 16) {
            float tot = 0.0f;
            #pragma unroll
            for (int g = 0; g < 16; g++) tot += pbuf[g][tid];
            int b = m >> 10, sI = m & 1023;
            routerO[((size_t)(b * Hdim + tid)) * Sdim + sI] = tot;
        }
    }
}

// ---------------- exact top-k threshold + compacted bias/index ----------------
__global__ __launch_bounds__(1024) void topk_kernel(const float* __restrict__ router, const float* __restrict__ amask,
                                                    float* __restrict__ biasC, int* __restrict__ idxC,
                                                    int* __restrict__ ntA) {
    int bh = blockIdx.x;
    int t = threadIdx.x;
    __shared__ float r[1024];
    __shared__ float kths;
    __shared__ int wcnt[16];
    float v = router[(size_t)bh * Sdim + t];
    r[t] = v;
    __syncthreads();
    int gt = 0, eq = 0;
    for (int j = 0; j < 1024; j++) {
        float xv = r[j];
        gt += (xv > v) ? 1 : 0;
        eq += (xv == v) ? 1 : 0;
    }
    if (gt < 512 && gt + eq >= 512) kths = v;
    // init pad region (ordered before scatter by the barrier below)
    biasC[(size_t)bh * Sdim + t] = -1e9f;
    idxC[(size_t)bh * Sdim + t] = 0;
    __syncthreads();
    float kth = kths;
    bool sel = (v >= kth);
    unsigned long long m = __ballot(sel);
    int wid = t >> 6, lane = t & 63;
    if (lane == 0) wcnt[wid] = __popcll(m);
    __syncthreads();
    int base = 0;
    for (int w = 0; w < wid; w++) base += wcnt[w];
    if (sel) {
        int rank = base + (int)__popcll(m & ((1ull << lane) - 1ull));
        float bias = (v >= 0.0f) ? -log1pf(expf(-v)) : (v - log1pf(expf(v)));
        int b = bh >> 4;
        bias += (1.0f - amask[b * Sdim + t]) * (-1e9f);
        biasC[(size_t)bh * Sdim + rank] = bias;
        idxC[(size_t)bh * Sdim + rank] = t;
    }
    if (t == 0) {
        int tot = 0;
        #pragma unroll
        for (int w = 0; w < 16; w++) tot += wcnt[w];
        ntA[bh] = (tot + 63) >> 6;
    }
}

// ---------------- all weight prepass: 4 x (QKVO + W1 + W2) + lm_head in one dispatch ----------------
__global__ __launch_bounds__(256) void tconv_all(const float* __restrict__ Wq, const float* __restrict__ Wk,
                                                 const float* __restrict__ Wv, const float* __restrict__ Wo,
                                                 const float* __restrict__ W1, const float* __restrict__ W2,
                                                 const float* __restrict__ lmh,
                                                 unsigned short* __restrict__ wtsL,
                                                 unsigned short* __restrict__ wtsLM) {
    const size_t M1 = 1u << 20;
    int bid = blockIdx.x;
    const float* S;
    unsigned short* D;
    int K, ldS, nt, kt;
    if (bid < 49152) {
        int lid = bid / 12288, sub = bid - lid * 12288;
        unsigned short* wl = wtsL + (size_t)lid * 12 * M1;
        if (sub < 4096) {            // QKVO: 4 x [1024][1024]
            int z = sub >> 10, t = sub & 1023;
            S = ((z == 0) ? Wq : (z == 1) ? Wk : (z == 2) ? Wv : Wo) + (size_t)lid * M1;
            D = wl + (size_t)z * M1;
            K = 1024; ldS = 1024; nt = t & 31; kt = t >> 5;
        } else if (sub < 8192) {     // W1: [1024][4096]
            int t = sub - 4096;
            S = W1 + (size_t)lid * 4 * M1; D = wl + 4 * M1;
            K = 1024; ldS = 4096; nt = t % 128; kt = t / 128;
        } else {                     // W2: [4096][1024]
            int t = sub - 8192;
            S = W2 + (size_t)lid * 4 * M1; D = wl + 8 * M1;
            K = 4096; ldS = 1024; nt = t % 32; kt = t / 32;
        }
    } else {                         // lm_head: [1024][32000]
        int t = bid - 49152;
        S = lmh; D = wtsLM;
        K = 1024; ldS = Vdim; nt = t % 1000; kt = t / 1000;
    }
    __shared__ float tb[32][33];
    int ktb = kt * 32, ntb = nt * 32;
    int r = threadIdx.x >> 3, c4 = (threadIdx.x & 7) * 4;
    float4 v = *(const float4*)(S + (size_t)(ktb + r) * ldS + ntb + c4);
    tb[r][c4] = v.x; tb[r][c4 + 1] = v.y; tb[r][c4 + 2] = v.z; tb[r][c4 + 3] = v.w;
    __syncthreads();
    short4 o = make_short4((short)f2bf(tb[c4][r]), (short)f2bf(tb[c4 + 1][r]),
                           (short)f2bf(tb[c4 + 2][r]), (short)f2bf(tb[c4 + 3][r]));
    *(short4*)(D + (size_t)(ntb + r) * K + ktb + c4) = o;
}

// ---------------- compacted V^T gather (XOR swizzle baked in) ----------------
__global__ __launch_bounds__(256) void vgather_kernel(const unsigned short* __restrict__ v16,
                                                      const int* __restrict__ idxC, const int* __restrict__ ntA,
                                                      unsigned short* __restrict__ vTc) {
    int jt = blockIdx.x;        // 16
    int bh = blockIdx.y;        // 32
    if (jt >= ntA[bh]) return;
    __shared__ unsigned short T[64][72];
    int tid = threadIdx.x;
    int jl = tid >> 2;
    int part = tid & 3;
    int j = jt * 64 + jl;
    int src = idxC[(size_t)bh * Sdim + j];
    const unsigned short* vr = v16 + ((size_t)bh * Sdim + src) * Ddim + part * 16;
    *(bf16x8*)&T[jl][part * 16] = *(const bf16x8*)vr;
    *(bf16x8*)&T[jl][part * 16 + 8] = *(const bf16x8*)(vr + 8);
    __syncthreads();
    int d = tid >> 2;
    int xr = (d & 7) << 3;
    unsigned short* dst = vTc + ((size_t)bh * Ddim + d) * Sdim + jt * 64;
    #pragma unroll
    for (int cc = 0; cc < 2; cc++) {
        int tb = (tid & 3) * 16 + cc * 8;
        bf16x8 o;
        #pragma unroll
        for (int i = 0; i < 8; i++) o[i] = (short)T[tb + i][d];
        *(bf16x8*)(dst + (tb ^ xr)) = o;
    }
}

// ================= 8-phase 512-thread MFMA GEMM (T2+T3+T4+T5) =================
// EPI: 1 = fused QKV (rope->bf16), 3 = bias+silu->bf16,
//      5 = plain f32 write at OF + ks*ksStride, 7 = nontemporal f32 write
template <int EPI, int BM, int BN, int WM, int WN>
__global__ __launch_bounds__(512) void gemm8p(
    const unsigned short* __restrict__ A, const unsigned short* __restrict__ Bt,
    float* __restrict__ OF, unsigned short* __restrict__ Hq, unsigned short* __restrict__ Hk,
    unsigned short* __restrict__ Hv, const float* __restrict__ bias,
    const float* __restrict__ cosT, const float* __restrict__ sinT,
    int Kc, int ldK, int ldC, int gridM, int gridN, size_t ksStride) {
    constexpr int MI = BM / WM / 16, NI = BN / WN / 16;
    constexpr int MH = MI / 2, NH = NI / 2;
    constexpr int LA = BM / 128, LB = BN / 128;
    constexpr int HA = BM / WM / 2;   // A half-selector
    constexpr int HB = BN / WN / 2;   // B half-selector
    constexpr int ABUF = BM * 64, BBUF = BN * 64;

    __shared__ unsigned short lds[2 * ABUF + 2 * BBUF];

    int bid = blockIdx.x;
    const int nwg = gridDim.x;
    if ((nwg & 7) == 0) bid = (bid & 7) * (nwg >> 3) + (bid >> 3);   // XCD swizzle (bijective: nwg%8==0)
    const int mn = gridM * gridN;
    const int ks = bid / mn;
    const int rem = bid - ks * mn;
    const int bm = (rem % gridM) * BM;
    const int bn = (rem / gridM) * BN;
    const unsigned short* Ap = A + (size_t)ks * Kc;
    const unsigned short* Bp = Bt + (size_t)ks * Kc;

    const int tid = threadIdx.x;
    const int lane = tid & 63, wid = tid >> 6;
    const int lc = lane & 15, lg = lane >> 4;
    const int wwm = wid / WN, wwn = wid % WN;

    const int srow = tid >> 3;                    // 0..63
    const int scol = ((tid & 7) ^ (srow & 7)) * 8;
    const int ak0 = (lg * 8) ^ ((lc & 7) * 8);
    const int ak1 = (32 + lg * 8) ^ ((lc & 7) * 8);

    f32x4 acc[MI][NI];
    f32x4 zero = {0.0f, 0.0f, 0.0f, 0.0f};
    #pragma unroll
    for (int i = 0; i < MI; i++)
        #pragma unroll
        for (int j = 0; j < NI; j++) acc[i][j] = zero;

    bf16x8 a[MH][2], b0[NH][2], b1[NH][2];

    auto stage_a = [&](int half, int nbuf, int kt) {
        #pragma unroll
        for (int j = 0; j < LA; j++) {
            const int idx = j * 64 + srow;                          // [0, BM/2)
            const int grow = (idx / HA) * (BM / WM) + half * HA + (idx % HA);
            const unsigned short* g = Ap + (size_t)(bm + grow) * ldK + kt + scol;
            GLD16(g, &lds[nbuf * ABUF + half * (ABUF / 2) + (j * 512 + tid) * 8]);
        }
    };
    auto stage_b = [&](int half, int nbuf, int kt) {
        #pragma unroll
        for (int j = 0; j < LB; j++) {
            const int idx = j * 64 + srow;                          // [0, BN/2)
            const int grow = (idx / HB) * (BN / WN) + half * HB + (idx % HB);
            const unsigned short* g = Bp + (size_t)(bn + grow) * ldK + kt + scol;
            GLD16(g, &lds[2 * ABUF + nbuf * BBUF + half * (BBUF / 2) + (j * 512 + tid) * 8]);
        }
    };

#define DS_A(mh_, cur_)                                                                   \
    _Pragma("unroll") for (int m = 0; m < MH; m++) {                                      \
        const int ro = (cur_)*ABUF + (mh_) * (ABUF / 2) + (wwm * HA + m * 16 + lc) * 64;  \
        a[m][0] = *(const bf16x8*)&lds[ro + ak0];                                         \
        a[m][1] = *(const bf16x8*)&lds[ro + ak1];                                         \
    }
#define DS_B(bb_, nh_, cur_)                                                              \
    _Pragma("unroll") for (int n = 0; n < NH; n++) {                                      \
        const int ro = 2 * ABUF + (cur_)*BBUF + (nh_) * (BBUF / 2) + (wwn * HB + n * 16 + lc) * 64; \
        bb_[n][0] = *(const bf16x8*)&lds[ro + ak0];                                       \
        bb_[n][1] = *(const bf16x8*)&lds[ro + ak1];                                       \
    }
#define MFMA_PH(mh_, nh_, bb_)                                                            \
    __builtin_amdgcn_s_setprio(1);                                                        \
    _Pragma("unroll") for (int m = 0; m < MH; m++) _Pragma("unroll") for (int n = 0; n < NH; n++) { \
        acc[(mh_)*MH + m][(nh_)*NH + n] = MFMA16(a[m][0], bb_[n][0], acc[(mh_)*MH + m][(nh_)*NH + n]); \
        acc[(mh_)*MH + m][(nh_)*NH + n] = MFMA16(a[m][1], bb_[n][1], acc[(mh_)*MH + m][(nh_)*NH + n]); \
    }                                                                                     \
    __builtin_amdgcn_s_setprio(0);
#define BAR_PRE()                                                                         \
    __builtin_amdgcn_sched_barrier(0);                                                    \
    __builtin_amdgcn_s_barrier();
#define BAR_END()                                                                         \
    asm volatile("" ::: "memory");                                                        \
    __builtin_amdgcn_s_barrier();                                                         \
    __builtin_amdgcn_sched_barrier(0);

    // prologue: tile 0 half-tiles in steady-state order; leave {Bh1,Ah1} in flight
    stage_a(0, 0, 0);
    stage_b(0, 0, 0);
    stage_b(1, 0, 0);
    stage_a(1, 0, 0);
    vwait<LA + LB>();
    BAR_END();

    const int NT = Kc >> 6;
    for (int t = 0; t < NT; t++) {
        const int cur = t & 1, nxt = cur ^ 1;
        const int ktn = (t + 1 < NT) ? (t + 1) * 64 : t * 64;
        // phase 1: quadrant (0,0)
        DS_A(0, cur);
        DS_B(b0, 0, cur);
        stage_a(0, nxt, ktn);
        BAR_PRE();
        MFMA_PH(0, 0, b0);
        vwait<2 * LA>();            // completes B_h1(cur)
        BAR_END();
        // phase 2: quadrant (0,1)
        DS_B(b1, 1, cur);
        stage_b(0, nxt, ktn);
        BAR_PRE();
        MFMA_PH(0, 1, b1);
        vwait<LA + LB>();           // completes A_h1(cur)
        BAR_END();
        // phase 3: quadrant (1,1)
        DS_A(1, cur);
        stage_b(1, nxt, ktn);
        BAR_PRE();
        MFMA_PH(1, 1, b1);
        BAR_END();
        // phase 4: quadrant (1,0)
        stage_a(1, nxt, ktn);
        BAR_PRE();
        MFMA_PH(1, 0, b0);
        vwait<LA + LB>();           // completes A_h0, B_h0 of nxt
        BAR_END();
    }
    asm volatile("s_waitcnt vmcnt(0)" ::: "memory");   // drain LDS-destined loads before endpgm
#undef DS_A
#undef DS_B
#undef MFMA_PH
#undef BAR_PRE
#undef BAR_END

    // epilogue. D frag layout: row = lg*4 + r, col = lc
    #pragma unroll
    for (int i = 0; i < MI; i++) {
        if (EPI == 1) {
            const int colbase = bn + wwn * (BN / WN);
            const int zc = colbase >> 10;                 // 0=q 1=k 2=v
            unsigned short* OH = (zc == 0) ? Hq : (zc == 1) ? Hk : Hv;
            const int hcol = (colbase >> 6) & 15;
            #pragma unroll
            for (int r = 0; r < 4; r++) {
                int row = bm + wwm * (BM / WM) + i * 16 + lg * 4 + r;
                int b = row >> 10, s = row & 1023;
                size_t base = ((size_t)(b * Hdim + hcol) * Sdim + s) << 6;
                if (zc == 2) {
                    #pragma unroll
                    for (int j = 0; j < 4; j++) OH[base + j * 16 + lc] = f2bf(acc[i][j][r]);
                } else {
                    #pragma unroll
                    for (int j = 0; j < 2; j++) {
                        int d = j * 16 + lc;              // [0,32)
                        float x1 = acc[i][j][r];
                        float x2 = acc[i][j + 2][r];
                        float c = cosT[s * 64 + d];
                        float sn = sinT[s * 64 + d];
                        OH[base + d] = f2bf(x1 * c - x2 * sn);
                        OH[base + d + 32] = f2bf(x2 * c + x1 * sn);
                    }
                }
            }
        } else {
            float* OFk = OF + (size_t)ks * ksStride;
            #pragma unroll
            for (int r = 0; r < 4; r++) {
                int row = bm + wwm * (BM / WM) + i * 16 + lg * 4 + r;
                #pragma unroll
                for (int j = 0; j < NI; j++) {
                    int col = bn + wwn * (BN / WN) + j * 16 + lc;
                    float v = acc[i][j][r];
                    if (EPI == 3) {
                        float t = v + bias[col];
                        Hq[(size_t)row * ldC + col] = f2bf(t / (1.0f + expf(-t)));
                    } else if (EPI == 7) {
                        __builtin_nontemporal_store(v, &OFk[(size_t)row * ldC + col]);
                    } else {
                        OFk[(size_t)row * ldC + col] = v;
                    }
                }
            }
        }
    }
}

// ---------------- flash attention over compacted keys (routed bias) ----------------
// QBLK=128: 8 waves x 16 q-rows; K gathered in-LDS-stage via idxC; V^T pre-gathered.
// T13 defer-max: skip O-rescale when the whole wave's tile-max growth <= 8.
__global__ __launch_bounds__(512) void attn_kernel(const unsigned short* __restrict__ q16,
                                                   const unsigned short* __restrict__ k16,
                                                   const unsigned short* __restrict__ vTc,
                                                   const int* __restrict__ idxC,
                                                   const float* __restrict__ biasC,
                                                   const int* __restrict__ ntA,
                                                   unsigned short* __restrict__ o16) {
    const int qb = blockIdx.x;   // 8 (128 q rows each)
    const int bh = blockIdx.y;   // 32
    const int tid = threadIdx.x;
    const int w = tid >> 6, lane = tid & 63;
    const int lg = lane >> 4, lc = lane & 15;
    const int nt = ntA[bh];

    __shared__ unsigned short Ks[2][64 * 64];
    __shared__ unsigned short Vs[2][64 * 64];
    __shared__ unsigned short Pq[8][16][72];
    __shared__ float sbAll[1024];

    {
        const float2 bv = ((const float2*)(biasC + (size_t)bh * Sdim))[tid];
        *(float2*)&sbAll[tid * 2] = bv;
    }

    const int qrow = qb * 128 + w * 16 + lc;
    const unsigned short* qbase = q16 + ((size_t)bh * Sdim + qrow) * Ddim;
    bf16x8 qf[2];
    qf[0] = *(const bf16x8*)(qbase + lg * 8);
    qf[1] = *(const bf16x8*)(qbase + 32 + lg * 8);

    const int grow = tid >> 3;                 // 0..63
    const int gc = (tid & 7) * 8;
    const int ksw = (grow & 7) << 3;           // K source-col swizzle
    const unsigned short* kbase = k16 + (size_t)bh * Sdim * Ddim;
    const int* ibase = idxC + (size_t)bh * Sdim;
    const unsigned short* vbase = vTc + (size_t)bh * Ddim * Sdim;

    auto stageKV = [&](int buf, int t1) {
        int s0 = ibase[t1 + grow];
        GLD16(kbase + (size_t)s0 * Ddim + (gc ^ ksw), &Ks[buf][tid * 8]);
        GLD16(vbase + (size_t)grow * Sdim + t1 + gc, &Vs[buf][tid * 8]);
    };

    stageKV(0, 0);
    __syncthreads();

    float m_i = -1e30f, l_i = 0.0f;
    f32x4 ot[4];
    f32x4 zero = {0.0f, 0.0f, 0.0f, 0.0f};
    #pragma unroll
    for (int fd = 0; fd < 4; fd++) ot[fd] = zero;

    const int sw = (lc & 7) << 3;

    for (int tt = 0; tt < nt; tt++) {
        const int cur = tt & 1;
        if (tt > 0) {
            asm volatile("s_waitcnt vmcnt(0)" ::: "memory");
            __builtin_amdgcn_sched_barrier(0);
            __builtin_amdgcn_s_barrier();
        }
        if (tt < nt - 1) {
            stageKV(cur ^ 1, (tt + 1) * 64);
        }

        f32x4 sf[4];
        #pragma unroll
        for (int f = 0; f < 4; f++) {
            const int trow = f * 16 + lc;
            f32x4 a = zero;
            #pragma unroll
            for (int ks = 0; ks < 2; ks++) {
                bf16x8 kfr = *(bf16x8*)&Ks[cur][trow * 64 + ((ks * 32 + lg * 8) ^ sw)];
                a = MFMA16(kfr, qf[ks], a);
            }
            sf[f] = a;
        }
        const int t0 = tt * 64;
        float tmax = -1e30f;
        #pragma unroll
        for (int f = 0; f < 4; f++)
            #pragma unroll
            for (int j = 0; j < 4; j++) {
                float v = sf[f][j] * 0.125f + sbAll[t0 + f * 16 + lg * 4 + j];
                sf[f][j] = v;
                tmax = fmaxf(tmax, v);
            }
        tmax = fmaxf(tmax, __shfl_xor(tmax, 16));
        tmax = fmaxf(tmax, __shfl_xor(tmax, 32));
        // T13 defer-max: rescale only when some lane's max grew by > 8
        if (!__all(tmax - m_i <= 8.0f)) {
            float mnew = fmaxf(m_i, tmax);
            float alpha = expf(m_i - mnew);
            l_i *= alpha;
            #pragma unroll
            for (int fd = 0; fd < 4; fd++)
                #pragma unroll
                for (int j = 0; j < 4; j++) ot[fd][j] *= alpha;
            m_i = mnew;
        }
        float lsum = 0.0f;
        #pragma unroll
        for (int f = 0; f < 4; f++)
            #pragma unroll
            for (int j = 0; j < 4; j++) {
                float p = expf(sf[f][j] - m_i);
                sf[f][j] = p;
                lsum += p;
            }
        lsum += __shfl_xor(lsum, 16);
        lsum += __shfl_xor(lsum, 32);
        l_i += lsum;
        #pragma unroll
        for (int f = 0; f < 4; f++) {
            short4 ps = make_short4((short)f2bf(sf[f][0]), (short)f2bf(sf[f][1]),
                                    (short)f2bf(sf[f][2]), (short)f2bf(sf[f][3]));
            *(short4*)&Pq[w][lc][f * 16 + lg * 4] = ps;
        }
        #pragma unroll
        for (int ks = 0; ks < 2; ks++) {
            bf16x8 pf = *(bf16x8*)&Pq[w][lc][ks * 32 + lg * 8];
            #pragma unroll
            for (int fd = 0; fd < 4; fd++) {
                bf16x8 vfr = *(bf16x8*)&Vs[cur][(fd * 16 + lc) * 64 + ((ks * 32 + lg * 8) ^ sw)];
                ot[fd] = MFMA16(vfr, pf, ot[fd]);
            }
        }
    }
    asm volatile("s_waitcnt vmcnt(0)" ::: "memory");   // drain LDS-destined loads before endpgm
    float rl = 1.0f / l_i;
    int b = bh >> 4, h = bh & 15;
    #pragma unroll
    for (int fd = 0; fd < 4; fd++)
        #pragma unroll
        for (int j = 0; j < 4; j++) {
            int d = fd * 16 + lg * 4 + j;
            o16[((size_t)b * Sdim + qrow) * HDdim + h * 64 + d] = f2bf(ot[fd][j] * rl);
        }
}

extern "C" void kernel_launch(void* const* d_in, const int* in_sizes, int n_in,
                              void* d_out, int out_size, void* d_ws, size_t ws_size,
                              hipStream_t stream) {
    const int* ids = (const int*)d_in[0];
    const float* amask = (const float*)d_in[1];
    const float* emb = (const float*)d_in[2];
    const float* ln1w = (const float*)d_in[3];
    const float* ln1b = (const float*)d_in[4];
    const float* Wq = (const float*)d_in[5];
    const float* Wk = (const float*)d_in[6];
    const float* Wv = (const float*)d_in[7];
    const float* Wo = (const float*)d_in[8];
    const float* Wr = (const float*)d_in[9];
    const float* ln2w = (const float*)d_in[10];
    const float* ln2b = (const float*)d_in[11];
    const float* W1 = (const float*)d_in[12];
    const float* b1 = (const float*)d_in[13];
    const float* W2 = (const float*)d_in[14];
    const float* b2 = (const float*)d_in[15];
    const float* nw = (const float*)d_in[16];
    const float* nb = (const float*)d_in[17];
    const float* lmh = (const float*)d_in[18];
    float* out = (float*)d_out;

    char* p = (char*)d_ws;
    size_t off = 0;
    auto alloc = [&](size_t bytes) -> void* {
        void* r = p + off;
        off += (bytes + 255) & ~(size_t)255;
        return r;
    };
    float* cosT = (float*)alloc((size_t)Sdim * Ddim * 4);
    float* sinT = (float*)alloc((size_t)Sdim * Ddim * 4);
    float* x = (float*)alloc((size_t)BSdim * HDdim * 4);
    unsigned short* h16 = (unsigned short*)alloc((size_t)BSdim * HDdim * 2);
    unsigned short* o16 = (unsigned short*)alloc((size_t)BSdim * HDdim * 2);
    unsigned short* m16 = (unsigned short*)alloc((size_t)BSdim * Idim * 2);
    unsigned short* q16 = (unsigned short*)alloc((size_t)Bdim * Hdim * Sdim * Ddim * 2);
    unsigned short* k16 = (unsigned short*)alloc((size_t)Bdim * Hdim * Sdim * Ddim * 2);
    unsigned short* v16 = (unsigned short*)alloc((size_t)Bdim * Hdim * Sdim * Ddim * 2);
    unsigned short* vTc = (unsigned short*)alloc((size_t)Bdim * Hdim * Sdim * Ddim * 2);
    float* router = (float*)alloc((size_t)Bdim * Hdim * Sdim * 4);
    float* biasC = (float*)alloc((size_t)Bdim * Hdim * Sdim * 4);
    int* idxC = (int*)alloc((size_t)Bdim * Hdim * Sdim * 4);
    int* ntA = (int*)alloc((size_t)Bdim * Hdim * 4);
    float* po = (float*)alloc((size_t)2 * BSdim * HDdim * 4);   // Wo split-K partials
    float* pw = (float*)alloc((size_t)4 * BSdim * HDdim * 4);   // W2 split-K partials
    unsigned short* wts = (unsigned short*)alloc((size_t)Vdim * HDdim * 2);        // 64MB lm_head
    unsigned short* wtsL = (unsigned short*)alloc((size_t)Ldim * 12 * (1u << 20) * 2);  // 96MB layer weights

    const size_t M1 = 1u << 20;  // 1M elems
    const size_t PS = (size_t)BSdim * HDdim;

    init_kernel<<<BSdim + 256, 256, 0, stream>>>(ids, emb, x, cosT, sinT);
    tconv_all<<<49152 + 32000, 256, 0, stream>>>(Wq, Wk, Wv, Wo, W1, W2, lmh, wtsL, wts);

    for (int l = 0; l < Ldim; l++) {
        unsigned short* wl = wtsL + (size_t)l * 12 * M1;
        const float* Wr_l = Wr + (size_t)l * HDdim * Hdim;
        const float* b1_l = b1 + (size_t)l * Idim;
        const float* b2_l = b2 + (size_t)l * HDdim;

        // ln1 (+fused router). For l>0 it also folds in prev layer's W2 partials + b2.
        if (l == 0)
            ln_kernel<0><<<BSdim, 256, 0, stream>>>(x, nullptr, nullptr, 0, nullptr,
                                                    ln1w + l * HDdim, ln1b + l * HDdim, h16, Wr_l, router);
        else
            ln_kernel<4><<<BSdim, 256, 0, stream>>>(x, x, pw, PS, b2 + (size_t)(l - 1) * HDdim,
                                                    ln1w + l * HDdim, ln1b + l * HDdim, h16, Wr_l, router);
        topk_kernel<<<Bdim * Hdim, 1024, 0, stream>>>(router, amask, biasC, idxC, ntA);
        // fused QKV GEMM (8-phase, 128x128): grid 16 x 24 = 384
        gemm8p<1, 128, 128, 4, 2><<<384, 512, 0, stream>>>(h16, wl, nullptr, q16, k16, v16,
                                                           nullptr, cosT, sinT, HDdim, HDdim, 0, 16, 24, 0);
        // compacted V^T gather; K gathered in-attn
        vgather_kernel<<<dim3(16, 32), 256, 0, stream>>>(v16, idxC, ntA, vTc);
        // attention: QBLK=128, 8 waves
        attn_kernel<<<dim3(8, 32), 512, 0, stream>>>(q16, k16, vTc, idxC, biasC, ntA, o16);
        // Wo GEMM (split-K=2 partial buffers): grid 16 x 8 x 2 = 256
        gemm8p<5, 128, 128, 4, 2><<<256, 512, 0, stream>>>(o16, wl + 3 * M1, po, nullptr, nullptr, nullptr,
                                                           nullptr, nullptr, nullptr, 512, HDdim, HDdim, 16, 8, PS);
        // ln2 folds in Wo partials (x += po0+po1) and LNs the result
        ln_kernel<2><<<BSdim, 256, 0, stream>>>(x, x, po, PS, nullptr,
                                                ln2w + l * HDdim, ln2b + l * HDdim, h16, nullptr, nullptr);
        // W1 GEMM (bias+silu): grid 16 x 32 = 512
        gemm8p<3, 128, 128, 4, 2><<<512, 512, 0, stream>>>(h16, wl + 4 * M1, nullptr, m16, nullptr, nullptr,
                                                           b1_l, nullptr, nullptr, HDdim, HDdim, Idim, 16, 32, 0);
        // W2 GEMM (split-K=4 partial buffers): grid 16 x 8 x 4 = 512
        gemm8p<5, 128, 128, 4, 2><<<512, 512, 0, stream>>>(m16, wl + 8 * M1, pw, nullptr, nullptr, nullptr,
                                                           nullptr, nullptr, nullptr, 1024, Idim, HDdim, 16, 8, PS);
    }

    // final ln folds in last layer's W2 partials + b2
    ln_kernel<4><<<BSdim, 256, 0, stream>>>(x, nullptr, pw, PS, b2 + (size_t)3 * HDdim,
                                            nw, nb, h16, nullptr, nullptr);
    // lm_head (256x256, nontemporal out), split into two dispatches
    gemm8p<7, 256, 256, 2, 4><<<496, 512, 0, stream>>>(h16, wts, out, nullptr, nullptr, nullptr,
                                                       nullptr, nullptr, nullptr, HDdim, HDdim, Vdim, 8, 62, 0);
    gemm8p<7, 256, 256, 2, 4><<<504, 512, 0, stream>>>(h16, wts + (size_t)62 * 256 * HDdim, out + 62 * 256,
                                                       nullptr, nullptr, nullptr, nullptr, nullptr, nullptr,
                                                       HDdim, HDdim, Vdim, 8, 63, 0);
}